// Round 1
// baseline (741.690 us; speedup 1.0000x reference)
//
#include <hip/hip_runtime.h>
#include <math.h>

#define F1 256
#define F2 128
#define F3 40

// ---------------- CSR build ----------------
__global__ __launch_bounds__(256) void k_zero(int* __restrict__ p, int n) {
  int i = blockIdx.x * 256 + threadIdx.x;
  if (i < n) p[i] = 0;
}

__global__ __launch_bounds__(256) void k_hist(const int* __restrict__ row, int* __restrict__ deg, int E) {
  int e = blockIdx.x * 256 + threadIdx.x;
  if (e < E) atomicAdd(&deg[row[e]], 1);
}

// exclusive scan, chunk = 1024 elements (256 thr x 4)
__global__ __launch_bounds__(256) void k_scan1(const int* __restrict__ in, int* __restrict__ out,
                                               int* __restrict__ aux, int n) {
  __shared__ int lds[256];
  int tid = threadIdx.x;
  int base = blockIdx.x * 1024 + tid * 4;
  int v0 = 0, v1 = 0, v2 = 0, v3 = 0;
  if (base + 0 < n) v0 = in[base + 0];
  if (base + 1 < n) v1 = in[base + 1];
  if (base + 2 < n) v2 = in[base + 2];
  if (base + 3 < n) v3 = in[base + 3];
  int s = v0 + v1 + v2 + v3;
  lds[tid] = s;
  __syncthreads();
  for (int off = 1; off < 256; off <<= 1) {
    int t = (tid >= off) ? lds[tid - off] : 0;
    __syncthreads();
    lds[tid] += t;
    __syncthreads();
  }
  int excl = (tid > 0) ? lds[tid - 1] : 0;
  if (tid == 255) aux[blockIdx.x] = lds[255];
  if (base + 0 < n) out[base + 0] = excl;
  if (base + 1 < n) out[base + 1] = excl + v0;
  if (base + 2 < n) out[base + 2] = excl + v0 + v1;
  if (base + 3 < n) out[base + 3] = excl + v0 + v1 + v2;
}

__global__ __launch_bounds__(128) void k_scan_aux(int* __restrict__ aux, int nb) {
  __shared__ int lds[128];
  int tid = threadIdx.x;
  int v = (tid < nb) ? aux[tid] : 0;
  lds[tid] = v;
  __syncthreads();
  for (int off = 1; off < 128; off <<= 1) {
    int t = (tid >= off) ? lds[tid - off] : 0;
    __syncthreads();
    lds[tid] += t;
    __syncthreads();
  }
  int excl = (tid > 0) ? lds[tid - 1] : 0;
  if (tid < nb) aux[tid] = excl;
}

__global__ __launch_bounds__(256) void k_scan_add(int* __restrict__ out, const int* __restrict__ aux,
                                                  int n, int E) {
  int add = aux[blockIdx.x];
  int base = blockIdx.x * 1024 + threadIdx.x * 4;
#pragma unroll
  for (int i = 0; i < 4; i++)
    if (base + i < n) out[base + i] += add;
  if (blockIdx.x == 0 && threadIdx.x == 0) out[n] = E;
}

__global__ __launch_bounds__(256) void k_scatter(const int* __restrict__ row, const int* __restrict__ col,
                                                 const float* __restrict__ w, const int* __restrict__ ip,
                                                 int* __restrict__ cur, int* __restrict__ ecol,
                                                 float* __restrict__ ew, int E) {
  int e = blockIdx.x * 256 + threadIdx.x;
  if (e < E) {
    int r = row[e];
    int pos = ip[r] + atomicAdd(&cur[r], 1);
    ecol[pos] = col[e];
    ew[pos] = w[e];
  }
}

// ---------------- GEMM1: h0[N,128] = x[N,256] @ W1[256,128] ----------------
#define G1_ROWS 16
__global__ __launch_bounds__(128) void k_gemm1(const float* __restrict__ x, const float* __restrict__ W1,
                                               float* __restrict__ h0) {
  __shared__ float xs[G1_ROWS][F1];
  const int tid = threadIdx.x;
  const int r0 = blockIdx.x * G1_ROWS;
  const float4* src = (const float4*)(x + (size_t)r0 * F1);
  float4* dst = (float4*)&xs[0][0];
#pragma unroll
  for (int i = 0; i < 8; i++) dst[tid + i * 128] = src[tid + i * 128];
  __syncthreads();
  float acc[G1_ROWS];
#pragma unroll
  for (int i = 0; i < G1_ROWS; i++) acc[i] = 0.f;
  for (int k = 0; k < F1; k += 4) {
    float w0 = W1[(k + 0) * F2 + tid];
    float w1 = W1[(k + 1) * F2 + tid];
    float w2 = W1[(k + 2) * F2 + tid];
    float w3 = W1[(k + 3) * F2 + tid];
#pragma unroll
    for (int i = 0; i < G1_ROWS; i++) {
      float4 xv = *(const float4*)&xs[i][k];
      acc[i] = fmaf(xv.x, w0, acc[i]);
      acc[i] = fmaf(xv.y, w1, acc[i]);
      acc[i] = fmaf(xv.z, w2, acc[i]);
      acc[i] = fmaf(xv.w, w3, acc[i]);
    }
  }
#pragma unroll
  for (int i = 0; i < G1_ROWS; i++) h0[(size_t)(r0 + i) * F2 + tid] = acc[i];
}

// ---------------- SpMM1 (F=128) + b1 + relu: wave per node ----------------
__global__ __launch_bounds__(256) void k_spmm1(const int* __restrict__ ip, const int* __restrict__ ec,
                                               const float* __restrict__ ew, const float* __restrict__ h0,
                                               const float* __restrict__ b1, float* __restrict__ h) {
  int node = blockIdx.x * 4 + (threadIdx.x >> 6);
  int lane = threadIdx.x & 63;
  int e0 = ip[node], e1 = ip[node + 1];
  float2 acc = {0.f, 0.f};
  for (int e = e0; e < e1; ++e) {
    int c = ec[e];
    float wt = ew[e];
    float2 v = *(const float2*)(h0 + (size_t)c * F2 + lane * 2);
    acc.x = fmaf(wt, v.x, acc.x);
    acc.y = fmaf(wt, v.y, acc.y);
  }
  float2 r;
  r.x = fmaxf(acc.x + b1[lane * 2 + 0], 0.f);
  r.y = fmaxf(acc.y + b1[lane * 2 + 1], 0.f);
  *(float2*)(h + (size_t)node * F2 + lane * 2) = r;
}

// ---------------- GEMM2: h2[N,40] = h[N,128] @ W2[128,40] ----------------
__global__ __launch_bounds__(320) void k_gemm2(const float* __restrict__ h, const float* __restrict__ W2,
                                               float* __restrict__ h2) {
  __shared__ float w2s[F2 * F3];
  int tid = threadIdx.x;
  for (int i = tid; i < F2 * F3; i += 320) w2s[i] = W2[i];
  __syncthreads();
  int node = blockIdx.x * 8 + tid / 40;
  int c = tid % 40;
  const float4* hrow = (const float4*)(h + (size_t)node * F2);
  float acc = 0.f;
#pragma unroll
  for (int kk = 0; kk < F2 / 4; kk++) {
    float4 hv = hrow[kk];
    int k = kk * 4;
    acc = fmaf(hv.x, w2s[(k + 0) * F3 + c], acc);
    acc = fmaf(hv.y, w2s[(k + 1) * F3 + c], acc);
    acc = fmaf(hv.z, w2s[(k + 2) * F3 + c], acc);
    acc = fmaf(hv.w, w2s[(k + 3) * F3 + c], acc);
  }
  h2[(size_t)node * F3 + c] = acc;
}

// ---------------- SpMM2 (F=40) + b2: wave per node ----------------
__global__ __launch_bounds__(256) void k_spmm2(const int* __restrict__ ip, const int* __restrict__ ec,
                                               const float* __restrict__ ew, const float* __restrict__ h2,
                                               const float* __restrict__ b2, float* __restrict__ out) {
  int node = blockIdx.x * 4 + (threadIdx.x >> 6);
  int lane = threadIdx.x & 63;
  int e0 = ip[node], e1 = ip[node + 1];
  float acc = 0.f;
  for (int e = e0; e < e1; ++e) {
    int c = ec[e];
    float wt = ew[e];
    // lanes >= 40 read into the (live, larger) ws region -> safe, discarded at store
    float v = h2[(size_t)c * F3 + lane];
    acc = fmaf(wt, v, acc);
  }
  if (lane < F3) out[(size_t)node * F3 + lane] = acc + b2[lane];
}

// ---------------- log_softmax in place over 40 cols ----------------
__global__ __launch_bounds__(256) void k_lsm(float* __restrict__ io) {
  int node = blockIdx.x * 4 + (threadIdx.x >> 6);
  int lane = threadIdx.x & 63;
  float* p = io + (size_t)node * F3;
  float v = (lane < F3) ? p[lane] : -INFINITY;
  float m = v;
#pragma unroll
  for (int off = 32; off > 0; off >>= 1) m = fmaxf(m, __shfl_xor(m, off));
  float e = (lane < F3) ? __expf(v - m) : 0.f;
  float s = e;
#pragma unroll
  for (int off = 32; off > 0; off >>= 1) s += __shfl_xor(s, off);
  if (lane < F3) p[lane] = v - m - __logf(s);
}

extern "C" void kernel_launch(void* const* d_in, const int* in_sizes, int n_in,
                              void* d_out, int out_size, void* d_ws, size_t ws_size,
                              hipStream_t stream) {
  const float* x     = (const float*)d_in[0];
  const int* erow    = (const int*)d_in[1];
  const int* ecol_in = (const int*)d_in[2];
  const float* ew_in = (const float*)d_in[3];
  const float* W1    = (const float*)d_in[4];
  const float* b1    = (const float*)d_in[5];
  const float* W2    = (const float*)d_in[6];
  const float* b2    = (const float*)d_in[7];
  float* out = (float*)d_out;

  const int N = in_sizes[0] / F1;  // 100000
  const int E = in_sizes[1];       // 1600000

  // ws layout (floats): h0 | h | csr ints ; h2 aliases dead h0
  float* h0 = (float*)d_ws;                 // N*F2
  float* h  = h0 + (size_t)N * F2;          // N*F2
  float* h2 = h0;                           // N*F3 (h0 dead by then)
  int* ip   = (int*)(h + (size_t)N * F2);   // N+1 (padded)
  int* deg  = ip + (N + 32);                // N
  int* cur  = deg + N;                      // N  (adjacent to deg for one zero-fill)
  int* aux  = cur + N;                      // 128
  int* ec   = aux + 128;                    // E
  float* ewp = (float*)(ec + E);            // E

  const int nb = (N + 1023) / 1024;

  hipLaunchKernelGGL(k_zero, dim3((2 * N + 255) / 256), dim3(256), 0, stream, deg, 2 * N);
  hipLaunchKernelGGL(k_hist, dim3((E + 255) / 256), dim3(256), 0, stream, erow, deg, E);
  hipLaunchKernelGGL(k_scan1, dim3(nb), dim3(256), 0, stream, deg, ip, aux, N);
  hipLaunchKernelGGL(k_scan_aux, dim3(1), dim3(128), 0, stream, aux, nb);
  hipLaunchKernelGGL(k_scan_add, dim3(nb), dim3(256), 0, stream, ip, aux, N, E);
  hipLaunchKernelGGL(k_scatter, dim3((E + 255) / 256), dim3(256), 0, stream,
                     erow, ecol_in, ew_in, ip, cur, ec, ewp, E);
  hipLaunchKernelGGL(k_gemm1, dim3(N / G1_ROWS), dim3(128), 0, stream, x, W1, h0);
  hipLaunchKernelGGL(k_spmm1, dim3(N / 4), dim3(256), 0, stream, ip, ec, ewp, h0, b1, h);
  hipLaunchKernelGGL(k_gemm2, dim3(N / 8), dim3(320), 0, stream, h, W2, h2);
  hipLaunchKernelGGL(k_spmm2, dim3(N / 4), dim3(256), 0, stream, ip, ec, ewp, h2, b2, out);
  hipLaunchKernelGGL(k_lsm, dim3(N / 4), dim3(256), 0, stream, out);
}

// Round 3
// 620.742 us; speedup vs baseline: 1.1948x; 1.1948x over previous
//
#include <hip/hip_runtime.h>
#include <math.h>

#define F1 256
#define F2 128
#define F3 40

typedef unsigned short ushort_t;

__device__ inline ushort_t f2bf(float f) {
  unsigned u = __builtin_bit_cast(unsigned, f);
  u += 0x7FFF + ((u >> 16) & 1);
  return (ushort_t)(u >> 16);
}
__device__ inline float bf2f(ushort_t b) {
  unsigned u = ((unsigned)b) << 16;
  return __builtin_bit_cast(float, u);
}

// ---------------- CSR build ----------------
__global__ __launch_bounds__(256) void k_zero(int* __restrict__ p, int n) {
  int i = blockIdx.x * 256 + threadIdx.x;
  if (i < n) p[i] = 0;
}

__global__ __launch_bounds__(256) void k_hist(const int* __restrict__ row, int* __restrict__ deg, int E) {
  int e = blockIdx.x * 256 + threadIdx.x;
  if (e < E) atomicAdd(&deg[row[e]], 1);
}

__global__ __launch_bounds__(256) void k_scan1(const int* __restrict__ in, int* __restrict__ out,
                                               int* __restrict__ aux, int n) {
  __shared__ int lds[256];
  int tid = threadIdx.x;
  int base = blockIdx.x * 1024 + tid * 4;
  int v0 = 0, v1 = 0, v2 = 0, v3 = 0;
  if (base + 0 < n) v0 = in[base + 0];
  if (base + 1 < n) v1 = in[base + 1];
  if (base + 2 < n) v2 = in[base + 2];
  if (base + 3 < n) v3 = in[base + 3];
  int s = v0 + v1 + v2 + v3;
  lds[tid] = s;
  __syncthreads();
  for (int off = 1; off < 256; off <<= 1) {
    int t = (tid >= off) ? lds[tid - off] : 0;
    __syncthreads();
    lds[tid] += t;
    __syncthreads();
  }
  int excl = (tid > 0) ? lds[tid - 1] : 0;
  if (tid == 255) aux[blockIdx.x] = lds[255];
  if (base + 0 < n) out[base + 0] = excl;
  if (base + 1 < n) out[base + 1] = excl + v0;
  if (base + 2 < n) out[base + 2] = excl + v0 + v1;
  if (base + 3 < n) out[base + 3] = excl + v0 + v1 + v2;
}

__global__ __launch_bounds__(128) void k_scan_aux(int* __restrict__ aux, int nb) {
  __shared__ int lds[128];
  int tid = threadIdx.x;
  int v = (tid < nb) ? aux[tid] : 0;
  lds[tid] = v;
  __syncthreads();
  for (int off = 1; off < 128; off <<= 1) {
    int t = (tid >= off) ? lds[tid - off] : 0;
    __syncthreads();
    lds[tid] += t;
    __syncthreads();
  }
  int excl = (tid > 0) ? lds[tid - 1] : 0;
  if (tid < nb) aux[tid] = excl;
}

__global__ __launch_bounds__(256) void k_scan_add(int* __restrict__ out, const int* __restrict__ aux,
                                                  int n, int E) {
  int add = aux[blockIdx.x];
  int base = blockIdx.x * 1024 + threadIdx.x * 4;
#pragma unroll
  for (int i = 0; i < 4; i++)
    if (base + i < n) out[base + i] += add;
  if (blockIdx.x == 0 && threadIdx.x == 0) out[n] = E;
}

__global__ __launch_bounds__(256) void k_scatter(const int* __restrict__ row, const int* __restrict__ col,
                                                 const float* __restrict__ w, const int* __restrict__ ip,
                                                 int* __restrict__ cur, int* __restrict__ ecol,
                                                 float* __restrict__ ew, int E) {
  int e = blockIdx.x * 256 + threadIdx.x;
  if (e < E) {
    int r = row[e];
    int pos = ip[r] + atomicAdd(&cur[r], 1);
    ecol[pos] = col[e];
    ew[pos] = w[e];
  }
}

// ---------------- GEMM1: h0[N,128] = x[N,256] @ W1[256,128], store bf16 ----------------
#define G1_ROWS 16
__global__ __launch_bounds__(128) void k_gemm1(const float* __restrict__ x, const float* __restrict__ W1,
                                               ushort_t* __restrict__ h0bf) {
  __shared__ float xs[G1_ROWS][F1];
  const int tid = threadIdx.x;
  const int r0 = blockIdx.x * G1_ROWS;
  const float4* src = (const float4*)(x + (size_t)r0 * F1);
  float4* dst = (float4*)&xs[0][0];
#pragma unroll
  for (int i = 0; i < 8; i++) dst[tid + i * 128] = src[tid + i * 128];
  __syncthreads();
  float acc[G1_ROWS];
#pragma unroll
  for (int i = 0; i < G1_ROWS; i++) acc[i] = 0.f;
  for (int k = 0; k < F1; k += 4) {
    float w0 = W1[(k + 0) * F2 + tid];
    float w1 = W1[(k + 1) * F2 + tid];
    float w2 = W1[(k + 2) * F2 + tid];
    float w3 = W1[(k + 3) * F2 + tid];
#pragma unroll
    for (int i = 0; i < G1_ROWS; i++) {
      float4 xv = *(const float4*)&xs[i][k];
      acc[i] = fmaf(xv.x, w0, acc[i]);
      acc[i] = fmaf(xv.y, w1, acc[i]);
      acc[i] = fmaf(xv.z, w2, acc[i]);
      acc[i] = fmaf(xv.w, w3, acc[i]);
    }
  }
#pragma unroll
  for (int i = 0; i < G1_ROWS; i++) h0bf[(size_t)(r0 + i) * F2 + tid] = f2bf(acc[i]);
}

// ---------------- SpMM1 (F=128, bf16 gather) + b1 + relu: wave per node ----------------
__global__ __launch_bounds__(256) void k_spmm1(const int* __restrict__ ip, const int* __restrict__ ec,
                                               const float* __restrict__ ew, const ushort_t* __restrict__ h0bf,
                                               const float* __restrict__ b1, ushort_t* __restrict__ hbf) {
  int node = blockIdx.x * 4 + (threadIdx.x >> 6);
  int lane = threadIdx.x & 63;
  int e0 = ip[node], e1 = ip[node + 1];
  float ax = 0.f, ay = 0.f;
  int e = e0;
  for (; e + 1 < e1; e += 2) {
    int c0 = ec[e], c1 = ec[e + 1];
    float w0 = ew[e], w1 = ew[e + 1];
    ushort2 v0 = *(const ushort2*)(h0bf + (size_t)c0 * F2 + lane * 2);
    ushort2 v1 = *(const ushort2*)(h0bf + (size_t)c1 * F2 + lane * 2);
    ax = fmaf(w0, bf2f(v0.x), ax);
    ay = fmaf(w0, bf2f(v0.y), ay);
    ax = fmaf(w1, bf2f(v1.x), ax);
    ay = fmaf(w1, bf2f(v1.y), ay);
  }
  if (e < e1) {
    int c = ec[e];
    float wt = ew[e];
    ushort2 v = *(const ushort2*)(h0bf + (size_t)c * F2 + lane * 2);
    ax = fmaf(wt, bf2f(v.x), ax);
    ay = fmaf(wt, bf2f(v.y), ay);
  }
  float2 bb = *(const float2*)(b1 + lane * 2);
  ushort2 r;
  r.x = f2bf(fmaxf(ax + bb.x, 0.f));
  r.y = f2bf(fmaxf(ay + bb.y, 0.f));
  *(ushort2*)(hbf + (size_t)node * F2 + lane * 2) = r;
}

// ---------------- GEMM2: h2[N,40] = h[N,128] @ W2[128,40], bf16 in/out ----------------
__global__ __launch_bounds__(320) void k_gemm2(const ushort_t* __restrict__ hbf, const float* __restrict__ W2,
                                               ushort_t* __restrict__ h2bf) {
  __shared__ float w2s[F2 * F3];
  __shared__ float hs[8 * F2];
  int tid = threadIdx.x;
  for (int i = tid; i < F2 * F3; i += 320) w2s[i] = W2[i];
  if (tid < 128) {
    uint4 v = ((const uint4*)hbf)[(size_t)blockIdx.x * 128 + tid];
    float* d = &hs[tid * 8];
    unsigned a0 = v.x, a1 = v.y, a2 = v.z, a3 = v.w;
    d[0] = bf2f((ushort_t)(a0 & 0xffff)); d[1] = bf2f((ushort_t)(a0 >> 16));
    d[2] = bf2f((ushort_t)(a1 & 0xffff)); d[3] = bf2f((ushort_t)(a1 >> 16));
    d[4] = bf2f((ushort_t)(a2 & 0xffff)); d[5] = bf2f((ushort_t)(a2 >> 16));
    d[6] = bf2f((ushort_t)(a3 & 0xffff)); d[7] = bf2f((ushort_t)(a3 >> 16));
  }
  __syncthreads();
  int nl = tid / 40, c = tid % 40;
  const float* hr = &hs[nl * F2];
  float acc = 0.f;
#pragma unroll
  for (int k = 0; k < F2; k += 4) {
    acc = fmaf(hr[k + 0], w2s[(k + 0) * F3 + c], acc);
    acc = fmaf(hr[k + 1], w2s[(k + 1) * F3 + c], acc);
    acc = fmaf(hr[k + 2], w2s[(k + 2) * F3 + c], acc);
    acc = fmaf(hr[k + 3], w2s[(k + 3) * F3 + c], acc);
  }
  h2bf[(size_t)(blockIdx.x * 8 + nl) * F3 + c] = f2bf(acc);
}

// ---------------- SpMM2 (F=40, bf16 gather) + b2 + log_softmax fused ----------------
__global__ __launch_bounds__(256) void k_spmm2lsm(const int* __restrict__ ip, const int* __restrict__ ec,
                                                  const float* __restrict__ ew, const ushort_t* __restrict__ h2bf,
                                                  const float* __restrict__ b2, float* __restrict__ out) {
  int node = blockIdx.x * 4 + (threadIdx.x >> 6);
  int lane = threadIdx.x & 63;
  int e0 = ip[node], e1 = ip[node + 1];
  float acc = 0.f;
  int e = e0;
  for (; e + 1 < e1; e += 2) {
    int c0 = ec[e], c1 = ec[e + 1];
    float w0 = ew[e], w1 = ew[e + 1];
    float v0 = (lane < F3) ? bf2f(h2bf[(size_t)c0 * F3 + lane]) : 0.f;
    float v1 = (lane < F3) ? bf2f(h2bf[(size_t)c1 * F3 + lane]) : 0.f;
    acc = fmaf(w0, v0, acc);
    acc = fmaf(w1, v1, acc);
  }
  if (e < e1) {
    int c = ec[e];
    float wt = ew[e];
    float v = (lane < F3) ? bf2f(h2bf[(size_t)c * F3 + lane]) : 0.f;
    acc = fmaf(wt, v, acc);
  }
  float logit = (lane < F3) ? (acc + b2[lane]) : -INFINITY;
  float m = logit;
#pragma unroll
  for (int off = 32; off > 0; off >>= 1) m = fmaxf(m, __shfl_xor(m, off));
  float ex = (lane < F3) ? __expf(logit - m) : 0.f;
  float s = ex;
#pragma unroll
  for (int off = 32; off > 0; off >>= 1) s += __shfl_xor(s, off);
  if (lane < F3) out[(size_t)node * F3 + lane] = logit - m - __logf(s);
}

extern "C" void kernel_launch(void* const* d_in, const int* in_sizes, int n_in,
                              void* d_out, int out_size, void* d_ws, size_t ws_size,
                              hipStream_t stream) {
  const float* x     = (const float*)d_in[0];
  const int* erow    = (const int*)d_in[1];
  const int* ecol_in = (const int*)d_in[2];
  const float* ew_in = (const float*)d_in[3];
  const float* W1    = (const float*)d_in[4];
  const float* b1    = (const float*)d_in[5];
  const float* W2    = (const float*)d_in[6];
  const float* b2    = (const float*)d_in[7];
  float* out = (float*)d_out;

  const int N = in_sizes[0] / F1;  // 100000
  const int E = in_sizes[1];       // 1600000

  // ws layout: h0bf[N*128] | hbf[N*128] | h2bf[N*40+64] (all ushort) | ints
  ushort_t* h0bf = (ushort_t*)d_ws;
  ushort_t* hbf  = h0bf + (size_t)N * F2;
  ushort_t* h2bf = hbf + (size_t)N * F2;
  int* ip   = (int*)(h2bf + (size_t)N * F3 + 64);
  int* deg  = ip + (N + 32);
  int* cur  = deg + N;
  int* aux  = cur + N;
  int* ec   = aux + 128;
  float* ewp = (float*)(ec + E);

  const int nb = (N + 1023) / 1024;

  hipLaunchKernelGGL(k_zero, dim3((2 * N + 255) / 256), dim3(256), 0, stream, deg, 2 * N);
  hipLaunchKernelGGL(k_hist, dim3((E + 255) / 256), dim3(256), 0, stream, erow, deg, E);
  hipLaunchKernelGGL(k_scan1, dim3(nb), dim3(256), 0, stream, deg, ip, aux, N);
  hipLaunchKernelGGL(k_scan_aux, dim3(1), dim3(128), 0, stream, aux, nb);
  hipLaunchKernelGGL(k_scan_add, dim3(nb), dim3(256), 0, stream, ip, aux, N, E);
  hipLaunchKernelGGL(k_scatter, dim3((E + 255) / 256), dim3(256), 0, stream,
                     erow, ecol_in, ew_in, ip, cur, ec, ewp, E);
  hipLaunchKernelGGL(k_gemm1, dim3(N / G1_ROWS), dim3(128), 0, stream, x, W1, h0bf);
  hipLaunchKernelGGL(k_spmm1, dim3(N / 4), dim3(256), 0, stream, ip, ec, ewp, h0bf, b1, hbf);
  hipLaunchKernelGGL(k_gemm2, dim3(N / 8), dim3(320), 0, stream, hbf, W2, h2bf);
  hipLaunchKernelGGL(k_spmm2lsm, dim3(N / 4), dim3(256), 0, stream, ip, ec, ewp, h2bf, b2, out);
}

// Round 4
// 542.255 us; speedup vs baseline: 1.3678x; 1.1447x over previous
//
#include <hip/hip_runtime.h>
#include <math.h>

#define F1 256
#define F2 128
#define F3 40

typedef unsigned short ushort_t;
typedef __attribute__((ext_vector_type(8))) short bf16x8;
typedef __attribute__((ext_vector_type(4))) float f32x4;

__device__ inline ushort_t f2bf(float f) {
  unsigned u = __builtin_bit_cast(unsigned, f);
  u += 0x7FFF + ((u >> 16) & 1);
  return (ushort_t)(u >> 16);
}
__device__ inline float bf2f(ushort_t b) {
  unsigned u = ((unsigned)b) << 16;
  return __builtin_bit_cast(float, u);
}

// ---------------- CSR build ----------------
__global__ __launch_bounds__(256) void k_zero(int* __restrict__ p, int n) {
  int i = blockIdx.x * 256 + threadIdx.x;
  if (i < n) p[i] = 0;
}

__global__ __launch_bounds__(256) void k_hist(const int* __restrict__ row, int* __restrict__ deg, int E) {
  int e = blockIdx.x * 256 + threadIdx.x;
  if (e < E) atomicAdd(&deg[row[e]], 1);
}

__global__ __launch_bounds__(256) void k_scan1(const int* __restrict__ in, int* __restrict__ out,
                                               int* __restrict__ aux, int n) {
  __shared__ int lds[256];
  int tid = threadIdx.x;
  int base = blockIdx.x * 1024 + tid * 4;
  int v0 = 0, v1 = 0, v2 = 0, v3 = 0;
  if (base + 0 < n) v0 = in[base + 0];
  if (base + 1 < n) v1 = in[base + 1];
  if (base + 2 < n) v2 = in[base + 2];
  if (base + 3 < n) v3 = in[base + 3];
  int s = v0 + v1 + v2 + v3;
  lds[tid] = s;
  __syncthreads();
  for (int off = 1; off < 256; off <<= 1) {
    int t = (tid >= off) ? lds[tid - off] : 0;
    __syncthreads();
    lds[tid] += t;
    __syncthreads();
  }
  int excl = (tid > 0) ? lds[tid - 1] : 0;
  if (tid == 255) aux[blockIdx.x] = lds[255];
  if (base + 0 < n) out[base + 0] = excl;
  if (base + 1 < n) out[base + 1] = excl + v0;
  if (base + 2 < n) out[base + 2] = excl + v0 + v1;
  if (base + 3 < n) out[base + 3] = excl + v0 + v1 + v2;
}

__global__ __launch_bounds__(128) void k_scan_aux(int* __restrict__ aux, int nb) {
  __shared__ int lds[128];
  int tid = threadIdx.x;
  int v = (tid < nb) ? aux[tid] : 0;
  lds[tid] = v;
  __syncthreads();
  for (int off = 1; off < 128; off <<= 1) {
    int t = (tid >= off) ? lds[tid - off] : 0;
    __syncthreads();
    lds[tid] += t;
    __syncthreads();
  }
  int excl = (tid > 0) ? lds[tid - 1] : 0;
  if (tid < nb) aux[tid] = excl;
}

__global__ __launch_bounds__(256) void k_scan_add(int* __restrict__ out, const int* __restrict__ aux,
                                                  int n, int E) {
  int add = aux[blockIdx.x];
  int base = blockIdx.x * 1024 + threadIdx.x * 4;
#pragma unroll
  for (int i = 0; i < 4; i++)
    if (base + i < n) out[base + i] += add;
  if (blockIdx.x == 0 && threadIdx.x == 0) out[n] = E;
}

__global__ __launch_bounds__(256) void k_scatter(const int* __restrict__ row, const int* __restrict__ col,
                                                 const float* __restrict__ w, const int* __restrict__ ip,
                                                 int* __restrict__ cur, int* __restrict__ ecol,
                                                 float* __restrict__ ew, int E) {
  int e = blockIdx.x * 256 + threadIdx.x;
  if (e < E) {
    int r = row[e];
    int pos = ip[r] + atomicAdd(&cur[r], 1);
    ecol[pos] = col[e];
    ew[pos] = w[e];
  }
}

// ---------------- W1 prep: fp32 [256][128] -> bf16 [8 kt][128 col][40 k-pad] ----------------
__global__ __launch_bounds__(256) void k_w1prep(const float* __restrict__ W1, ushort_t* __restrict__ w1p) {
  int t = blockIdx.x * 256 + threadIdx.x;
  if (t < 256 * 128) {
    int k = t >> 7, c = t & 127;
    w1p[(size_t)((k >> 5) * 128 + c) * 40 + (k & 31)] = f2bf(W1[t]);
  }
}

// ---------------- GEMM1 (MFMA): h0[N,128] = x[N,256] @ W1, store bf16 ----------------
#define XPAD 264
__global__ __launch_bounds__(256) void k_gemm1(const float* __restrict__ x, const ushort_t* __restrict__ w1p,
                                               ushort_t* __restrict__ h0bf, int N) {
  __shared__ ushort_t xs[64 * XPAD];        // 33792 B
  __shared__ ushort_t wb[2][128 * 40];      // 20480 B
  const int tid = threadIdx.x;
  const int lane = tid & 63;
  const int w = tid >> 6;
  const int r0 = blockIdx.x * 64;

  // stage x tile (fp32 -> bf16): each wave stages its own 16 rows; one row per iter (64 lanes x float4)
#pragma unroll 4
  for (int i = 0; i < 16; ++i) {
    int row = w * 16 + i;
    int gr = r0 + row;
    if (gr >= N) gr = 0;
    float4 v = ((const float4*)(x + (size_t)gr * F1))[lane];
    ushort_t* d = &xs[row * XPAD + lane * 4];
    d[0] = f2bf(v.x); d[1] = f2bf(v.y); d[2] = f2bf(v.z); d[3] = f2bf(v.w);
  }
  // stage W1 k-tile 0
  {
    const uint4* src = (const uint4*)w1p;
    uint4* dst = (uint4*)&wb[0][0];
    for (int o = tid; o < 640; o += 256) dst[o] = src[o];
  }
  __syncthreads();

  f32x4 acc[8];
#pragma unroll
  for (int t = 0; t < 8; ++t) acc[t] = (f32x4){0.f, 0.f, 0.f, 0.f};

  const int arow = w * 16 + (lane & 15);
  const int kg = (lane >> 4) * 8;  // self-consistent slot->k convention for A and B

  for (int kt = 0; kt < 8; ++kt) {
    if (kt < 7) {  // prefetch next W1 k-tile into the other buffer
      const uint4* src = (const uint4*)(w1p + (size_t)(kt + 1) * 128 * 40);
      uint4* dst = (uint4*)&wb[(kt + 1) & 1][0];
      for (int o = tid; o < 640; o += 256) dst[o] = src[o];
    }
    bf16x8 a = *(const bf16x8*)&xs[arow * XPAD + kt * 32 + kg];
    const ushort_t* wbb = &wb[kt & 1][0];
#pragma unroll
    for (int t = 0; t < 8; ++t) {
      bf16x8 b = *(const bf16x8*)&wbb[(t * 16 + (lane & 15)) * 40 + kg];
      acc[t] = __builtin_amdgcn_mfma_f32_16x16x32_bf16(a, b, acc[t], 0, 0, 0);
    }
    __syncthreads();
  }

  // C/D layout (HW-verified): col = lane&15, row = (lane>>4)*4 + reg
#pragma unroll
  for (int t = 0; t < 8; ++t) {
    int gc = t * 16 + (lane & 15);
#pragma unroll
    for (int j = 0; j < 4; ++j) {
      int gr = r0 + w * 16 + (lane >> 4) * 4 + j;
      if (gr < N) h0bf[(size_t)gr * F2 + gc] = f2bf(acc[t][j]);
    }
  }
}

// ---------------- SpMM1 (F=128, bf16 gather) + b1 + relu: wave per node ----------------
__global__ __launch_bounds__(256) void k_spmm1(const int* __restrict__ ip, const int* __restrict__ ec,
                                               const float* __restrict__ ew, const ushort_t* __restrict__ h0bf,
                                               const float* __restrict__ b1, ushort_t* __restrict__ hbf) {
  int node = blockIdx.x * 4 + (threadIdx.x >> 6);
  int lane = threadIdx.x & 63;
  int e0 = ip[node], e1 = ip[node + 1];
  float ax = 0.f, ay = 0.f;
  int e = e0;
  for (; e + 1 < e1; e += 2) {
    int c0 = ec[e], c1 = ec[e + 1];
    float w0 = ew[e], w1 = ew[e + 1];
    ushort2 v0 = *(const ushort2*)(h0bf + (size_t)c0 * F2 + lane * 2);
    ushort2 v1 = *(const ushort2*)(h0bf + (size_t)c1 * F2 + lane * 2);
    ax = fmaf(w0, bf2f(v0.x), ax);
    ay = fmaf(w0, bf2f(v0.y), ay);
    ax = fmaf(w1, bf2f(v1.x), ax);
    ay = fmaf(w1, bf2f(v1.y), ay);
  }
  if (e < e1) {
    int c = ec[e];
    float wt = ew[e];
    ushort2 v = *(const ushort2*)(h0bf + (size_t)c * F2 + lane * 2);
    ax = fmaf(wt, bf2f(v.x), ax);
    ay = fmaf(wt, bf2f(v.y), ay);
  }
  float2 bb = *(const float2*)(b1 + lane * 2);
  ushort2 r;
  r.x = f2bf(fmaxf(ax + bb.x, 0.f));
  r.y = f2bf(fmaxf(ay + bb.y, 0.f));
  *(ushort2*)(hbf + (size_t)node * F2 + lane * 2) = r;
}

// ---------------- GEMM2: h2[N,40] = h[N,128] @ W2[128,40], bf16 in/out ----------------
__global__ __launch_bounds__(320) void k_gemm2(const ushort_t* __restrict__ hbf, const float* __restrict__ W2,
                                               ushort_t* __restrict__ h2bf) {
  __shared__ float w2s[F2 * F3];
  __shared__ float hs[8 * F2];
  int tid = threadIdx.x;
  for (int i = tid; i < F2 * F3; i += 320) w2s[i] = W2[i];
  if (tid < 128) {
    uint4 v = ((const uint4*)hbf)[(size_t)blockIdx.x * 128 + tid];
    float* d = &hs[tid * 8];
    unsigned a0 = v.x, a1 = v.y, a2 = v.z, a3 = v.w;
    d[0] = bf2f((ushort_t)(a0 & 0xffff)); d[1] = bf2f((ushort_t)(a0 >> 16));
    d[2] = bf2f((ushort_t)(a1 & 0xffff)); d[3] = bf2f((ushort_t)(a1 >> 16));
    d[4] = bf2f((ushort_t)(a2 & 0xffff)); d[5] = bf2f((ushort_t)(a2 >> 16));
    d[6] = bf2f((ushort_t)(a3 & 0xffff)); d[7] = bf2f((ushort_t)(a3 >> 16));
  }
  __syncthreads();
  int nl = tid / 40, c = tid % 40;
  const float* hr = &hs[nl * F2];
  float acc = 0.f;
#pragma unroll
  for (int k = 0; k < F2; k += 4) {
    acc = fmaf(hr[k + 0], w2s[(k + 0) * F3 + c], acc);
    acc = fmaf(hr[k + 1], w2s[(k + 1) * F3 + c], acc);
    acc = fmaf(hr[k + 2], w2s[(k + 2) * F3 + c], acc);
    acc = fmaf(hr[k + 3], w2s[(k + 3) * F3 + c], acc);
  }
  h2bf[(size_t)(blockIdx.x * 8 + nl) * F3 + c] = f2bf(acc);
}

// ---------------- SpMM2 (F=40, bf16 gather) + b2 + log_softmax fused ----------------
__global__ __launch_bounds__(256) void k_spmm2lsm(const int* __restrict__ ip, const int* __restrict__ ec,
                                                  const float* __restrict__ ew, const ushort_t* __restrict__ h2bf,
                                                  const float* __restrict__ b2, float* __restrict__ out) {
  int node = blockIdx.x * 4 + (threadIdx.x >> 6);
  int lane = threadIdx.x & 63;
  int e0 = ip[node], e1 = ip[node + 1];
  float acc = 0.f;
  int e = e0;
  for (; e + 1 < e1; e += 2) {
    int c0 = ec[e], c1 = ec[e + 1];
    float w0 = ew[e], w1 = ew[e + 1];
    float v0 = (lane < F3) ? bf2f(h2bf[(size_t)c0 * F3 + lane]) : 0.f;
    float v1 = (lane < F3) ? bf2f(h2bf[(size_t)c1 * F3 + lane]) : 0.f;
    acc = fmaf(w0, v0, acc);
    acc = fmaf(w1, v1, acc);
  }
  if (e < e1) {
    int c = ec[e];
    float wt = ew[e];
    float v = (lane < F3) ? bf2f(h2bf[(size_t)c * F3 + lane]) : 0.f;
    acc = fmaf(wt, v, acc);
  }
  float logit = (lane < F3) ? (acc + b2[lane]) : -INFINITY;
  float m = logit;
#pragma unroll
  for (int off = 32; off > 0; off >>= 1) m = fmaxf(m, __shfl_xor(m, off));
  float ex = (lane < F3) ? __expf(logit - m) : 0.f;
  float s = ex;
#pragma unroll
  for (int off = 32; off > 0; off >>= 1) s += __shfl_xor(s, off);
  if (lane < F3) out[(size_t)node * F3 + lane] = logit - m - __logf(s);
}

extern "C" void kernel_launch(void* const* d_in, const int* in_sizes, int n_in,
                              void* d_out, int out_size, void* d_ws, size_t ws_size,
                              hipStream_t stream) {
  const float* x     = (const float*)d_in[0];
  const int* erow    = (const int*)d_in[1];
  const int* ecol_in = (const int*)d_in[2];
  const float* ew_in = (const float*)d_in[3];
  const float* W1    = (const float*)d_in[4];
  const float* b1    = (const float*)d_in[5];
  const float* W2    = (const float*)d_in[6];
  const float* b2    = (const float*)d_in[7];
  float* out = (float*)d_out;

  const int N = in_sizes[0] / F1;  // 100000
  const int E = in_sizes[1];       // 1600000

  // ws layout: h0bf[N*128] | hbf[N*128] | h2bf[N*40+64] (ushort) | ints | w1p
  ushort_t* h0bf = (ushort_t*)d_ws;
  ushort_t* hbf  = h0bf + (size_t)N * F2;
  ushort_t* h2bf = hbf + (size_t)N * F2;
  int* ip   = (int*)(h2bf + (size_t)N * F3 + 64);
  int* deg  = ip + (N + 32);
  int* cur  = deg + N;
  int* aux  = cur + N;
  int* ec   = aux + 128;
  float* ewp = (float*)(ec + E);
  ushort_t* w1p = (ushort_t*)(ewp + E);   // 8*128*40 = 40960 ushorts

  const int nb = (N + 1023) / 1024;

  hipLaunchKernelGGL(k_zero, dim3((2 * N + 255) / 256), dim3(256), 0, stream, deg, 2 * N);
  hipLaunchKernelGGL(k_hist, dim3((E + 255) / 256), dim3(256), 0, stream, erow, deg, E);
  hipLaunchKernelGGL(k_scan1, dim3(nb), dim3(256), 0, stream, deg, ip, aux, N);
  hipLaunchKernelGGL(k_scan_aux, dim3(1), dim3(128), 0, stream, aux, nb);
  hipLaunchKernelGGL(k_scan_add, dim3(nb), dim3(256), 0, stream, ip, aux, N, E);
  hipLaunchKernelGGL(k_scatter, dim3((E + 255) / 256), dim3(256), 0, stream,
                     erow, ecol_in, ew_in, ip, cur, ec, ewp, E);
  hipLaunchKernelGGL(k_w1prep, dim3(128), dim3(256), 0, stream, W1, w1p);
  hipLaunchKernelGGL(k_gemm1, dim3((N + 63) / 64), dim3(256), 0, stream, x, w1p, h0bf, N);
  hipLaunchKernelGGL(k_spmm1, dim3(N / 4), dim3(256), 0, stream, ip, ec, ewp, h0bf, b1, hbf);
  hipLaunchKernelGGL(k_gemm2, dim3(N / 8), dim3(320), 0, stream, hbf, W2, h2bf);
  hipLaunchKernelGGL(k_spmm2lsm, dim3(N / 4), dim3(256), 0, stream, ip, ec, ewp, h2bf, b2, out);
}

// Round 6
// 426.410 us; speedup vs baseline: 1.7394x; 1.2717x over previous
//
#include <hip/hip_runtime.h>
#include <math.h>

#define F1 256
#define F2 128
#define F3 40
#define H2S 64   // padded h2 row stride (one 128B cacheline)

typedef unsigned short ushort_t;
typedef __attribute__((ext_vector_type(8))) short bf16x8;
typedef __attribute__((ext_vector_type(4))) float f32x4;

__device__ inline ushort_t f2bf(float f) {
  unsigned u = __builtin_bit_cast(unsigned, f);
  u += 0x7FFF + ((u >> 16) & 1);
  return (ushort_t)(u >> 16);
}
__device__ inline float bf2f(ushort_t b) {
  unsigned u = ((unsigned)b) << 16;
  return __builtin_bit_cast(float, u);
}
__device__ inline float i2f(int b) { return __builtin_bit_cast(float, b); }

// ---------------- CSR build ----------------
__global__ __launch_bounds__(256) void k_zero(int* __restrict__ p, int n) {
  int i = blockIdx.x * 256 + threadIdx.x;
  if (i < n) p[i] = 0;
}

__global__ __launch_bounds__(256) void k_hist(const int* __restrict__ row, int* __restrict__ deg, int E) {
  int e = blockIdx.x * 256 + threadIdx.x;
  if (e < E) atomicAdd(&deg[row[e]], 1);
}

__global__ __launch_bounds__(256) void k_scan1(const int* __restrict__ in, int* __restrict__ out,
                                               int* __restrict__ aux, int n) {
  __shared__ int lds[256];
  int tid = threadIdx.x;
  int base = blockIdx.x * 1024 + tid * 4;
  int v0 = 0, v1 = 0, v2 = 0, v3 = 0;
  if (base + 0 < n) v0 = in[base + 0];
  if (base + 1 < n) v1 = in[base + 1];
  if (base + 2 < n) v2 = in[base + 2];
  if (base + 3 < n) v3 = in[base + 3];
  int s = v0 + v1 + v2 + v3;
  lds[tid] = s;
  __syncthreads();
  for (int off = 1; off < 256; off <<= 1) {
    int t = (tid >= off) ? lds[tid - off] : 0;
    __syncthreads();
    lds[tid] += t;
    __syncthreads();
  }
  int excl = (tid > 0) ? lds[tid - 1] : 0;
  if (tid == 255) aux[blockIdx.x] = lds[255];
  if (base + 0 < n) out[base + 0] = excl;
  if (base + 1 < n) out[base + 1] = excl + v0;
  if (base + 2 < n) out[base + 2] = excl + v0 + v1;
  if (base + 3 < n) out[base + 3] = excl + v0 + v1 + v2;
}

__global__ __launch_bounds__(128) void k_scan_aux(int* __restrict__ aux, int nb) {
  __shared__ int lds[128];
  int tid = threadIdx.x;
  int v = (tid < nb) ? aux[tid] : 0;
  lds[tid] = v;
  __syncthreads();
  for (int off = 1; off < 128; off <<= 1) {
    int t = (tid >= off) ? lds[tid - off] : 0;
    __syncthreads();
    lds[tid] += t;
    __syncthreads();
  }
  int excl = (tid > 0) ? lds[tid - 1] : 0;
  if (tid < nb) aux[tid] = excl;
}

__global__ __launch_bounds__(256) void k_scan_add(int* __restrict__ out, const int* __restrict__ aux,
                                                  int n, int E) {
  int add = aux[blockIdx.x];
  int base = blockIdx.x * 1024 + threadIdx.x * 4;
#pragma unroll
  for (int i = 0; i < 4; i++)
    if (base + i < n) out[base + i] += add;
  if (blockIdx.x == 0 && threadIdx.x == 0) out[n] = E;
}

// scatter packed edge records: {col, weight_bits}
__global__ __launch_bounds__(256) void k_scatter(const int* __restrict__ row, const int* __restrict__ col,
                                                 const float* __restrict__ w, const int* __restrict__ ip,
                                                 int* __restrict__ cur, int2* __restrict__ epk, int E) {
  int e = blockIdx.x * 256 + threadIdx.x;
  if (e < E) {
    int r = row[e];
    int pos = ip[r] + atomicAdd(&cur[r], 1);
    epk[pos] = make_int2(col[e], __builtin_bit_cast(int, w[e]));
  }
}

// ---------------- W1 prep: fp32 [256][128] -> bf16 [8 kt][128 col][40 k-pad] ----------------
// writes ALL 40960 slots (k-pad slots 32..39 zeroed) so nothing is read-before-write
__global__ __launch_bounds__(256) void k_w1prep(const float* __restrict__ W1, ushort_t* __restrict__ w1p) {
  int t = blockIdx.x * 256 + threadIdx.x;
  if (t < 8 * 128 * 40) {
    int kk = t % 40;
    int rem = t / 40;
    int c = rem & 127;
    int kt = rem >> 7;
    w1p[t] = (kk < 32) ? f2bf(W1[(size_t)(kt * 32 + kk) * F2 + c]) : (ushort_t)0;
  }
}

// ---------------- GEMM1 (MFMA): h0[N,128] = x[N,256] @ W1, store bf16 ----------------
#define XPAD 264
__global__ __launch_bounds__(256) void k_gemm1(const float* __restrict__ x, const ushort_t* __restrict__ w1p,
                                               ushort_t* __restrict__ h0bf, int N) {
  __shared__ ushort_t xs[64 * XPAD];
  __shared__ ushort_t wb[2][128 * 40];
  const int tid = threadIdx.x;
  const int lane = tid & 63;
  const int w = tid >> 6;
  const int r0 = blockIdx.x * 64;

#pragma unroll 4
  for (int i = 0; i < 16; ++i) {
    int row = w * 16 + i;
    int gr = r0 + row;
    if (gr >= N) gr = 0;
    float4 v = ((const float4*)(x + (size_t)gr * F1))[lane];
    ushort_t* d = &xs[row * XPAD + lane * 4];
    d[0] = f2bf(v.x); d[1] = f2bf(v.y); d[2] = f2bf(v.z); d[3] = f2bf(v.w);
  }
  {
    const uint4* src = (const uint4*)w1p;
    uint4* dst = (uint4*)&wb[0][0];
    for (int o = tid; o < 640; o += 256) dst[o] = src[o];
  }
  __syncthreads();

  f32x4 acc[8];
#pragma unroll
  for (int t = 0; t < 8; ++t) acc[t] = (f32x4){0.f, 0.f, 0.f, 0.f};

  const int arow = w * 16 + (lane & 15);
  const int kg = (lane >> 4) * 8;

  for (int kt = 0; kt < 8; ++kt) {
    if (kt < 7) {
      const uint4* src = (const uint4*)(w1p + (size_t)(kt + 1) * 128 * 40);
      uint4* dst = (uint4*)&wb[(kt + 1) & 1][0];
      for (int o = tid; o < 640; o += 256) dst[o] = src[o];
    }
    bf16x8 a = *(const bf16x8*)&xs[arow * XPAD + kt * 32 + kg];
    const ushort_t* wbb = &wb[kt & 1][0];
#pragma unroll
    for (int t = 0; t < 8; ++t) {
      bf16x8 b = *(const bf16x8*)&wbb[(t * 16 + (lane & 15)) * 40 + kg];
      acc[t] = __builtin_amdgcn_mfma_f32_16x16x32_bf16(a, b, acc[t], 0, 0, 0);
    }
    __syncthreads();
  }

#pragma unroll
  for (int t = 0; t < 8; ++t) {
    int gc = t * 16 + (lane & 15);
#pragma unroll
    for (int j = 0; j < 4; ++j) {
      int gr = r0 + w * 16 + (lane >> 4) * 4 + j;
      if (gr < N) h0bf[(size_t)gr * F2 + gc] = f2bf(acc[t][j]);
    }
  }
}

// ---------------- SpMM1 (F=128, bf16 gather) + b1 + relu: wave per node, unroll4 ----------------
__global__ __launch_bounds__(256) void k_spmm1(const int* __restrict__ ip, const int2* __restrict__ epk,
                                               const ushort_t* __restrict__ h0bf,
                                               const float* __restrict__ b1, ushort_t* __restrict__ hbf) {
  int node = blockIdx.x * 4 + (threadIdx.x >> 6);
  int lane = threadIdx.x & 63;
  int e0 = __builtin_amdgcn_readfirstlane(ip[node]);
  int e1 = __builtin_amdgcn_readfirstlane(ip[node + 1]);
  float ax0 = 0.f, ay0 = 0.f, ax1 = 0.f, ay1 = 0.f;
  float ax2 = 0.f, ay2 = 0.f, ax3 = 0.f, ay3 = 0.f;
  int e = e0;
  for (; e + 4 <= e1; e += 4) {
    int2 p0 = epk[e], p1 = epk[e + 1], p2 = epk[e + 2], p3 = epk[e + 3];
    ushort2 v0 = *(const ushort2*)(h0bf + (size_t)p0.x * F2 + lane * 2);
    ushort2 v1 = *(const ushort2*)(h0bf + (size_t)p1.x * F2 + lane * 2);
    ushort2 v2 = *(const ushort2*)(h0bf + (size_t)p2.x * F2 + lane * 2);
    ushort2 v3 = *(const ushort2*)(h0bf + (size_t)p3.x * F2 + lane * 2);
    float w0 = i2f(p0.y), w1 = i2f(p1.y), w2 = i2f(p2.y), w3 = i2f(p3.y);
    ax0 = fmaf(w0, bf2f(v0.x), ax0); ay0 = fmaf(w0, bf2f(v0.y), ay0);
    ax1 = fmaf(w1, bf2f(v1.x), ax1); ay1 = fmaf(w1, bf2f(v1.y), ay1);
    ax2 = fmaf(w2, bf2f(v2.x), ax2); ay2 = fmaf(w2, bf2f(v2.y), ay2);
    ax3 = fmaf(w3, bf2f(v3.x), ax3); ay3 = fmaf(w3, bf2f(v3.y), ay3);
  }
  for (; e < e1; ++e) {
    int2 p = epk[e];
    ushort2 v = *(const ushort2*)(h0bf + (size_t)p.x * F2 + lane * 2);
    float wt = i2f(p.y);
    ax0 = fmaf(wt, bf2f(v.x), ax0); ay0 = fmaf(wt, bf2f(v.y), ay0);
  }
  float ax = (ax0 + ax1) + (ax2 + ax3);
  float ay = (ay0 + ay1) + (ay2 + ay3);
  float2 bb = *(const float2*)(b1 + lane * 2);
  ushort2 r;
  r.x = f2bf(fmaxf(ax + bb.x, 0.f));
  r.y = f2bf(fmaxf(ay + bb.y, 0.f));
  *(ushort2*)(hbf + (size_t)node * F2 + lane * 2) = r;
}

// ---------------- GEMM2: h2p[N,64pad] = h[N,128] @ W2[128,40], bf16 in/out ----------------
__global__ __launch_bounds__(320) void k_gemm2(const ushort_t* __restrict__ hbf, const float* __restrict__ W2,
                                               ushort_t* __restrict__ h2p) {
  __shared__ float w2s[F2 * F3];
  __shared__ float hs[8 * F2];
  int tid = threadIdx.x;
  for (int i = tid; i < F2 * F3; i += 320) w2s[i] = W2[i];
  if (tid < 128) {
    uint4 v = ((const uint4*)hbf)[(size_t)blockIdx.x * 128 + tid];
    float* d = &hs[tid * 8];
    unsigned a0 = v.x, a1 = v.y, a2 = v.z, a3 = v.w;
    d[0] = bf2f((ushort_t)(a0 & 0xffff)); d[1] = bf2f((ushort_t)(a0 >> 16));
    d[2] = bf2f((ushort_t)(a1 & 0xffff)); d[3] = bf2f((ushort_t)(a1 >> 16));
    d[4] = bf2f((ushort_t)(a2 & 0xffff)); d[5] = bf2f((ushort_t)(a2 >> 16));
    d[6] = bf2f((ushort_t)(a3 & 0xffff)); d[7] = bf2f((ushort_t)(a3 >> 16));
  }
  // zero the pad columns (40..63) of this block's 8 rows
  if (tid < 192) {
    int nl = tid / 24, pc = 40 + tid % 24;
    h2p[(size_t)(blockIdx.x * 8 + nl) * H2S + pc] = 0;
  }
  __syncthreads();
  int nl = tid / 40, c = tid % 40;
  const float* hr = &hs[nl * F2];
  float acc = 0.f;
#pragma unroll
  for (int k = 0; k < F2; k += 4) {
    acc = fmaf(hr[k + 0], w2s[(k + 0) * F3 + c], acc);
    acc = fmaf(hr[k + 1], w2s[(k + 1) * F3 + c], acc);
    acc = fmaf(hr[k + 2], w2s[(k + 2) * F3 + c], acc);
    acc = fmaf(hr[k + 3], w2s[(k + 3) * F3 + c], acc);
  }
  h2p[(size_t)(blockIdx.x * 8 + nl) * H2S + c] = f2bf(acc);
}

// ---------------- SpMM2 (padded rows) + b2 + log_softmax fused, unroll4 ----------------
__global__ __launch_bounds__(256) void k_spmm2lsm(const int* __restrict__ ip, const int2* __restrict__ epk,
                                                  const ushort_t* __restrict__ h2p,
                                                  const float* __restrict__ b2, float* __restrict__ out) {
  int node = blockIdx.x * 4 + (threadIdx.x >> 6);
  int lane = threadIdx.x & 63;
  int e0 = __builtin_amdgcn_readfirstlane(ip[node]);
  int e1 = __builtin_amdgcn_readfirstlane(ip[node + 1]);
  float a0 = 0.f, a1 = 0.f, a2 = 0.f, a3 = 0.f;
  int e = e0;
  for (; e + 4 <= e1; e += 4) {
    int2 p0 = epk[e], p1 = epk[e + 1], p2 = epk[e + 2], p3 = epk[e + 3];
    float v0 = bf2f(h2p[(size_t)p0.x * H2S + lane]);
    float v1 = bf2f(h2p[(size_t)p1.x * H2S + lane]);
    float v2 = bf2f(h2p[(size_t)p2.x * H2S + lane]);
    float v3 = bf2f(h2p[(size_t)p3.x * H2S + lane]);
    a0 = fmaf(i2f(p0.y), v0, a0);
    a1 = fmaf(i2f(p1.y), v1, a1);
    a2 = fmaf(i2f(p2.y), v2, a2);
    a3 = fmaf(i2f(p3.y), v3, a3);
  }
  for (; e < e1; ++e) {
    int2 p = epk[e];
    float v = bf2f(h2p[(size_t)p.x * H2S + lane]);
    a0 = fmaf(i2f(p.y), v, a0);
  }
  float acc = (a0 + a1) + (a2 + a3);
  float logit = (lane < F3) ? (acc + b2[lane]) : -INFINITY;
  float m = logit;
#pragma unroll
  for (int off = 32; off > 0; off >>= 1) m = fmaxf(m, __shfl_xor(m, off));
  float ex = (lane < F3) ? __expf(logit - m) : 0.f;
  float s = ex;
#pragma unroll
  for (int off = 32; off > 0; off >>= 1) s += __shfl_xor(s, off);
  if (lane < F3) out[(size_t)node * F3 + lane] = logit - m - __logf(s);
}

extern "C" void kernel_launch(void* const* d_in, const int* in_sizes, int n_in,
                              void* d_out, int out_size, void* d_ws, size_t ws_size,
                              hipStream_t stream) {
  const float* x     = (const float*)d_in[0];
  const int* erow    = (const int*)d_in[1];
  const int* ecol_in = (const int*)d_in[2];
  const float* ew_in = (const float*)d_in[3];
  const float* W1    = (const float*)d_in[4];
  const float* b1    = (const float*)d_in[5];
  const float* W2    = (const float*)d_in[6];
  const float* b2    = (const float*)d_in[7];
  float* out = (float*)d_out;

  const int N = in_sizes[0] / F1;  // 100000
  const int E = in_sizes[1];       // 1600000

  // ws layout (65.3 MB total — below the round-4-proven 73.4 MB):
  //   h0bf[N*128] (h2p[N*64] aliases this region: h0bf dead after spmm1, gemm2 runs later)
  //   hbf[N*128] | ip/deg/cur/aux ints | epk[E] int2 | w1p[8*128*40] u16
  ushort_t* h0bf = (ushort_t*)d_ws;
  ushort_t* h2p  = h0bf;                      // alias: h0bf no longer needed when gemm2 writes
  ushort_t* hbf  = h0bf + (size_t)N * F2;
  int* ip   = (int*)(hbf + (size_t)N * F2);
  int* deg  = ip + (N + 32);
  int* cur  = deg + N;
  int* aux  = cur + N;
  int2* epk = (int2*)(aux + 128);
  ushort_t* w1p = (ushort_t*)(epk + E);       // 40960 ushorts

  const int nb = (N + 1023) / 1024;

  hipLaunchKernelGGL(k_zero, dim3((2 * N + 255) / 256), dim3(256), 0, stream, deg, 2 * N);
  hipLaunchKernelGGL(k_hist, dim3((E + 255) / 256), dim3(256), 0, stream, erow, deg, E);
  hipLaunchKernelGGL(k_scan1, dim3(nb), dim3(256), 0, stream, deg, ip, aux, N);
  hipLaunchKernelGGL(k_scan_aux, dim3(1), dim3(128), 0, stream, aux, nb);
  hipLaunchKernelGGL(k_scan_add, dim3(nb), dim3(256), 0, stream, ip, aux, N, E);
  hipLaunchKernelGGL(k_scatter, dim3((E + 255) / 256), dim3(256), 0, stream,
                     erow, ecol_in, ew_in, ip, cur, epk, E);
  hipLaunchKernelGGL(k_w1prep, dim3((8 * 128 * 40 + 255) / 256), dim3(256), 0, stream, W1, w1p);
  hipLaunchKernelGGL(k_gemm1, dim3((N + 63) / 64), dim3(256), 0, stream, x, w1p, h0bf, N);
  hipLaunchKernelGGL(k_spmm1, dim3(N / 4), dim3(256), 0, stream, ip, epk, h0bf, b1, hbf);
  hipLaunchKernelGGL(k_gemm2, dim3(N / 8), dim3(320), 0, stream, hbf, W2, h2p);
  hipLaunchKernelGGL(k_spmm2lsm, dim3(N / 4), dim3(256), 0, stream, ip, epk, h2p, b2, out);
}

// Round 7
// 307.093 us; speedup vs baseline: 2.4152x; 1.3885x over previous
//
#include <hip/hip_runtime.h>
#include <math.h>

#define F1 256
#define F2 128
#define F3 40
#define H2S 64    // padded h2 row stride (one 128B cacheline)
#define RPB 256   // rows per bin (counting-sort granularity)
#define RSH 8
#define TPB 8192  // edges per block in cnt/scatter1 passes

typedef unsigned short ushort_t;
typedef __attribute__((ext_vector_type(8))) short bf16x8;
typedef __attribute__((ext_vector_type(4))) float f32x4;

__device__ inline ushort_t f2bf(float f) {
  unsigned u = __builtin_bit_cast(unsigned, f);
  u += 0x7FFF + ((u >> 16) & 1);
  return (ushort_t)(u >> 16);
}
__device__ inline float bf2f(ushort_t b) {
  unsigned u = ((unsigned)b) << 16;
  return __builtin_bit_cast(float, u);
}
__device__ inline float i2f(int b) { return __builtin_bit_cast(float, b); }

// ---------------- CSR build: 2-level counting sort (XCD-write-amplification-free) ----------------

// pass 1: per-(block tile) coarse-bin histogram -> cnt[bin*G + blk]
__global__ __launch_bounds__(256) void k_cnt(const int* __restrict__ row, int* __restrict__ cnt,
                                             int E, int G, int NBIN) {
  __shared__ int h[400];
  int tid = threadIdx.x, blk = blockIdx.x;
  for (int i = tid; i < NBIN; i += 256) h[i] = 0;
  __syncthreads();
  int base = blk * TPB, lim = min(base + TPB, E);
  for (int i = base + tid; i < lim; i += 256) atomicAdd(&h[row[i] >> RSH], 1);
  __syncthreads();
  for (int i = tid; i < NBIN; i += 256) cnt[i * G + blk] = h[i];
}

// exclusive scan, chunk = 1024 elements (256 thr x 4)
__global__ __launch_bounds__(256) void k_scan1(const int* __restrict__ in, int* __restrict__ out,
                                               int* __restrict__ aux, int n) {
  __shared__ int lds[256];
  int tid = threadIdx.x;
  int base = blockIdx.x * 1024 + tid * 4;
  int v0 = 0, v1 = 0, v2 = 0, v3 = 0;
  if (base + 0 < n) v0 = in[base + 0];
  if (base + 1 < n) v1 = in[base + 1];
  if (base + 2 < n) v2 = in[base + 2];
  if (base + 3 < n) v3 = in[base + 3];
  int s = v0 + v1 + v2 + v3;
  lds[tid] = s;
  __syncthreads();
  for (int off = 1; off < 256; off <<= 1) {
    int t = (tid >= off) ? lds[tid - off] : 0;
    __syncthreads();
    lds[tid] += t;
    __syncthreads();
  }
  int excl = (tid > 0) ? lds[tid - 1] : 0;
  if (tid == 255) aux[blockIdx.x] = lds[255];
  if (base + 0 < n) out[base + 0] = excl;
  if (base + 1 < n) out[base + 1] = excl + v0;
  if (base + 2 < n) out[base + 2] = excl + v0 + v1;
  if (base + 3 < n) out[base + 3] = excl + v0 + v1 + v2;
}

__global__ __launch_bounds__(128) void k_scan_aux(int* __restrict__ aux, int nb) {
  __shared__ int lds[128];
  int tid = threadIdx.x;
  int v = (tid < nb) ? aux[tid] : 0;
  lds[tid] = v;
  __syncthreads();
  for (int off = 1; off < 128; off <<= 1) {
    int t = (tid >= off) ? lds[tid - off] : 0;
    __syncthreads();
    lds[tid] += t;
    __syncthreads();
  }
  int excl = (tid > 0) ? lds[tid - 1] : 0;
  if (tid < nb) aux[tid] = excl;
}

__global__ __launch_bounds__(256) void k_scan_add(int* __restrict__ out, const int* __restrict__ aux,
                                                  int n, int E) {
  int add = aux[blockIdx.x];
  int base = blockIdx.x * 1024 + threadIdx.x * 4;
#pragma unroll
  for (int i = 0; i < 4; i++)
    if (base + i < n) out[base + i] += add;
  if (blockIdx.x == 0 && threadIdx.x == 0) out[n] = E;  // sentinel: cntoff[M] = E
}

// pass 2: coarse scatter via LDS cursors; each (block,bin) writes a private contiguous run.
// record packs ((row & 255) << 17) | col  (col < 2^17), plus weight bits.
__global__ __launch_bounds__(256) void k_scatter1(const int* __restrict__ row, const int* __restrict__ col,
                                                  const float* __restrict__ w, const int* __restrict__ cntoff,
                                                  int2* __restrict__ epk2, int E, int G, int NBIN) {
  __shared__ int cur[400];
  int tid = threadIdx.x, blk = blockIdx.x;
  for (int i = tid; i < NBIN; i += 256) cur[i] = cntoff[i * G + blk];
  __syncthreads();
  int base = blk * TPB, lim = min(base + TPB, E);
  for (int i = base + tid; i < lim; i += 256) {
    int r = row[i];
    int pos = atomicAdd(&cur[r >> RSH], 1);
    epk2[pos] = make_int2(((r & (RPB - 1)) << 17) | col[i], __builtin_bit_cast(int, w[i]));
  }
}

// pass 3: per-bin exact sort to row order; derives ip[] for free; all writes block-private.
__global__ __launch_bounds__(256) void k_binsort(const int* __restrict__ cntoff, const int2* __restrict__ epk2,
                                                 int* __restrict__ ip, int2* __restrict__ epk,
                                                 int G, int NBIN, int N, int E) {
  __shared__ int sc[256], cur[256];
  int tid = threadIdx.x, b = blockIdx.x;
  int s = cntoff[b * G], eend = cntoff[(b + 1) * G];
  cur[tid] = 0;
  __syncthreads();
  for (int i = s + tid; i < eend; i += 256) atomicAdd(&cur[epk2[i].x >> 17], 1);
  __syncthreads();
  int d = cur[tid];
  sc[tid] = d;
  __syncthreads();
  for (int o = 1; o < 256; o <<= 1) {
    int t = (tid >= o) ? sc[tid - o] : 0;
    __syncthreads();
    sc[tid] += t;
    __syncthreads();
  }
  int excl = (tid > 0) ? sc[tid - 1] : 0;
  __syncthreads();
  cur[tid] = excl;
  int gr = (b << RSH) + tid;
  if (gr <= N) ip[gr] = s + excl;          // gr==N (last partial bin): excl == bin total -> ip[N]=E
  if (b == 0 && tid == 0) ip[N] = E;       // generality guard; same value, benign
  __syncthreads();
  for (int i = s + tid; i < eend; i += 256) {
    int2 rec = epk2[i];
    int local = rec.x >> 17, c = rec.x & 0x1FFFF;
    int p = s + atomicAdd(&cur[local], 1);
    epk[p] = make_int2(c, rec.y);
  }
}

// ---------------- W1 prep: fp32 [256][128] -> bf16 [8 kt][128 col][40 k-pad] ----------------
__global__ __launch_bounds__(256) void k_w1prep(const float* __restrict__ W1, ushort_t* __restrict__ w1p) {
  int t = blockIdx.x * 256 + threadIdx.x;
  if (t < 8 * 128 * 40) {
    int kk = t % 40;
    int rem = t / 40;
    int c = rem & 127;
    int kt = rem >> 7;
    w1p[t] = (kk < 32) ? f2bf(W1[(size_t)(kt * 32 + kk) * F2 + c]) : (ushort_t)0;
  }
}

// ---------------- GEMM1 (MFMA): h0[N,128] = x[N,256] @ W1, store bf16 ----------------
#define XPAD 264
__global__ __launch_bounds__(256) void k_gemm1(const float* __restrict__ x, const ushort_t* __restrict__ w1p,
                                               ushort_t* __restrict__ h0bf, int N) {
  __shared__ ushort_t xs[64 * XPAD];
  __shared__ ushort_t wb[2][128 * 40];
  const int tid = threadIdx.x;
  const int lane = tid & 63;
  const int w = tid >> 6;
  const int r0 = blockIdx.x * 64;

#pragma unroll 4
  for (int i = 0; i < 16; ++i) {
    int row = w * 16 + i;
    int gr = r0 + row;
    if (gr >= N) gr = 0;
    float4 v = ((const float4*)(x + (size_t)gr * F1))[lane];
    ushort_t* d = &xs[row * XPAD + lane * 4];
    d[0] = f2bf(v.x); d[1] = f2bf(v.y); d[2] = f2bf(v.z); d[3] = f2bf(v.w);
  }
  {
    const uint4* src = (const uint4*)w1p;
    uint4* dst = (uint4*)&wb[0][0];
    for (int o = tid; o < 640; o += 256) dst[o] = src[o];
  }
  __syncthreads();

  f32x4 acc[8];
#pragma unroll
  for (int t = 0; t < 8; ++t) acc[t] = (f32x4){0.f, 0.f, 0.f, 0.f};

  const int arow = w * 16 + (lane & 15);
  const int kg = (lane >> 4) * 8;

  for (int kt = 0; kt < 8; ++kt) {
    if (kt < 7) {
      const uint4* src = (const uint4*)(w1p + (size_t)(kt + 1) * 128 * 40);
      uint4* dst = (uint4*)&wb[(kt + 1) & 1][0];
      for (int o = tid; o < 640; o += 256) dst[o] = src[o];
    }
    bf16x8 a = *(const bf16x8*)&xs[arow * XPAD + kt * 32 + kg];
    const ushort_t* wbb = &wb[kt & 1][0];
#pragma unroll
    for (int t = 0; t < 8; ++t) {
      bf16x8 bfr = *(const bf16x8*)&wbb[(t * 16 + (lane & 15)) * 40 + kg];
      acc[t] = __builtin_amdgcn_mfma_f32_16x16x32_bf16(a, bfr, acc[t], 0, 0, 0);
    }
    __syncthreads();
  }

#pragma unroll
  for (int t = 0; t < 8; ++t) {
    int gc = t * 16 + (lane & 15);
#pragma unroll
    for (int j = 0; j < 4; ++j) {
      int gr = r0 + w * 16 + (lane >> 4) * 4 + j;
      if (gr < N) h0bf[(size_t)gr * F2 + gc] = f2bf(acc[t][j]);
    }
  }
}

// ---------------- SpMM1 (F=128, bf16 gather) + b1 + relu: wave per node, unroll4 ----------------
__global__ __launch_bounds__(256) void k_spmm1(const int* __restrict__ ip, const int2* __restrict__ epk,
                                               const ushort_t* __restrict__ h0bf,
                                               const float* __restrict__ b1, ushort_t* __restrict__ hbf) {
  int node = blockIdx.x * 4 + (threadIdx.x >> 6);
  int lane = threadIdx.x & 63;
  int e0 = __builtin_amdgcn_readfirstlane(ip[node]);
  int e1 = __builtin_amdgcn_readfirstlane(ip[node + 1]);
  float ax0 = 0.f, ay0 = 0.f, ax1 = 0.f, ay1 = 0.f;
  float ax2 = 0.f, ay2 = 0.f, ax3 = 0.f, ay3 = 0.f;
  int e = e0;
  for (; e + 4 <= e1; e += 4) {
    int2 p0 = epk[e], p1 = epk[e + 1], p2 = epk[e + 2], p3 = epk[e + 3];
    ushort2 v0 = *(const ushort2*)(h0bf + (size_t)p0.x * F2 + lane * 2);
    ushort2 v1 = *(const ushort2*)(h0bf + (size_t)p1.x * F2 + lane * 2);
    ushort2 v2 = *(const ushort2*)(h0bf + (size_t)p2.x * F2 + lane * 2);
    ushort2 v3 = *(const ushort2*)(h0bf + (size_t)p3.x * F2 + lane * 2);
    float w0 = i2f(p0.y), w1 = i2f(p1.y), w2 = i2f(p2.y), w3 = i2f(p3.y);
    ax0 = fmaf(w0, bf2f(v0.x), ax0); ay0 = fmaf(w0, bf2f(v0.y), ay0);
    ax1 = fmaf(w1, bf2f(v1.x), ax1); ay1 = fmaf(w1, bf2f(v1.y), ay1);
    ax2 = fmaf(w2, bf2f(v2.x), ax2); ay2 = fmaf(w2, bf2f(v2.y), ay2);
    ax3 = fmaf(w3, bf2f(v3.x), ax3); ay3 = fmaf(w3, bf2f(v3.y), ay3);
  }
  for (; e < e1; ++e) {
    int2 p = epk[e];
    ushort2 v = *(const ushort2*)(h0bf + (size_t)p.x * F2 + lane * 2);
    float wt = i2f(p.y);
    ax0 = fmaf(wt, bf2f(v.x), ax0); ay0 = fmaf(wt, bf2f(v.y), ay0);
  }
  float ax = (ax0 + ax1) + (ax2 + ax3);
  float ay = (ay0 + ay1) + (ay2 + ay3);
  float2 bb = *(const float2*)(b1 + lane * 2);
  ushort2 r;
  r.x = f2bf(fmaxf(ax + bb.x, 0.f));
  r.y = f2bf(fmaxf(ay + bb.y, 0.f));
  *(ushort2*)(hbf + (size_t)node * F2 + lane * 2) = r;
}

// ---------------- GEMM2: h2p[N,64pad] = h[N,128] @ W2[128,40], bf16 in/out ----------------
__global__ __launch_bounds__(320) void k_gemm2(const ushort_t* __restrict__ hbf, const float* __restrict__ W2,
                                               ushort_t* __restrict__ h2p) {
  __shared__ float w2s[F2 * F3];
  __shared__ float hs[8 * F2];
  int tid = threadIdx.x;
  for (int i = tid; i < F2 * F3; i += 320) w2s[i] = W2[i];
  if (tid < 128) {
    uint4 v = ((const uint4*)hbf)[(size_t)blockIdx.x * 128 + tid];
    float* d = &hs[tid * 8];
    unsigned a0 = v.x, a1 = v.y, a2 = v.z, a3 = v.w;
    d[0] = bf2f((ushort_t)(a0 & 0xffff)); d[1] = bf2f((ushort_t)(a0 >> 16));
    d[2] = bf2f((ushort_t)(a1 & 0xffff)); d[3] = bf2f((ushort_t)(a1 >> 16));
    d[4] = bf2f((ushort_t)(a2 & 0xffff)); d[5] = bf2f((ushort_t)(a2 >> 16));
    d[6] = bf2f((ushort_t)(a3 & 0xffff)); d[7] = bf2f((ushort_t)(a3 >> 16));
  }
  if (tid < 192) {
    int nl = tid / 24, pc = 40 + tid % 24;
    h2p[(size_t)(blockIdx.x * 8 + nl) * H2S + pc] = 0;
  }
  __syncthreads();
  int nl = tid / 40, c = tid % 40;
  const float* hr = &hs[nl * F2];
  float acc = 0.f;
#pragma unroll
  for (int k = 0; k < F2; k += 4) {
    acc = fmaf(hr[k + 0], w2s[(k + 0) * F3 + c], acc);
    acc = fmaf(hr[k + 1], w2s[(k + 1) * F3 + c], acc);
    acc = fmaf(hr[k + 2], w2s[(k + 2) * F3 + c], acc);
    acc = fmaf(hr[k + 3], w2s[(k + 3) * F3 + c], acc);
  }
  h2p[(size_t)(blockIdx.x * 8 + nl) * H2S + c] = f2bf(acc);
}

// ---------------- SpMM2 (padded rows) + b2 + log_softmax fused, unroll4 ----------------
__global__ __launch_bounds__(256) void k_spmm2lsm(const int* __restrict__ ip, const int2* __restrict__ epk,
                                                  const ushort_t* __restrict__ h2p,
                                                  const float* __restrict__ b2, float* __restrict__ out) {
  int node = blockIdx.x * 4 + (threadIdx.x >> 6);
  int lane = threadIdx.x & 63;
  int e0 = __builtin_amdgcn_readfirstlane(ip[node]);
  int e1 = __builtin_amdgcn_readfirstlane(ip[node + 1]);
  float a0 = 0.f, a1 = 0.f, a2 = 0.f, a3 = 0.f;
  int e = e0;
  for (; e + 4 <= e1; e += 4) {
    int2 p0 = epk[e], p1 = epk[e + 1], p2 = epk[e + 2], p3 = epk[e + 3];
    float v0 = bf2f(h2p[(size_t)p0.x * H2S + lane]);
    float v1 = bf2f(h2p[(size_t)p1.x * H2S + lane]);
    float v2 = bf2f(h2p[(size_t)p2.x * H2S + lane]);
    float v3 = bf2f(h2p[(size_t)p3.x * H2S + lane]);
    a0 = fmaf(i2f(p0.y), v0, a0);
    a1 = fmaf(i2f(p1.y), v1, a1);
    a2 = fmaf(i2f(p2.y), v2, a2);
    a3 = fmaf(i2f(p3.y), v3, a3);
  }
  for (; e < e1; ++e) {
    int2 p = epk[e];
    float v = bf2f(h2p[(size_t)p.x * H2S + lane]);
    a0 = fmaf(i2f(p.y), v, a0);
  }
  float acc = (a0 + a1) + (a2 + a3);
  float logit = (lane < F3) ? (acc + b2[lane]) : -INFINITY;
  float m = logit;
#pragma unroll
  for (int off = 32; off > 0; off >>= 1) m = fmaxf(m, __shfl_xor(m, off));
  float ex = (lane < F3) ? __expf(logit - m) : 0.f;
  float s = ex;
#pragma unroll
  for (int off = 32; off > 0; off >>= 1) s += __shfl_xor(s, off);
  if (lane < F3) out[(size_t)node * F3 + lane] = logit - m - __logf(s);
}

extern "C" void kernel_launch(void* const* d_in, const int* in_sizes, int n_in,
                              void* d_out, int out_size, void* d_ws, size_t ws_size,
                              hipStream_t stream) {
  const float* x     = (const float*)d_in[0];
  const int* erow    = (const int*)d_in[1];
  const int* ecol_in = (const int*)d_in[2];
  const float* ew_in = (const float*)d_in[3];
  const float* W1    = (const float*)d_in[4];
  const float* b1    = (const float*)d_in[5];
  const float* W2    = (const float*)d_in[6];
  const float* b2    = (const float*)d_in[7];
  float* out = (float*)d_out;

  const int N = in_sizes[0] / F1;  // 100000
  const int E = in_sizes[1];       // 1600000

  const int G = (E + TPB - 1) / TPB;          // 196
  const int NBIN = (N + RPB - 1) >> RSH;      // 391
  const int M = NBIN * G;                     // 76636
  const int nb2 = (M + 1023) / 1024;          // 75  (<=128 for k_scan_aux)

  // ws layout (~65.1 MB, matches round-6-proven footprint):
  //   region0 [N*128 u16 = 25.6MB]: epk2 (CSR build) -> h0bf (gemm1..spmm1) -> h2p (gemm2..spmm2)
  //   hbf[N*128 u16] | ip[N+32] | cnt[M+8] | cntoff[M+64] | aux[128] | epk[E] int2 | w1p[40960] u16
  ushort_t* h0bf = (ushort_t*)d_ws;
  int2* epk2 = (int2*)d_ws;
  ushort_t* h2p = h0bf;
  ushort_t* hbf = h0bf + (size_t)N * F2;
  int* ip = (int*)(hbf + (size_t)N * F2);
  int* cnt = ip + (N + 32);
  int* cntoff = cnt + M + 8;
  int* aux = cntoff + M + 64;
  int2* epk = (int2*)(aux + 128);
  ushort_t* w1p = (ushort_t*)(epk + E);

  hipLaunchKernelGGL(k_cnt, dim3(G), dim3(256), 0, stream, erow, cnt, E, G, NBIN);
  hipLaunchKernelGGL(k_scan1, dim3(nb2), dim3(256), 0, stream, cnt, cntoff, aux, M);
  hipLaunchKernelGGL(k_scan_aux, dim3(1), dim3(128), 0, stream, aux, nb2);
  hipLaunchKernelGGL(k_scan_add, dim3(nb2), dim3(256), 0, stream, cntoff, aux, M, E);
  hipLaunchKernelGGL(k_scatter1, dim3(G), dim3(256), 0, stream, erow, ecol_in, ew_in, cntoff, epk2, E, G, NBIN);
  hipLaunchKernelGGL(k_binsort, dim3(NBIN), dim3(256), 0, stream, cntoff, epk2, ip, epk, G, NBIN, N, E);
  hipLaunchKernelGGL(k_w1prep, dim3((8 * 128 * 40 + 255) / 256), dim3(256), 0, stream, W1, w1p);
  hipLaunchKernelGGL(k_gemm1, dim3((N + 63) / 64), dim3(256), 0, stream, x, w1p, h0bf, N);
  hipLaunchKernelGGL(k_spmm1, dim3(N / 4), dim3(256), 0, stream, ip, epk, h0bf, b1, hbf);
  hipLaunchKernelGGL(k_gemm2, dim3(N / 8), dim3(320), 0, stream, hbf, W2, h2p);
  hipLaunchKernelGGL(k_spmm2lsm, dim3(N / 4), dim3(256), 0, stream, ip, epk, h2p, b2, out);
}

// Round 8
// 244.526 us; speedup vs baseline: 3.0332x; 1.2559x over previous
//
#include <hip/hip_runtime.h>
#include <math.h>

#define F1 256
#define F2 128
#define F3 40
#define H2S 64    // padded h2 row stride (one 128B cacheline)
#define RPB 256   // rows per bin (counting-sort granularity)
#define RSH 8
#define TPB 8192  // edges per block in cnt/scatter1 passes

typedef unsigned short ushort_t;
typedef __attribute__((ext_vector_type(8))) short bf16x8;
typedef __attribute__((ext_vector_type(4))) float f32x4;

__device__ inline ushort_t f2bf(float f) {
  unsigned u = __builtin_bit_cast(unsigned, f);
  u += 0x7FFF + ((u >> 16) & 1);
  return (ushort_t)(u >> 16);
}
__device__ inline float bf2f(ushort_t b) {
  unsigned u = ((unsigned)b) << 16;
  return __builtin_bit_cast(float, u);
}
__device__ inline float i2f(int b) { return __builtin_bit_cast(float, b); }

// ---------------- CSR build: 2-level counting sort (XCD-write-amplification-free) ----------------

__global__ __launch_bounds__(256) void k_cnt(const int* __restrict__ row, int* __restrict__ cnt,
                                             int E, int G, int NBIN) {
  __shared__ int h[400];
  int tid = threadIdx.x, blk = blockIdx.x;
  for (int i = tid; i < NBIN; i += 256) h[i] = 0;
  __syncthreads();
  int base = blk * TPB, lim = min(base + TPB, E);
  for (int i = base + tid; i < lim; i += 256) atomicAdd(&h[row[i] >> RSH], 1);
  __syncthreads();
  for (int i = tid; i < NBIN; i += 256) cnt[i * G + blk] = h[i];
}

__global__ __launch_bounds__(256) void k_scan1(const int* __restrict__ in, int* __restrict__ out,
                                               int* __restrict__ aux, int n) {
  __shared__ int lds[256];
  int tid = threadIdx.x;
  int base = blockIdx.x * 1024 + tid * 4;
  int v0 = 0, v1 = 0, v2 = 0, v3 = 0;
  if (base + 0 < n) v0 = in[base + 0];
  if (base + 1 < n) v1 = in[base + 1];
  if (base + 2 < n) v2 = in[base + 2];
  if (base + 3 < n) v3 = in[base + 3];
  int s = v0 + v1 + v2 + v3;
  lds[tid] = s;
  __syncthreads();
  for (int off = 1; off < 256; off <<= 1) {
    int t = (tid >= off) ? lds[tid - off] : 0;
    __syncthreads();
    lds[tid] += t;
    __syncthreads();
  }
  int excl = (tid > 0) ? lds[tid - 1] : 0;
  if (tid == 255) aux[blockIdx.x] = lds[255];
  if (base + 0 < n) out[base + 0] = excl;
  if (base + 1 < n) out[base + 1] = excl + v0;
  if (base + 2 < n) out[base + 2] = excl + v0 + v1;
  if (base + 3 < n) out[base + 3] = excl + v0 + v1 + v2;
}

__global__ __launch_bounds__(128) void k_scan_aux(int* __restrict__ aux, int nb) {
  __shared__ int lds[128];
  int tid = threadIdx.x;
  int v = (tid < nb) ? aux[tid] : 0;
  lds[tid] = v;
  __syncthreads();
  for (int off = 1; off < 128; off <<= 1) {
    int t = (tid >= off) ? lds[tid - off] : 0;
    __syncthreads();
    lds[tid] += t;
    __syncthreads();
  }
  int excl = (tid > 0) ? lds[tid - 1] : 0;
  if (tid < nb) aux[tid] = excl;
}

__global__ __launch_bounds__(256) void k_scan_add(int* __restrict__ out, const int* __restrict__ aux,
                                                  int n, int E) {
  int add = aux[blockIdx.x];
  int base = blockIdx.x * 1024 + threadIdx.x * 4;
#pragma unroll
  for (int i = 0; i < 4; i++)
    if (base + i < n) out[base + i] += add;
  if (blockIdx.x == 0 && threadIdx.x == 0) out[n] = E;  // sentinel: cntoff[M] = E
}

__global__ __launch_bounds__(256) void k_scatter1(const int* __restrict__ row, const int* __restrict__ col,
                                                  const float* __restrict__ w, const int* __restrict__ cntoff,
                                                  int2* __restrict__ epk2, int E, int G, int NBIN) {
  __shared__ int cur[400];
  int tid = threadIdx.x, blk = blockIdx.x;
  for (int i = tid; i < NBIN; i += 256) cur[i] = cntoff[i * G + blk];
  __syncthreads();
  int base = blk * TPB, lim = min(base + TPB, E);
  for (int i = base + tid; i < lim; i += 256) {
    int r = row[i];
    int pos = atomicAdd(&cur[r >> RSH], 1);
    epk2[pos] = make_int2(((r & (RPB - 1)) << 17) | col[i], __builtin_bit_cast(int, w[i]));
  }
}

__global__ __launch_bounds__(256) void k_binsort(const int* __restrict__ cntoff, const int2* __restrict__ epk2,
                                                 int* __restrict__ ip, int2* __restrict__ epk,
                                                 int G, int NBIN, int N, int E) {
  __shared__ int sc[256], cur[256];
  int tid = threadIdx.x, b = blockIdx.x;
  int s = cntoff[b * G], eend = cntoff[(b + 1) * G];
  cur[tid] = 0;
  __syncthreads();
  for (int i = s + tid; i < eend; i += 256) atomicAdd(&cur[epk2[i].x >> 17], 1);
  __syncthreads();
  int d = cur[tid];
  sc[tid] = d;
  __syncthreads();
  for (int o = 1; o < 256; o <<= 1) {
    int t = (tid >= o) ? sc[tid - o] : 0;
    __syncthreads();
    sc[tid] += t;
    __syncthreads();
  }
  int excl = (tid > 0) ? sc[tid - 1] : 0;
  __syncthreads();
  cur[tid] = excl;
  int gr = (b << RSH) + tid;
  if (gr <= N) ip[gr] = s + excl;
  if (b == 0 && tid == 0) ip[N] = E;
  __syncthreads();
  for (int i = s + tid; i < eend; i += 256) {
    int2 rec = epk2[i];
    int local = rec.x >> 17, c = rec.x & 0x1FFFF;
    int p = s + atomicAdd(&cur[local], 1);
    epk[p] = make_int2(c, rec.y);
  }
}

// ---------------- W1 prep: fp32 [256][128] -> bf16 [8 kt][128 col][40 k-pad] ----------------
__global__ __launch_bounds__(256) void k_w1prep(const float* __restrict__ W1, ushort_t* __restrict__ w1p) {
  int t = blockIdx.x * 256 + threadIdx.x;
  if (t < 8 * 128 * 40) {
    int kk = t % 40;
    int rem = t / 40;
    int c = rem & 127;
    int kt = rem >> 7;
    w1p[t] = (kk < 32) ? f2bf(W1[(size_t)(kt * 32 + kk) * F2 + c]) : (ushort_t)0;
  }
}

// ---------------- W2 prep: fp32 [128][40] -> per-lane B-fragments [kt 4][t 3][lane 64][8] ----------------
__global__ __launch_bounds__(256) void k_w2prep(const float* __restrict__ W2, ushort_t* __restrict__ w2p) {
  int idx = blockIdx.x * 256 + threadIdx.x;
  if (idx < 4 * 3 * 64 * 8) {
    int j = idx & 7;
    int rem = idx >> 3;
    int l = rem & 63;
    int g = rem >> 6;       // 0..11
    int t = g % 3, kt = g / 3;
    int colc = t * 16 + (l & 15);
    int k = kt * 32 + (l >> 4) * 8 + j;
    w2p[idx] = (colc < F3) ? f2bf(W2[(size_t)k * F3 + colc]) : (ushort_t)0;
  }
}

// ---------------- GEMM1 (MFMA): h0[N,128] = x[N,256] @ W1, store bf16 ----------------
#define XPAD 264
__global__ __launch_bounds__(256) void k_gemm1(const float* __restrict__ x, const ushort_t* __restrict__ w1p,
                                               ushort_t* __restrict__ h0bf, int N) {
  __shared__ ushort_t xs[64 * XPAD];
  __shared__ ushort_t wb[2][128 * 40];
  const int tid = threadIdx.x;
  const int lane = tid & 63;
  const int w = tid >> 6;
  const int r0 = blockIdx.x * 64;

#pragma unroll 4
  for (int i = 0; i < 16; ++i) {
    int row = w * 16 + i;
    int gr = r0 + row;
    if (gr >= N) gr = 0;
    float4 v = ((const float4*)(x + (size_t)gr * F1))[lane];
    ushort_t* d = &xs[row * XPAD + lane * 4];
    d[0] = f2bf(v.x); d[1] = f2bf(v.y); d[2] = f2bf(v.z); d[3] = f2bf(v.w);
  }
  {
    const uint4* src = (const uint4*)w1p;
    uint4* dst = (uint4*)&wb[0][0];
    for (int o = tid; o < 640; o += 256) dst[o] = src[o];
  }
  __syncthreads();

  f32x4 acc[8];
#pragma unroll
  for (int t = 0; t < 8; ++t) acc[t] = (f32x4){0.f, 0.f, 0.f, 0.f};

  const int arow = w * 16 + (lane & 15);
  const int kg = (lane >> 4) * 8;

  for (int kt = 0; kt < 8; ++kt) {
    if (kt < 7) {
      const uint4* src = (const uint4*)(w1p + (size_t)(kt + 1) * 128 * 40);
      uint4* dst = (uint4*)&wb[(kt + 1) & 1][0];
      for (int o = tid; o < 640; o += 256) dst[o] = src[o];
    }
    bf16x8 a = *(const bf16x8*)&xs[arow * XPAD + kt * 32 + kg];
    const ushort_t* wbb = &wb[kt & 1][0];
#pragma unroll
    for (int t = 0; t < 8; ++t) {
      bf16x8 bfr = *(const bf16x8*)&wbb[(t * 16 + (lane & 15)) * 40 + kg];
      acc[t] = __builtin_amdgcn_mfma_f32_16x16x32_bf16(a, bfr, acc[t], 0, 0, 0);
    }
    __syncthreads();
  }

#pragma unroll
  for (int t = 0; t < 8; ++t) {
    int gc = t * 16 + (lane & 15);
#pragma unroll
    for (int j = 0; j < 4; ++j) {
      int gr = r0 + w * 16 + (lane >> 4) * 4 + j;
      if (gr < N) h0bf[(size_t)gr * F2 + gc] = f2bf(acc[t][j]);
    }
  }
}

// ---------------- SpMM1 (F=128, bf16 gather) + b1 + relu: wave per node, unroll4 ----------------
__global__ __launch_bounds__(256) void k_spmm1(const int* __restrict__ ip, const int2* __restrict__ epk,
                                               const ushort_t* __restrict__ h0bf,
                                               const float* __restrict__ b1, ushort_t* __restrict__ hbf) {
  int node = blockIdx.x * 4 + (threadIdx.x >> 6);
  int lane = threadIdx.x & 63;
  int e0 = __builtin_amdgcn_readfirstlane(ip[node]);
  int e1 = __builtin_amdgcn_readfirstlane(ip[node + 1]);
  float ax0 = 0.f, ay0 = 0.f, ax1 = 0.f, ay1 = 0.f;
  float ax2 = 0.f, ay2 = 0.f, ax3 = 0.f, ay3 = 0.f;
  int e = e0;
  for (; e + 4 <= e1; e += 4) {
    int2 p0 = epk[e], p1 = epk[e + 1], p2 = epk[e + 2], p3 = epk[e + 3];
    ushort2 v0 = *(const ushort2*)(h0bf + (size_t)p0.x * F2 + lane * 2);
    ushort2 v1 = *(const ushort2*)(h0bf + (size_t)p1.x * F2 + lane * 2);
    ushort2 v2 = *(const ushort2*)(h0bf + (size_t)p2.x * F2 + lane * 2);
    ushort2 v3 = *(const ushort2*)(h0bf + (size_t)p3.x * F2 + lane * 2);
    float w0 = i2f(p0.y), w1 = i2f(p1.y), w2 = i2f(p2.y), w3 = i2f(p3.y);
    ax0 = fmaf(w0, bf2f(v0.x), ax0); ay0 = fmaf(w0, bf2f(v0.y), ay0);
    ax1 = fmaf(w1, bf2f(v1.x), ax1); ay1 = fmaf(w1, bf2f(v1.y), ay1);
    ax2 = fmaf(w2, bf2f(v2.x), ax2); ay2 = fmaf(w2, bf2f(v2.y), ay2);
    ax3 = fmaf(w3, bf2f(v3.x), ax3); ay3 = fmaf(w3, bf2f(v3.y), ay3);
  }
  for (; e < e1; ++e) {
    int2 p = epk[e];
    ushort2 v = *(const ushort2*)(h0bf + (size_t)p.x * F2 + lane * 2);
    float wt = i2f(p.y);
    ax0 = fmaf(wt, bf2f(v.x), ax0); ay0 = fmaf(wt, bf2f(v.y), ay0);
  }
  float ax = (ax0 + ax1) + (ax2 + ax3);
  float ay = (ay0 + ay1) + (ay2 + ay3);
  float2 bb = *(const float2*)(b1 + lane * 2);
  ushort2 r;
  r.x = f2bf(fmaxf(ax + bb.x, 0.f));
  r.y = f2bf(fmaxf(ay + bb.y, 0.f));
  *(ushort2*)(hbf + (size_t)node * F2 + lane * 2) = r;
}

// ---------------- GEMM2 (MFMA, no LDS): h2p[N,64pad] = h[N,128] @ W2[128,40] ----------------
__global__ __launch_bounds__(256) void k_gemm2(const ushort_t* __restrict__ hbf, const ushort_t* __restrict__ w2p,
                                               ushort_t* __restrict__ h2p, int N) {
  const int tid = threadIdx.x;
  const int lane = tid & 63;
  const int w = tid >> 6;
  const int r0 = blockIdx.x * 64;
  const int arow = r0 + w * 16 + (lane & 15);
  const int ar = (arow < N) ? arow : 0;
  const int kg = (lane >> 4) * 8;

  bf16x8 a[4];
#pragma unroll
  for (int kt = 0; kt < 4; ++kt)
    a[kt] = *(const bf16x8*)(hbf + (size_t)ar * F2 + kt * 32 + kg);

  f32x4 acc[3];
#pragma unroll
  for (int t = 0; t < 3; ++t) acc[t] = (f32x4){0.f, 0.f, 0.f, 0.f};

#pragma unroll
  for (int kt = 0; kt < 4; ++kt) {
#pragma unroll
    for (int t = 0; t < 3; ++t) {
      bf16x8 b = *(const bf16x8*)(w2p + (size_t)(((kt * 3 + t) * 64) + lane) * 8);
      acc[t] = __builtin_amdgcn_mfma_f32_16x16x32_bf16(a[kt], b, acc[t], 0, 0, 0);
    }
  }

  // C/D layout: col = lane&15, row = (lane>>4)*4 + j
#pragma unroll
  for (int t = 0; t < 3; ++t) {
    int gc = t * 16 + (lane & 15);
    if (gc < F3) {
#pragma unroll
      for (int j = 0; j < 4; ++j) {
        int gr = r0 + w * 16 + (lane >> 4) * 4 + j;
        if (gr < N) h2p[(size_t)gr * H2S + gc] = f2bf(acc[t][j]);
      }
    }
  }
  // zero pad cols 40..63 of this block's rows
  for (int idx = tid; idx < 64 * 24; idx += 256) {
    int row = idx / 24, pc = F3 + idx % 24;
    int gr = r0 + row;
    if (gr < N) h2p[(size_t)gr * H2S + pc] = 0;
  }
}

// ---------------- SpMM2 (padded rows) + b2 + log_softmax fused, unroll4 ----------------
__global__ __launch_bounds__(256) void k_spmm2lsm(const int* __restrict__ ip, const int2* __restrict__ epk,
                                                  const ushort_t* __restrict__ h2p,
                                                  const float* __restrict__ b2, float* __restrict__ out) {
  int node = blockIdx.x * 4 + (threadIdx.x >> 6);
  int lane = threadIdx.x & 63;
  int e0 = __builtin_amdgcn_readfirstlane(ip[node]);
  int e1 = __builtin_amdgcn_readfirstlane(ip[node + 1]);
  float a0 = 0.f, a1 = 0.f, a2 = 0.f, a3 = 0.f;
  int e = e0;
  for (; e + 4 <= e1; e += 4) {
    int2 p0 = epk[e], p1 = epk[e + 1], p2 = epk[e + 2], p3 = epk[e + 3];
    float v0 = bf2f(h2p[(size_t)p0.x * H2S + lane]);
    float v1 = bf2f(h2p[(size_t)p1.x * H2S + lane]);
    float v2 = bf2f(h2p[(size_t)p2.x * H2S + lane]);
    float v3 = bf2f(h2p[(size_t)p3.x * H2S + lane]);
    a0 = fmaf(i2f(p0.y), v0, a0);
    a1 = fmaf(i2f(p1.y), v1, a1);
    a2 = fmaf(i2f(p2.y), v2, a2);
    a3 = fmaf(i2f(p3.y), v3, a3);
  }
  for (; e < e1; ++e) {
    int2 p = epk[e];
    float v = bf2f(h2p[(size_t)p.x * H2S + lane]);
    a0 = fmaf(i2f(p.y), v, a0);
  }
  float acc = (a0 + a1) + (a2 + a3);
  float logit = (lane < F3) ? (acc + b2[lane]) : -INFINITY;
  float m = logit;
#pragma unroll
  for (int off = 32; off > 0; off >>= 1) m = fmaxf(m, __shfl_xor(m, off));
  float ex = (lane < F3) ? __expf(logit - m) : 0.f;
  float s = ex;
#pragma unroll
  for (int off = 32; off > 0; off >>= 1) s += __shfl_xor(s, off);
  if (lane < F3) out[(size_t)node * F3 + lane] = logit - m - __logf(s);
}

extern "C" void kernel_launch(void* const* d_in, const int* in_sizes, int n_in,
                              void* d_out, int out_size, void* d_ws, size_t ws_size,
                              hipStream_t stream) {
  const float* x     = (const float*)d_in[0];
  const int* erow    = (const int*)d_in[1];
  const int* ecol_in = (const int*)d_in[2];
  const float* ew_in = (const float*)d_in[3];
  const float* W1    = (const float*)d_in[4];
  const float* b1    = (const float*)d_in[5];
  const float* W2    = (const float*)d_in[6];
  const float* b2    = (const float*)d_in[7];
  float* out = (float*)d_out;

  const int N = in_sizes[0] / F1;  // 100000
  const int E = in_sizes[1];       // 1600000

  const int G = (E + TPB - 1) / TPB;          // 196
  const int NBIN = (N + RPB - 1) >> RSH;      // 391
  const int M = NBIN * G;                     // 76636
  const int nb2 = (M + 1023) / 1024;          // 75

  // ws layout (~65.1 MB):
  //   region0 [N*128 u16 = 25.6MB]: epk2 (CSR build) -> h0bf (gemm1..spmm1) -> h2p (gemm2..spmm2)
  //   hbf[N*128 u16] | ip[N+32] | cnt[M+8] | cntoff[M+64] | aux[128] | epk[E] int2 | w1p | w2p
  ushort_t* h0bf = (ushort_t*)d_ws;
  int2* epk2 = (int2*)d_ws;
  ushort_t* h2p = h0bf;
  ushort_t* hbf = h0bf + (size_t)N * F2;
  int* ip = (int*)(hbf + (size_t)N * F2);
  int* cnt = ip + (N + 32);
  int* cntoff = cnt + M + 8;
  int* aux = cntoff + M + 64;
  int2* epk = (int2*)(aux + 128);
  ushort_t* w1p = (ushort_t*)(epk + E);       // 40960 ushorts
  ushort_t* w2p = w1p + 40960;                // 6144 ushorts

  hipLaunchKernelGGL(k_cnt, dim3(G), dim3(256), 0, stream, erow, cnt, E, G, NBIN);
  hipLaunchKernelGGL(k_scan1, dim3(nb2), dim3(256), 0, stream, cnt, cntoff, aux, M);
  hipLaunchKernelGGL(k_scan_aux, dim3(1), dim3(128), 0, stream, aux, nb2);
  hipLaunchKernelGGL(k_scan_add, dim3(nb2), dim3(256), 0, stream, cntoff, aux, M, E);
  hipLaunchKernelGGL(k_scatter1, dim3(G), dim3(256), 0, stream, erow, ecol_in, ew_in, cntoff, epk2, E, G, NBIN);
  hipLaunchKernelGGL(k_binsort, dim3(NBIN), dim3(256), 0, stream, cntoff, epk2, ip, epk, G, NBIN, N, E);
  hipLaunchKernelGGL(k_w1prep, dim3((8 * 128 * 40 + 255) / 256), dim3(256), 0, stream, W1, w1p);
  hipLaunchKernelGGL(k_w2prep, dim3((4 * 3 * 64 * 8 + 255) / 256), dim3(256), 0, stream, W2, w2p);
  hipLaunchKernelGGL(k_gemm1, dim3((N + 63) / 64), dim3(256), 0, stream, x, w1p, h0bf, N);
  hipLaunchKernelGGL(k_spmm1, dim3(N / 4), dim3(256), 0, stream, ip, epk, h0bf, b1, hbf);
  hipLaunchKernelGGL(k_gemm2, dim3((N + 63) / 64), dim3(256), 0, stream, hbf, w2p, h2p, N);
  hipLaunchKernelGGL(k_spmm2lsm, dim3(N / 4), dim3(256), 0, stream, ip, epk, h2p, b2, out);
}

// Round 9
// 223.564 us; speedup vs baseline: 3.3176x; 1.0938x over previous
//
#include <hip/hip_runtime.h>
#include <math.h>

#define F1 256
#define F2 128
#define F3 40
#define H2S 64    // padded h2 row stride (one 128B cacheline)
#define RPB 256   // rows per bin (counting-sort granularity)
#define RSH 8
#define TPB 8192  // edges per block in cnt/scatter1 passes

typedef unsigned short ushort_t;
typedef __attribute__((ext_vector_type(8))) short bf16x8;
typedef __attribute__((ext_vector_type(4))) float f32x4;

__device__ inline ushort_t f2bf(float f) {
  unsigned u = __builtin_bit_cast(unsigned, f);
  u += 0x7FFF + ((u >> 16) & 1);
  return (ushort_t)(u >> 16);
}
__device__ inline float bf2f(ushort_t b) {
  unsigned u = ((unsigned)b) << 16;
  return __builtin_bit_cast(float, u);
}
__device__ inline float i2f(int b) { return __builtin_bit_cast(float, b); }

// ---------------- CSR build: 2-level counting sort (XCD-write-amplification-free) ----------------

__global__ __launch_bounds__(256) void k_cnt(const int* __restrict__ row, int* __restrict__ cnt,
                                             int E, int G, int NBIN) {
  __shared__ int h[400];
  int tid = threadIdx.x, blk = blockIdx.x;
  for (int i = tid; i < NBIN; i += 256) h[i] = 0;
  __syncthreads();
  int base = blk * TPB, lim = min(base + TPB, E);
  for (int i = base + tid; i < lim; i += 256) atomicAdd(&h[row[i] >> RSH], 1);
  __syncthreads();
  for (int i = tid; i < NBIN; i += 256) cnt[i * G + blk] = h[i];
}

__global__ __launch_bounds__(256) void k_scan1(const int* __restrict__ in, int* __restrict__ out,
                                               int* __restrict__ aux, int n) {
  __shared__ int lds[256];
  int tid = threadIdx.x;
  int base = blockIdx.x * 1024 + tid * 4;
  int v0 = 0, v1 = 0, v2 = 0, v3 = 0;
  if (base + 0 < n) v0 = in[base + 0];
  if (base + 1 < n) v1 = in[base + 1];
  if (base + 2 < n) v2 = in[base + 2];
  if (base + 3 < n) v3 = in[base + 3];
  int s = v0 + v1 + v2 + v3;
  lds[tid] = s;
  __syncthreads();
  for (int off = 1; off < 256; off <<= 1) {
    int t = (tid >= off) ? lds[tid - off] : 0;
    __syncthreads();
    lds[tid] += t;
    __syncthreads();
  }
  int excl = (tid > 0) ? lds[tid - 1] : 0;
  if (tid == 255) aux[blockIdx.x] = lds[255];
  if (base + 0 < n) out[base + 0] = excl;
  if (base + 1 < n) out[base + 1] = excl + v0;
  if (base + 2 < n) out[base + 2] = excl + v0 + v1;
  if (base + 3 < n) out[base + 3] = excl + v0 + v1 + v2;
}

__global__ __launch_bounds__(128) void k_scan_aux(int* __restrict__ aux, int nb) {
  __shared__ int lds[128];
  int tid = threadIdx.x;
  int v = (tid < nb) ? aux[tid] : 0;
  lds[tid] = v;
  __syncthreads();
  for (int off = 1; off < 128; off <<= 1) {
    int t = (tid >= off) ? lds[tid - off] : 0;
    __syncthreads();
    lds[tid] += t;
    __syncthreads();
  }
  int excl = (tid > 0) ? lds[tid - 1] : 0;
  if (tid < nb) aux[tid] = excl;
}

__global__ __launch_bounds__(256) void k_scan_add(int* __restrict__ out, const int* __restrict__ aux,
                                                  int n, int E) {
  int add = aux[blockIdx.x];
  int base = blockIdx.x * 1024 + threadIdx.x * 4;
#pragma unroll
  for (int i = 0; i < 4; i++)
    if (base + i < n) out[base + i] += add;
  if (blockIdx.x == 0 && threadIdx.x == 0) out[n] = E;  // sentinel: cntoff[M] = E
}

__global__ __launch_bounds__(256) void k_scatter1(const int* __restrict__ row, const int* __restrict__ col,
                                                  const float* __restrict__ w, const int* __restrict__ cntoff,
                                                  int2* __restrict__ epk2, int E, int G, int NBIN) {
  __shared__ int cur[400];
  int tid = threadIdx.x, blk = blockIdx.x;
  for (int i = tid; i < NBIN; i += 256) cur[i] = cntoff[i * G + blk];
  __syncthreads();
  int base = blk * TPB, lim = min(base + TPB, E);
  for (int i = base + tid; i < lim; i += 256) {
    int r = row[i];
    int pos = atomicAdd(&cur[r >> RSH], 1);
    epk2[pos] = make_int2(((r & (RPB - 1)) << 17) | col[i], __builtin_bit_cast(int, w[i]));
  }
}

__global__ __launch_bounds__(256) void k_binsort(const int* __restrict__ cntoff, const int2* __restrict__ epk2,
                                                 int* __restrict__ ip, int2* __restrict__ epk,
                                                 int G, int NBIN, int N, int E) {
  __shared__ int sc[256], cur[256];
  int tid = threadIdx.x, b = blockIdx.x;
  int s = cntoff[b * G], eend = cntoff[(b + 1) * G];
  cur[tid] = 0;
  __syncthreads();
  for (int i = s + tid; i < eend; i += 256) atomicAdd(&cur[epk2[i].x >> 17], 1);
  __syncthreads();
  int d = cur[tid];
  sc[tid] = d;
  __syncthreads();
  for (int o = 1; o < 256; o <<= 1) {
    int t = (tid >= o) ? sc[tid - o] : 0;
    __syncthreads();
    sc[tid] += t;
    __syncthreads();
  }
  int excl = (tid > 0) ? sc[tid - 1] : 0;
  __syncthreads();
  cur[tid] = excl;
  int gr = (b << RSH) + tid;
  if (gr <= N) ip[gr] = s + excl;
  if (b == 0 && tid == 0) ip[N] = E;
  __syncthreads();
  for (int i = s + tid; i < eend; i += 256) {
    int2 rec = epk2[i];
    int local = rec.x >> 17, c = rec.x & 0x1FFFF;
    int p = s + atomicAdd(&cur[local], 1);
    epk[p] = make_int2(c, rec.y);
  }
}

// ---------------- W1 prep: fp32 [256][128] -> per-lane B-fragments [kt 8][t 8][lane 64][8] ----------------
__global__ __launch_bounds__(256) void k_w1prep(const float* __restrict__ W1, ushort_t* __restrict__ w1pf) {
  int idx = blockIdx.x * 256 + threadIdx.x;
  if (idx < 8 * 8 * 64 * 8) {
    int j = idx & 7;
    int l = (idx >> 3) & 63;
    int t = (idx >> 9) & 7;
    int kt = idx >> 12;
    int k = kt * 32 + (l >> 4) * 8 + j;
    int c = t * 16 + (l & 15);
    w1pf[idx] = f2bf(W1[(size_t)k * F2 + c]);
  }
}

// ---------------- W2 prep: fp32 [128][40] -> per-lane B-fragments [kt 4][t 3][lane 64][8] ----------------
__global__ __launch_bounds__(256) void k_w2prep(const float* __restrict__ W2, ushort_t* __restrict__ w2p) {
  int idx = blockIdx.x * 256 + threadIdx.x;
  if (idx < 4 * 3 * 64 * 8) {
    int j = idx & 7;
    int rem = idx >> 3;
    int l = rem & 63;
    int g = rem >> 6;       // 0..11
    int t = g % 3, kt = g / 3;
    int colc = t * 16 + (l & 15);
    int k = kt * 32 + (l >> 4) * 8 + j;
    w2p[idx] = (colc < F3) ? f2bf(W2[(size_t)k * F3 + colc]) : (ushort_t)0;
  }
}

// ---------------- GEMM1 (MFMA, no LDS): h0[N,128] = x[N,256] @ W1, store bf16 ----------------
__global__ __launch_bounds__(256) void k_gemm1(const float* __restrict__ x, const ushort_t* __restrict__ w1pf,
                                               ushort_t* __restrict__ h0bf, int N) {
  const int tid = threadIdx.x;
  const int lane = tid & 63;
  const int w = tid >> 6;
  const int r0 = blockIdx.x * 64;
  const int arow = r0 + w * 16 + (lane & 15);
  const int ar = (arow < N) ? arow : 0;
  const int kg = (lane >> 4) * 8;
  const float* xr = x + (size_t)ar * F1 + kg;

  f32x4 acc[8];
#pragma unroll
  for (int t = 0; t < 8; ++t) acc[t] = (f32x4){0.f, 0.f, 0.f, 0.f};

#pragma unroll
  for (int kt = 0; kt < 8; ++kt) {
    float4 v0 = *(const float4*)(xr + kt * 32);
    float4 v1 = *(const float4*)(xr + kt * 32 + 4);
    bf16x8 a;
    a[0] = (short)f2bf(v0.x); a[1] = (short)f2bf(v0.y);
    a[2] = (short)f2bf(v0.z); a[3] = (short)f2bf(v0.w);
    a[4] = (short)f2bf(v1.x); a[5] = (short)f2bf(v1.y);
    a[6] = (short)f2bf(v1.z); a[7] = (short)f2bf(v1.w);
#pragma unroll
    for (int t = 0; t < 8; ++t) {
      bf16x8 b = *(const bf16x8*)(w1pf + (size_t)(((kt * 8 + t) * 64) + lane) * 8);
      acc[t] = __builtin_amdgcn_mfma_f32_16x16x32_bf16(a, b, acc[t], 0, 0, 0);
    }
  }

  // C/D layout (HW-verified): col = lane&15, row = (lane>>4)*4 + j
#pragma unroll
  for (int t = 0; t < 8; ++t) {
    int gc = t * 16 + (lane & 15);
#pragma unroll
    for (int j = 0; j < 4; ++j) {
      int gr = r0 + w * 16 + (lane >> 4) * 4 + j;
      if (gr < N) h0bf[(size_t)gr * F2 + gc] = f2bf(acc[t][j]);
    }
  }
}

// ---------------- SpMM1 (F=128, bf16 gather) + b1 + relu: wave per node, unroll4 ----------------
__global__ __launch_bounds__(256) void k_spmm1(const int* __restrict__ ip, const int2* __restrict__ epk,
                                               const ushort_t* __restrict__ h0bf,
                                               const float* __restrict__ b1, ushort_t* __restrict__ hbf) {
  int node = blockIdx.x * 4 + (threadIdx.x >> 6);
  int lane = threadIdx.x & 63;
  int e0 = __builtin_amdgcn_readfirstlane(ip[node]);
  int e1 = __builtin_amdgcn_readfirstlane(ip[node + 1]);
  float ax0 = 0.f, ay0 = 0.f, ax1 = 0.f, ay1 = 0.f;
  float ax2 = 0.f, ay2 = 0.f, ax3 = 0.f, ay3 = 0.f;
  int e = e0;
  for (; e + 4 <= e1; e += 4) {
    int2 p0 = epk[e], p1 = epk[e + 1], p2 = epk[e + 2], p3 = epk[e + 3];
    ushort2 v0 = *(const ushort2*)(h0bf + (size_t)p0.x * F2 + lane * 2);
    ushort2 v1 = *(const ushort2*)(h0bf + (size_t)p1.x * F2 + lane * 2);
    ushort2 v2 = *(const ushort2*)(h0bf + (size_t)p2.x * F2 + lane * 2);
    ushort2 v3 = *(const ushort2*)(h0bf + (size_t)p3.x * F2 + lane * 2);
    float w0 = i2f(p0.y), w1 = i2f(p1.y), w2 = i2f(p2.y), w3 = i2f(p3.y);
    ax0 = fmaf(w0, bf2f(v0.x), ax0); ay0 = fmaf(w0, bf2f(v0.y), ay0);
    ax1 = fmaf(w1, bf2f(v1.x), ax1); ay1 = fmaf(w1, bf2f(v1.y), ay1);
    ax2 = fmaf(w2, bf2f(v2.x), ax2); ay2 = fmaf(w2, bf2f(v2.y), ay2);
    ax3 = fmaf(w3, bf2f(v3.x), ax3); ay3 = fmaf(w3, bf2f(v3.y), ay3);
  }
  for (; e < e1; ++e) {
    int2 p = epk[e];
    ushort2 v = *(const ushort2*)(h0bf + (size_t)p.x * F2 + lane * 2);
    float wt = i2f(p.y);
    ax0 = fmaf(wt, bf2f(v.x), ax0); ay0 = fmaf(wt, bf2f(v.y), ay0);
  }
  float ax = (ax0 + ax1) + (ax2 + ax3);
  float ay = (ay0 + ay1) + (ay2 + ay3);
  float2 bb = *(const float2*)(b1 + lane * 2);
  ushort2 r;
  r.x = f2bf(fmaxf(ax + bb.x, 0.f));
  r.y = f2bf(fmaxf(ay + bb.y, 0.f));
  *(ushort2*)(hbf + (size_t)node * F2 + lane * 2) = r;
}

// ---------------- GEMM2 (MFMA, no LDS): h2p[N,64pad] = h[N,128] @ W2[128,40] ----------------
__global__ __launch_bounds__(256) void k_gemm2(const ushort_t* __restrict__ hbf, const ushort_t* __restrict__ w2p,
                                               ushort_t* __restrict__ h2p, int N) {
  const int tid = threadIdx.x;
  const int lane = tid & 63;
  const int w = tid >> 6;
  const int r0 = blockIdx.x * 64;
  const int arow = r0 + w * 16 + (lane & 15);
  const int ar = (arow < N) ? arow : 0;
  const int kg = (lane >> 4) * 8;

  bf16x8 a[4];
#pragma unroll
  for (int kt = 0; kt < 4; ++kt)
    a[kt] = *(const bf16x8*)(hbf + (size_t)ar * F2 + kt * 32 + kg);

  f32x4 acc[3];
#pragma unroll
  for (int t = 0; t < 3; ++t) acc[t] = (f32x4){0.f, 0.f, 0.f, 0.f};

#pragma unroll
  for (int kt = 0; kt < 4; ++kt) {
#pragma unroll
    for (int t = 0; t < 3; ++t) {
      bf16x8 b = *(const bf16x8*)(w2p + (size_t)(((kt * 3 + t) * 64) + lane) * 8);
      acc[t] = __builtin_amdgcn_mfma_f32_16x16x32_bf16(a[kt], b, acc[t], 0, 0, 0);
    }
  }

#pragma unroll
  for (int t = 0; t < 3; ++t) {
    int gc = t * 16 + (lane & 15);
    if (gc < F3) {
#pragma unroll
      for (int j = 0; j < 4; ++j) {
        int gr = r0 + w * 16 + (lane >> 4) * 4 + j;
        if (gr < N) h2p[(size_t)gr * H2S + gc] = f2bf(acc[t][j]);
      }
    }
  }
  for (int idx = tid; idx < 64 * 24; idx += 256) {
    int row = idx / 24, pc = F3 + idx % 24;
    int gr = r0 + row;
    if (gr < N) h2p[(size_t)gr * H2S + pc] = 0;
  }
}

// ---------------- SpMM2 (padded rows) + b2 + log_softmax fused, unroll4 ----------------
__global__ __launch_bounds__(256) void k_spmm2lsm(const int* __restrict__ ip, const int2* __restrict__ epk,
                                                  const ushort_t* __restrict__ h2p,
                                                  const float* __restrict__ b2, float* __restrict__ out) {
  int node = blockIdx.x * 4 + (threadIdx.x >> 6);
  int lane = threadIdx.x & 63;
  int e0 = __builtin_amdgcn_readfirstlane(ip[node]);
  int e1 = __builtin_amdgcn_readfirstlane(ip[node + 1]);
  float a0 = 0.f, a1 = 0.f, a2 = 0.f, a3 = 0.f;
  int e = e0;
  for (; e + 4 <= e1; e += 4) {
    int2 p0 = epk[e], p1 = epk[e + 1], p2 = epk[e + 2], p3 = epk[e + 3];
    float v0 = bf2f(h2p[(size_t)p0.x * H2S + lane]);
    float v1 = bf2f(h2p[(size_t)p1.x * H2S + lane]);
    float v2 = bf2f(h2p[(size_t)p2.x * H2S + lane]);
    float v3 = bf2f(h2p[(size_t)p3.x * H2S + lane]);
    a0 = fmaf(i2f(p0.y), v0, a0);
    a1 = fmaf(i2f(p1.y), v1, a1);
    a2 = fmaf(i2f(p2.y), v2, a2);
    a3 = fmaf(i2f(p3.y), v3, a3);
  }
  for (; e < e1; ++e) {
    int2 p = epk[e];
    float v = bf2f(h2p[(size_t)p.x * H2S + lane]);
    a0 = fmaf(i2f(p.y), v, a0);
  }
  float acc = (a0 + a1) + (a2 + a3);
  float logit = (lane < F3) ? (acc + b2[lane]) : -INFINITY;
  float m = logit;
#pragma unroll
  for (int off = 32; off > 0; off >>= 1) m = fmaxf(m, __shfl_xor(m, off));
  float ex = (lane < F3) ? __expf(logit - m) : 0.f;
  float s = ex;
#pragma unroll
  for (int off = 32; off > 0; off >>= 1) s += __shfl_xor(s, off);
  if (lane < F3) out[(size_t)node * F3 + lane] = logit - m - __logf(s);
}

extern "C" void kernel_launch(void* const* d_in, const int* in_sizes, int n_in,
                              void* d_out, int out_size, void* d_ws, size_t ws_size,
                              hipStream_t stream) {
  const float* x     = (const float*)d_in[0];
  const int* erow    = (const int*)d_in[1];
  const int* ecol_in = (const int*)d_in[2];
  const float* ew_in = (const float*)d_in[3];
  const float* W1    = (const float*)d_in[4];
  const float* b1    = (const float*)d_in[5];
  const float* W2    = (const float*)d_in[6];
  const float* b2    = (const float*)d_in[7];
  float* out = (float*)d_out;

  const int N = in_sizes[0] / F1;  // 100000
  const int E = in_sizes[1];       // 1600000

  const int G = (E + TPB - 1) / TPB;          // 196
  const int NBIN = (N + RPB - 1) >> RSH;      // 391
  const int M = NBIN * G;                     // 76636
  const int nb2 = (M + 1023) / 1024;          // 75

  // ws layout (~65.1 MB):
  //   region0 [N*128 u16 = 25.6MB]: epk2 (CSR build) -> h0bf (gemm1..spmm1) -> h2p (gemm2..spmm2)
  //   hbf[N*128 u16] | ip[N+32] | cnt[M+8] | cntoff[M+64] | aux[128] | epk[E] int2 | w1pf | w2p
  ushort_t* h0bf = (ushort_t*)d_ws;
  int2* epk2 = (int2*)d_ws;
  ushort_t* h2p = h0bf;
  ushort_t* hbf = h0bf + (size_t)N * F2;
  int* ip = (int*)(hbf + (size_t)N * F2);
  int* cnt = ip + (N + 32);
  int* cntoff = cnt + M + 8;
  int* aux = cntoff + M + 64;
  int2* epk = (int2*)(aux + 128);
  ushort_t* w1pf = (ushort_t*)(epk + E);      // 8*8*64*8 = 32768 ushorts
  ushort_t* w2p = w1pf + 32768;               // 6144 ushorts

  hipLaunchKernelGGL(k_cnt, dim3(G), dim3(256), 0, stream, erow, cnt, E, G, NBIN);
  hipLaunchKernelGGL(k_scan1, dim3(nb2), dim3(256), 0, stream, cnt, cntoff, aux, M);
  hipLaunchKernelGGL(k_scan_aux, dim3(1), dim3(128), 0, stream, aux, nb2);
  hipLaunchKernelGGL(k_scan_add, dim3(nb2), dim3(256), 0, stream, cntoff, aux, M, E);
  hipLaunchKernelGGL(k_scatter1, dim3(G), dim3(256), 0, stream, erow, ecol_in, ew_in, cntoff, epk2, E, G, NBIN);
  hipLaunchKernelGGL(k_binsort, dim3(NBIN), dim3(256), 0, stream, cntoff, epk2, ip, epk, G, NBIN, N, E);
  hipLaunchKernelGGL(k_w1prep, dim3(128), dim3(256), 0, stream, W1, w1pf);
  hipLaunchKernelGGL(k_w2prep, dim3((4 * 3 * 64 * 8 + 255) / 256), dim3(256), 0, stream, W2, w2p);
  hipLaunchKernelGGL(k_gemm1, dim3((N + 63) / 64), dim3(256), 0, stream, x, w1pf, h0bf, N);
  hipLaunchKernelGGL(k_spmm1, dim3(N / 4), dim3(256), 0, stream, ip, epk, h0bf, b1, hbf);
  hipLaunchKernelGGL(k_gemm2, dim3((N + 63) / 64), dim3(256), 0, stream, hbf, w2p, h2p, N);
  hipLaunchKernelGGL(k_spmm2lsm, dim3(N / 4), dim3(256), 0, stream, ip, epk, h2p, b2, out);
}

// Round 10
// 223.413 us; speedup vs baseline: 3.3198x; 1.0007x over previous
//
#include <hip/hip_runtime.h>
#include <math.h>

#define F1 256
#define F2 128
#define F3 40
#define H2S 64    // padded h2 row stride (one 128B cacheline)
#define RPB 256   // rows per bin (counting-sort granularity)
#define RSH 8
#define TPB 8192  // edges per block in cnt/scatter1 passes

typedef unsigned short ushort_t;
typedef __attribute__((ext_vector_type(8))) short bf16x8;
typedef __attribute__((ext_vector_type(4))) float f32x4;

__device__ inline ushort_t f2bf(float f) {
  unsigned u = __builtin_bit_cast(unsigned, f);
  u += 0x7FFF + ((u >> 16) & 1);
  return (ushort_t)(u >> 16);
}
__device__ inline float bf2f(ushort_t b) {
  unsigned u = ((unsigned)b) << 16;
  return __builtin_bit_cast(float, u);
}
__device__ inline float i2f(int b) { return __builtin_bit_cast(float, b); }

// ---------------- CSR build: 2-level counting sort (XCD-write-amplification-free) ----------------

__global__ __launch_bounds__(256) void k_cnt(const int* __restrict__ row, int* __restrict__ cnt,
                                             int E, int G, int NBIN) {
  __shared__ int h[400];
  int tid = threadIdx.x, blk = blockIdx.x;
  for (int i = tid; i < NBIN; i += 256) h[i] = 0;
  __syncthreads();
  int base = blk * TPB, lim = min(base + TPB, E);
  for (int i = base + tid; i < lim; i += 256) atomicAdd(&h[row[i] >> RSH], 1);
  __syncthreads();
  for (int i = tid; i < NBIN; i += 256) cnt[i * G + blk] = h[i];
}

__global__ __launch_bounds__(256) void k_scan1(const int* __restrict__ in, int* __restrict__ out,
                                               int* __restrict__ aux, int n) {
  __shared__ int lds[256];
  int tid = threadIdx.x;
  int base = blockIdx.x * 1024 + tid * 4;
  int v0 = 0, v1 = 0, v2 = 0, v3 = 0;
  if (base + 0 < n) v0 = in[base + 0];
  if (base + 1 < n) v1 = in[base + 1];
  if (base + 2 < n) v2 = in[base + 2];
  if (base + 3 < n) v3 = in[base + 3];
  int s = v0 + v1 + v2 + v3;
  lds[tid] = s;
  __syncthreads();
  for (int off = 1; off < 256; off <<= 1) {
    int t = (tid >= off) ? lds[tid - off] : 0;
    __syncthreads();
    lds[tid] += t;
    __syncthreads();
  }
  int excl = (tid > 0) ? lds[tid - 1] : 0;
  if (tid == 255) aux[blockIdx.x] = lds[255];
  if (base + 0 < n) out[base + 0] = excl;
  if (base + 1 < n) out[base + 1] = excl + v0;
  if (base + 2 < n) out[base + 2] = excl + v0 + v1;
  if (base + 3 < n) out[base + 3] = excl + v0 + v1 + v2;
}

__global__ __launch_bounds__(128) void k_scan_aux(int* __restrict__ aux, int nb) {
  __shared__ int lds[128];
  int tid = threadIdx.x;
  int v = (tid < nb) ? aux[tid] : 0;
  lds[tid] = v;
  __syncthreads();
  for (int off = 1; off < 128; off <<= 1) {
    int t = (tid >= off) ? lds[tid - off] : 0;
    __syncthreads();
    lds[tid] += t;
    __syncthreads();
  }
  int excl = (tid > 0) ? lds[tid - 1] : 0;
  if (tid < nb) aux[tid] = excl;
}

__global__ __launch_bounds__(256) void k_scan_add(int* __restrict__ out, const int* __restrict__ aux,
                                                  int n, int E) {
  int add = aux[blockIdx.x];
  int base = blockIdx.x * 1024 + threadIdx.x * 4;
#pragma unroll
  for (int i = 0; i < 4; i++)
    if (base + i < n) out[base + i] += add;
  if (blockIdx.x == 0 && threadIdx.x == 0) out[n] = E;  // sentinel: cntoff[M] = E
}

__global__ __launch_bounds__(256) void k_scatter1(const int* __restrict__ row, const int* __restrict__ col,
                                                  const float* __restrict__ w, const int* __restrict__ cntoff,
                                                  int2* __restrict__ epk2, int E, int G, int NBIN) {
  __shared__ int cur[400];
  int tid = threadIdx.x, blk = blockIdx.x;
  for (int i = tid; i < NBIN; i += 256) cur[i] = cntoff[i * G + blk];
  __syncthreads();
  int base = blk * TPB, lim = min(base + TPB, E);
  for (int i = base + tid; i < lim; i += 256) {
    int r = row[i];
    int pos = atomicAdd(&cur[r >> RSH], 1);
    epk2[pos] = make_int2(((r & (RPB - 1)) << 17) | col[i], __builtin_bit_cast(int, w[i]));
  }
}

__global__ __launch_bounds__(256) void k_binsort(const int* __restrict__ cntoff, const int2* __restrict__ epk2,
                                                 int* __restrict__ ip, int2* __restrict__ epk,
                                                 int G, int NBIN, int N, int E) {
  __shared__ int sc[256], cur[256];
  int tid = threadIdx.x, b = blockIdx.x;
  int s = cntoff[b * G], eend = cntoff[(b + 1) * G];
  cur[tid] = 0;
  __syncthreads();
  for (int i = s + tid; i < eend; i += 256) atomicAdd(&cur[epk2[i].x >> 17], 1);
  __syncthreads();
  int d = cur[tid];
  sc[tid] = d;
  __syncthreads();
  for (int o = 1; o < 256; o <<= 1) {
    int t = (tid >= o) ? sc[tid - o] : 0;
    __syncthreads();
    sc[tid] += t;
    __syncthreads();
  }
  int excl = (tid > 0) ? sc[tid - 1] : 0;
  __syncthreads();
  cur[tid] = excl;
  int gr = (b << RSH) + tid;
  if (gr <= N) ip[gr] = s + excl;
  if (b == 0 && tid == 0) ip[N] = E;
  __syncthreads();
  for (int i = s + tid; i < eend; i += 256) {
    int2 rec = epk2[i];
    int local = rec.x >> 17, c = rec.x & 0x1FFFF;
    int p = s + atomicAdd(&cur[local], 1);
    epk[p] = make_int2(c, rec.y);
  }
}

// ---------------- W1 prep: fp32 [256][128] -> per-lane B-fragments [kt 8][t 8][lane 64][8] ----------------
__global__ __launch_bounds__(256) void k_w1prep(const float* __restrict__ W1, ushort_t* __restrict__ w1pf) {
  int idx = blockIdx.x * 256 + threadIdx.x;
  if (idx < 8 * 8 * 64 * 8) {
    int j = idx & 7;
    int l = (idx >> 3) & 63;
    int t = (idx >> 9) & 7;
    int kt = idx >> 12;
    int k = kt * 32 + (l >> 4) * 8 + j;
    int c = t * 16 + (l & 15);
    w1pf[idx] = f2bf(W1[(size_t)k * F2 + c]);
  }
}

// ---------------- W2 prep: fp32 [128][40] -> per-lane B-fragments [kt 4][t 3][lane 64][8] ----------------
__global__ __launch_bounds__(256) void k_w2prep(const float* __restrict__ W2, ushort_t* __restrict__ w2p) {
  int idx = blockIdx.x * 256 + threadIdx.x;
  if (idx < 4 * 3 * 64 * 8) {
    int j = idx & 7;
    int rem = idx >> 3;
    int l = rem & 63;
    int g = rem >> 6;       // 0..11
    int t = g % 3, kt = g / 3;
    int colc = t * 16 + (l & 15);
    int k = kt * 32 + (l >> 4) * 8 + j;
    w2p[idx] = (colc < F3) ? f2bf(W2[(size_t)k * F3 + colc]) : (ushort_t)0;
  }
}

// ---------------- GEMM1 (MFMA, no LDS): h0[N,128] = x[N,256] @ W1, store bf16 ----------------
__global__ __launch_bounds__(256) void k_gemm1(const float* __restrict__ x, const ushort_t* __restrict__ w1pf,
                                               ushort_t* __restrict__ h0bf, int N) {
  const int tid = threadIdx.x;
  const int lane = tid & 63;
  const int w = tid >> 6;
  const int r0 = blockIdx.x * 64;
  const int arow = r0 + w * 16 + (lane & 15);
  const int ar = (arow < N) ? arow : 0;
  const int kg = (lane >> 4) * 8;
  const float* xr = x + (size_t)ar * F1 + kg;

  f32x4 acc[8];
#pragma unroll
  for (int t = 0; t < 8; ++t) acc[t] = (f32x4){0.f, 0.f, 0.f, 0.f};

#pragma unroll
  for (int kt = 0; kt < 8; ++kt) {
    float4 v0 = *(const float4*)(xr + kt * 32);
    float4 v1 = *(const float4*)(xr + kt * 32 + 4);
    bf16x8 a;
    a[0] = (short)f2bf(v0.x); a[1] = (short)f2bf(v0.y);
    a[2] = (short)f2bf(v0.z); a[3] = (short)f2bf(v0.w);
    a[4] = (short)f2bf(v1.x); a[5] = (short)f2bf(v1.y);
    a[6] = (short)f2bf(v1.z); a[7] = (short)f2bf(v1.w);
#pragma unroll
    for (int t = 0; t < 8; ++t) {
      bf16x8 b = *(const bf16x8*)(w1pf + (size_t)(((kt * 8 + t) * 64) + lane) * 8);
      acc[t] = __builtin_amdgcn_mfma_f32_16x16x32_bf16(a, b, acc[t], 0, 0, 0);
    }
  }

  // C/D layout (HW-verified): col = lane&15, row = (lane>>4)*4 + j
#pragma unroll
  for (int t = 0; t < 8; ++t) {
    int gc = t * 16 + (lane & 15);
#pragma unroll
    for (int j = 0; j < 4; ++j) {
      int gr = r0 + w * 16 + (lane >> 4) * 4 + j;
      if (gr < N) h0bf[(size_t)gr * F2 + gc] = f2bf(acc[t][j]);
    }
  }
}

// ---------------- SpMM1 (F=128, bf16 gather) + b1 + relu: wave/node, 8-deep clamped groups ----------------
__global__ __launch_bounds__(256) void k_spmm1(const int* __restrict__ ip, const int2* __restrict__ epk,
                                               const ushort_t* __restrict__ h0bf,
                                               const float* __restrict__ b1, ushort_t* __restrict__ hbf) {
  int node = blockIdx.x * 4 + (threadIdx.x >> 6);
  int lane = threadIdx.x & 63;
  int e0 = __builtin_amdgcn_readfirstlane(ip[node]);
  int e1 = __builtin_amdgcn_readfirstlane(ip[node + 1]);
  float ax[8], ay[8];
#pragma unroll
  for (int k = 0; k < 8; ++k) { ax[k] = 0.f; ay[k] = 0.f; }
  for (int e = e0; e < e1; e += 8) {
#pragma unroll
    for (int k = 0; k < 8; ++k) {
      int ee = e + k;
      int ec = (ee < e1) ? ee : (e1 - 1);   // e1 > e0 whenever loop body runs
      int2 p = epk[ec];
      ushort2 v = *(const ushort2*)(h0bf + (size_t)p.x * F2 + lane * 2);
      float wt = (ee < e1) ? i2f(p.y) : 0.f;
      ax[k] = fmaf(wt, bf2f(v.x), ax[k]);
      ay[k] = fmaf(wt, bf2f(v.y), ay[k]);
    }
  }
  float axs = ((ax[0] + ax[1]) + (ax[2] + ax[3])) + ((ax[4] + ax[5]) + (ax[6] + ax[7]));
  float ays = ((ay[0] + ay[1]) + (ay[2] + ay[3])) + ((ay[4] + ay[5]) + (ay[6] + ay[7]));
  float2 bb = *(const float2*)(b1 + lane * 2);
  ushort2 r;
  r.x = f2bf(fmaxf(axs + bb.x, 0.f));
  r.y = f2bf(fmaxf(ays + bb.y, 0.f));
  *(ushort2*)(hbf + (size_t)node * F2 + lane * 2) = r;
}

// ---------------- GEMM2 (MFMA, no LDS): h2p[N,64pad] = h[N,128] @ W2[128,40] ----------------
__global__ __launch_bounds__(256) void k_gemm2(const ushort_t* __restrict__ hbf, const ushort_t* __restrict__ w2p,
                                               ushort_t* __restrict__ h2p, int N) {
  const int tid = threadIdx.x;
  const int lane = tid & 63;
  const int w = tid >> 6;
  const int r0 = blockIdx.x * 64;
  const int arow = r0 + w * 16 + (lane & 15);
  const int ar = (arow < N) ? arow : 0;
  const int kg = (lane >> 4) * 8;

  bf16x8 a[4];
#pragma unroll
  for (int kt = 0; kt < 4; ++kt)
    a[kt] = *(const bf16x8*)(hbf + (size_t)ar * F2 + kt * 32 + kg);

  f32x4 acc[3];
#pragma unroll
  for (int t = 0; t < 3; ++t) acc[t] = (f32x4){0.f, 0.f, 0.f, 0.f};

#pragma unroll
  for (int kt = 0; kt < 4; ++kt) {
#pragma unroll
    for (int t = 0; t < 3; ++t) {
      bf16x8 b = *(const bf16x8*)(w2p + (size_t)(((kt * 3 + t) * 64) + lane) * 8);
      acc[t] = __builtin_amdgcn_mfma_f32_16x16x32_bf16(a[kt], b, acc[t], 0, 0, 0);
    }
  }

#pragma unroll
  for (int t = 0; t < 3; ++t) {
    int gc = t * 16 + (lane & 15);
    if (gc < F3) {
#pragma unroll
      for (int j = 0; j < 4; ++j) {
        int gr = r0 + w * 16 + (lane >> 4) * 4 + j;
        if (gr < N) h2p[(size_t)gr * H2S + gc] = f2bf(acc[t][j]);
      }
    }
  }
  for (int idx = tid; idx < 64 * 24; idx += 256) {
    int row = idx / 24, pc = F3 + idx % 24;
    int gr = r0 + row;
    if (gr < N) h2p[(size_t)gr * H2S + pc] = 0;
  }
}

// ---------------- SpMM2 (padded rows) + b2 + log_softmax fused, 8-deep clamped groups ----------------
__global__ __launch_bounds__(256) void k_spmm2lsm(const int* __restrict__ ip, const int2* __restrict__ epk,
                                                  const ushort_t* __restrict__ h2p,
                                                  const float* __restrict__ b2, float* __restrict__ out) {
  int node = blockIdx.x * 4 + (threadIdx.x >> 6);
  int lane = threadIdx.x & 63;
  int e0 = __builtin_amdgcn_readfirstlane(ip[node]);
  int e1 = __builtin_amdgcn_readfirstlane(ip[node + 1]);
  float a[8];
#pragma unroll
  for (int k = 0; k < 8; ++k) a[k] = 0.f;
  for (int e = e0; e < e1; e += 8) {
#pragma unroll
    for (int k = 0; k < 8; ++k) {
      int ee = e + k;
      int ec = (ee < e1) ? ee : (e1 - 1);
      int2 p = epk[ec];
      float v = bf2f(h2p[(size_t)p.x * H2S + lane]);
      float wt = (ee < e1) ? i2f(p.y) : 0.f;
      a[k] = fmaf(wt, v, a[k]);
    }
  }
  float acc = ((a[0] + a[1]) + (a[2] + a[3])) + ((a[4] + a[5]) + (a[6] + a[7]));
  float logit = (lane < F3) ? (acc + b2[lane]) : -INFINITY;
  float m = logit;
#pragma unroll
  for (int off = 32; off > 0; off >>= 1) m = fmaxf(m, __shfl_xor(m, off));
  float ex = (lane < F3) ? __expf(logit - m) : 0.f;
  float s = ex;
#pragma unroll
  for (int off = 32; off > 0; off >>= 1) s += __shfl_xor(s, off);
  if (lane < F3) out[(size_t)node * F3 + lane] = logit - m - __logf(s);
}

extern "C" void kernel_launch(void* const* d_in, const int* in_sizes, int n_in,
                              void* d_out, int out_size, void* d_ws, size_t ws_size,
                              hipStream_t stream) {
  const float* x     = (const float*)d_in[0];
  const int* erow    = (const int*)d_in[1];
  const int* ecol_in = (const int*)d_in[2];
  const float* ew_in = (const float*)d_in[3];
  const float* W1    = (const float*)d_in[4];
  const float* b1    = (const float*)d_in[5];
  const float* W2    = (const float*)d_in[6];
  const float* b2    = (const float*)d_in[7];
  float* out = (float*)d_out;

  const int N = in_sizes[0] / F1;  // 100000
  const int E = in_sizes[1];       // 1600000

  const int G = (E + TPB - 1) / TPB;          // 196
  const int NBIN = (N + RPB - 1) >> RSH;      // 391
  const int M = NBIN * G;                     // 76636
  const int nb2 = (M + 1023) / 1024;          // 75

  // ws layout (~65.1 MB):
  //   region0 [N*128 u16 = 25.6MB]: epk2 (CSR build) -> h0bf (gemm1..spmm1) -> h2p (gemm2..spmm2)
  //   hbf[N*128 u16] | ip[N+32] | cnt[M+8] | cntoff[M+64] | aux[128] | epk[E] int2 | w1pf | w2p
  ushort_t* h0bf = (ushort_t*)d_ws;
  int2* epk2 = (int2*)d_ws;
  ushort_t* h2p = h0bf;
  ushort_t* hbf = h0bf + (size_t)N * F2;
  int* ip = (int*)(hbf + (size_t)N * F2);
  int* cnt = ip + (N + 32);
  int* cntoff = cnt + M + 8;
  int* aux = cntoff + M + 64;
  int2* epk = (int2*)(aux + 128);
  ushort_t* w1pf = (ushort_t*)(epk + E);      // 8*8*64*8 = 32768 ushorts
  ushort_t* w2p = w1pf + 32768;               // 6144 ushorts

  hipLaunchKernelGGL(k_cnt, dim3(G), dim3(256), 0, stream, erow, cnt, E, G, NBIN);
  hipLaunchKernelGGL(k_scan1, dim3(nb2), dim3(256), 0, stream, cnt, cntoff, aux, M);
  hipLaunchKernelGGL(k_scan_aux, dim3(1), dim3(128), 0, stream, aux, nb2);
  hipLaunchKernelGGL(k_scan_add, dim3(nb2), dim3(256), 0, stream, cntoff, aux, M, E);
  hipLaunchKernelGGL(k_scatter1, dim3(G), dim3(256), 0, stream, erow, ecol_in, ew_in, cntoff, epk2, E, G, NBIN);
  hipLaunchKernelGGL(k_binsort, dim3(NBIN), dim3(256), 0, stream, cntoff, epk2, ip, epk, G, NBIN, N, E);
  hipLaunchKernelGGL(k_w1prep, dim3(128), dim3(256), 0, stream, W1, w1pf);
  hipLaunchKernelGGL(k_w2prep, dim3((4 * 3 * 64 * 8 + 255) / 256), dim3(256), 0, stream, W2, w2p);
  hipLaunchKernelGGL(k_gemm1, dim3((N + 63) / 64), dim3(256), 0, stream, x, w1pf, h0bf, N);
  hipLaunchKernelGGL(k_spmm1, dim3(N / 4), dim3(256), 0, stream, ip, epk, h0bf, b1, hbf);
  hipLaunchKernelGGL(k_gemm2, dim3((N + 63) / 64), dim3(256), 0, stream, hbf, w2p, h2p, N);
  hipLaunchKernelGGL(k_spmm2lsm, dim3(N / 4), dim3(256), 0, stream, ip, epk, h2p, b2, out);
}

// Round 11
// 221.119 us; speedup vs baseline: 3.3543x; 1.0104x over previous
//
#include <hip/hip_runtime.h>
#include <math.h>

#define F1 256
#define F2 128
#define F3 40
#define H2S 64    // padded h2 row stride (one 128B cacheline)
#define RPB 256   // rows per bin (counting-sort granularity)
#define RSH 8
#define TPB 8192  // edges per block in cnt/scatter1 passes

typedef unsigned short ushort_t;
typedef __attribute__((ext_vector_type(8))) short bf16x8;
typedef __attribute__((ext_vector_type(4))) float f32x4;

__device__ inline ushort_t f2bf(float f) {
  unsigned u = __builtin_bit_cast(unsigned, f);
  u += 0x7FFF + ((u >> 16) & 1);
  return (ushort_t)(u >> 16);
}
__device__ inline float bf2f(ushort_t b) {
  unsigned u = ((unsigned)b) << 16;
  return __builtin_bit_cast(float, u);
}
__device__ inline float i2f(int b) { return __builtin_bit_cast(float, b); }

// ---------------- CSR build: 2-level counting sort (XCD-write-amplification-free) ----------------

__global__ __launch_bounds__(256) void k_cnt(const int* __restrict__ row, int* __restrict__ cnt,
                                             int E, int G, int NBIN) {
  __shared__ int h[400];
  int tid = threadIdx.x, blk = blockIdx.x;
  for (int i = tid; i < NBIN; i += 256) h[i] = 0;
  __syncthreads();
  int base = blk * TPB, lim = min(base + TPB, E);
  for (int i = base + tid; i < lim; i += 256) atomicAdd(&h[row[i] >> RSH], 1);
  __syncthreads();
  for (int i = tid; i < NBIN; i += 256) cnt[i * G + blk] = h[i];
}

__global__ __launch_bounds__(256) void k_scan1(const int* __restrict__ in, int* __restrict__ out,
                                               int* __restrict__ aux, int n) {
  __shared__ int lds[256];
  int tid = threadIdx.x;
  int base = blockIdx.x * 1024 + tid * 4;
  int v0 = 0, v1 = 0, v2 = 0, v3 = 0;
  if (base + 0 < n) v0 = in[base + 0];
  if (base + 1 < n) v1 = in[base + 1];
  if (base + 2 < n) v2 = in[base + 2];
  if (base + 3 < n) v3 = in[base + 3];
  int s = v0 + v1 + v2 + v3;
  lds[tid] = s;
  __syncthreads();
  for (int off = 1; off < 256; off <<= 1) {
    int t = (tid >= off) ? lds[tid - off] : 0;
    __syncthreads();
    lds[tid] += t;
    __syncthreads();
  }
  int excl = (tid > 0) ? lds[tid - 1] : 0;
  if (tid == 255) aux[blockIdx.x] = lds[255];
  if (base + 0 < n) out[base + 0] = excl;
  if (base + 1 < n) out[base + 1] = excl + v0;
  if (base + 2 < n) out[base + 2] = excl + v0 + v1;
  if (base + 3 < n) out[base + 3] = excl + v0 + v1 + v2;
}

__global__ __launch_bounds__(128) void k_scan_aux(int* __restrict__ aux, int nb) {
  __shared__ int lds[128];
  int tid = threadIdx.x;
  int v = (tid < nb) ? aux[tid] : 0;
  lds[tid] = v;
  __syncthreads();
  for (int off = 1; off < 128; off <<= 1) {
    int t = (tid >= off) ? lds[tid - off] : 0;
    __syncthreads();
    lds[tid] += t;
    __syncthreads();
  }
  int excl = (tid > 0) ? lds[tid - 1] : 0;
  if (tid < nb) aux[tid] = excl;
}

__global__ __launch_bounds__(256) void k_scan_add(int* __restrict__ out, const int* __restrict__ aux,
                                                  int n, int E) {
  int add = aux[blockIdx.x];
  int base = blockIdx.x * 1024 + threadIdx.x * 4;
#pragma unroll
  for (int i = 0; i < 4; i++)
    if (base + i < n) out[base + i] += add;
  if (blockIdx.x == 0 && threadIdx.x == 0) out[n] = E;  // sentinel: cntoff[M] = E
}

__global__ __launch_bounds__(256) void k_scatter1(const int* __restrict__ row, const int* __restrict__ col,
                                                  const float* __restrict__ w, const int* __restrict__ cntoff,
                                                  int2* __restrict__ epk2, int E, int G, int NBIN) {
  __shared__ int cur[400];
  int tid = threadIdx.x, blk = blockIdx.x;
  for (int i = tid; i < NBIN; i += 256) cur[i] = cntoff[i * G + blk];
  __syncthreads();
  int base = blk * TPB, lim = min(base + TPB, E);
  for (int i = base + tid; i < lim; i += 256) {
    int r = row[i];
    int pos = atomicAdd(&cur[r >> RSH], 1);
    epk2[pos] = make_int2(((r & (RPB - 1)) << 17) | col[i], __builtin_bit_cast(int, w[i]));
  }
}

__global__ __launch_bounds__(256) void k_binsort(const int* __restrict__ cntoff, const int2* __restrict__ epk2,
                                                 int* __restrict__ ip, int2* __restrict__ epk,
                                                 int G, int NBIN, int N, int E) {
  __shared__ int sc[256], cur[256];
  int tid = threadIdx.x, b = blockIdx.x;
  int s = cntoff[b * G], eend = cntoff[(b + 1) * G];
  cur[tid] = 0;
  __syncthreads();
  for (int i = s + tid; i < eend; i += 256) atomicAdd(&cur[epk2[i].x >> 17], 1);
  __syncthreads();
  int d = cur[tid];
  sc[tid] = d;
  __syncthreads();
  for (int o = 1; o < 256; o <<= 1) {
    int t = (tid >= o) ? sc[tid - o] : 0;
    __syncthreads();
    sc[tid] += t;
    __syncthreads();
  }
  int excl = (tid > 0) ? sc[tid - 1] : 0;
  __syncthreads();
  cur[tid] = excl;
  int gr = (b << RSH) + tid;
  if (gr <= N) ip[gr] = s + excl;
  if (b == 0 && tid == 0) ip[N] = E;
  __syncthreads();
  for (int i = s + tid; i < eend; i += 256) {
    int2 rec = epk2[i];
    int local = rec.x >> 17, c = rec.x & 0x1FFFF;
    int p = s + atomicAdd(&cur[local], 1);
    epk[p] = make_int2(c, rec.y);
  }
}

// ---------------- W1 prep: fp32 [256][128] -> per-lane B-fragments [kt 8][t 8][lane 64][8] ----------------
__global__ __launch_bounds__(256) void k_w1prep(const float* __restrict__ W1, ushort_t* __restrict__ w1pf) {
  int idx = blockIdx.x * 256 + threadIdx.x;
  if (idx < 8 * 8 * 64 * 8) {
    int j = idx & 7;
    int l = (idx >> 3) & 63;
    int t = (idx >> 9) & 7;
    int kt = idx >> 12;
    int k = kt * 32 + (l >> 4) * 8 + j;
    int c = t * 16 + (l & 15);
    w1pf[idx] = f2bf(W1[(size_t)k * F2 + c]);
  }
}

// ---------------- W2 prep: fp32 [128][40] -> per-lane B-fragments [kt 4][t 3][lane 64][8] ----------------
__global__ __launch_bounds__(256) void k_w2prep(const float* __restrict__ W2, ushort_t* __restrict__ w2p) {
  int idx = blockIdx.x * 256 + threadIdx.x;
  if (idx < 4 * 3 * 64 * 8) {
    int j = idx & 7;
    int rem = idx >> 3;
    int l = rem & 63;
    int g = rem >> 6;       // 0..11
    int t = g % 3, kt = g / 3;
    int colc = t * 16 + (l & 15);
    int k = kt * 32 + (l >> 4) * 8 + j;
    w2p[idx] = (colc < F3) ? f2bf(W2[(size_t)k * F3 + colc]) : (ushort_t)0;
  }
}

// ---------------- GEMM1 (MFMA, no LDS): h0[N,128] = x[N,256] @ W1, store bf16 ----------------
__global__ __launch_bounds__(256) void k_gemm1(const float* __restrict__ x, const ushort_t* __restrict__ w1pf,
                                               ushort_t* __restrict__ h0bf, int N) {
  const int tid = threadIdx.x;
  const int lane = tid & 63;
  const int w = tid >> 6;
  const int r0 = blockIdx.x * 64;
  const int arow = r0 + w * 16 + (lane & 15);
  const int ar = (arow < N) ? arow : 0;
  const int kg = (lane >> 4) * 8;
  const float* xr = x + (size_t)ar * F1 + kg;

  f32x4 acc[8];
#pragma unroll
  for (int t = 0; t < 8; ++t) acc[t] = (f32x4){0.f, 0.f, 0.f, 0.f};

#pragma unroll
  for (int kt = 0; kt < 8; ++kt) {
    float4 v0 = *(const float4*)(xr + kt * 32);
    float4 v1 = *(const float4*)(xr + kt * 32 + 4);
    bf16x8 a;
    a[0] = (short)f2bf(v0.x); a[1] = (short)f2bf(v0.y);
    a[2] = (short)f2bf(v0.z); a[3] = (short)f2bf(v0.w);
    a[4] = (short)f2bf(v1.x); a[5] = (short)f2bf(v1.y);
    a[6] = (short)f2bf(v1.z); a[7] = (short)f2bf(v1.w);
#pragma unroll
    for (int t = 0; t < 8; ++t) {
      bf16x8 b = *(const bf16x8*)(w1pf + (size_t)(((kt * 8 + t) * 64) + lane) * 8);
      acc[t] = __builtin_amdgcn_mfma_f32_16x16x32_bf16(a, b, acc[t], 0, 0, 0);
    }
  }

  // C/D layout (HW-verified): col = lane&15, row = (lane>>4)*4 + j
#pragma unroll
  for (int t = 0; t < 8; ++t) {
    int gc = t * 16 + (lane & 15);
#pragma unroll
    for (int j = 0; j < 4; ++j) {
      int gr = r0 + w * 16 + (lane >> 4) * 4 + j;
      if (gr < N) h0bf[(size_t)gr * F2 + gc] = f2bf(acc[t][j]);
    }
  }
}

// ---------------- SpMM1 (F=128, bf16 gather) + b1 + relu ----------------
// wave/node; 8-wide batched phases (records -> 8 independent gathers -> FMAs) for real MLP
__global__ __launch_bounds__(256) void k_spmm1(const int* __restrict__ ip, const int2* __restrict__ epk,
                                               const ushort_t* __restrict__ h0bf,
                                               const float* __restrict__ b1, ushort_t* __restrict__ hbf) {
  int node = blockIdx.x * 4 + (threadIdx.x >> 6);
  int lane = threadIdx.x & 63;
  int e0 = __builtin_amdgcn_readfirstlane(ip[node]);
  int e1 = __builtin_amdgcn_readfirstlane(ip[node + 1]);
  const ushort2* hb = (const ushort2*)h0bf;  // row stride F2/2 = 64 ushort2
  float ax0 = 0.f, ay0 = 0.f, ax1 = 0.f, ay1 = 0.f;
  float ax2 = 0.f, ay2 = 0.f, ax3 = 0.f, ay3 = 0.f;
  float ax4 = 0.f, ay4 = 0.f, ax5 = 0.f, ay5 = 0.f;
  float ax6 = 0.f, ay6 = 0.f, ax7 = 0.f, ay7 = 0.f;
  for (int e = e0; e < e1; e += 8) {
    int i1 = e1 - 1;
    // phase 1: edge records (uniform)
    int2 p0 = epk[(e + 0 < e1) ? e + 0 : i1];
    int2 p1 = epk[(e + 1 < e1) ? e + 1 : i1];
    int2 p2 = epk[(e + 2 < e1) ? e + 2 : i1];
    int2 p3 = epk[(e + 3 < e1) ? e + 3 : i1];
    int2 p4 = epk[(e + 4 < e1) ? e + 4 : i1];
    int2 p5 = epk[(e + 5 < e1) ? e + 5 : i1];
    int2 p6 = epk[(e + 6 < e1) ? e + 6 : i1];
    int2 p7 = epk[(e + 7 < e1) ? e + 7 : i1];
    // phase 2: 8 independent gathers
    ushort2 v0 = hb[(size_t)p0.x * 64 + lane];
    ushort2 v1 = hb[(size_t)p1.x * 64 + lane];
    ushort2 v2 = hb[(size_t)p2.x * 64 + lane];
    ushort2 v3 = hb[(size_t)p3.x * 64 + lane];
    ushort2 v4 = hb[(size_t)p4.x * 64 + lane];
    ushort2 v5 = hb[(size_t)p5.x * 64 + lane];
    ushort2 v6 = hb[(size_t)p6.x * 64 + lane];
    ushort2 v7 = hb[(size_t)p7.x * 64 + lane];
    // phase 3: FMAs (zero weight for clamped slots)
    float w0 = (e + 0 < e1) ? i2f(p0.y) : 0.f;
    float w1 = (e + 1 < e1) ? i2f(p1.y) : 0.f;
    float w2 = (e + 2 < e1) ? i2f(p2.y) : 0.f;
    float w3 = (e + 3 < e1) ? i2f(p3.y) : 0.f;
    float w4 = (e + 4 < e1) ? i2f(p4.y) : 0.f;
    float w5 = (e + 5 < e1) ? i2f(p5.y) : 0.f;
    float w6 = (e + 6 < e1) ? i2f(p6.y) : 0.f;
    float w7 = (e + 7 < e1) ? i2f(p7.y) : 0.f;
    ax0 = fmaf(w0, bf2f(v0.x), ax0); ay0 = fmaf(w0, bf2f(v0.y), ay0);
    ax1 = fmaf(w1, bf2f(v1.x), ax1); ay1 = fmaf(w1, bf2f(v1.y), ay1);
    ax2 = fmaf(w2, bf2f(v2.x), ax2); ay2 = fmaf(w2, bf2f(v2.y), ay2);
    ax3 = fmaf(w3, bf2f(v3.x), ax3); ay3 = fmaf(w3, bf2f(v3.y), ay3);
    ax4 = fmaf(w4, bf2f(v4.x), ax4); ay4 = fmaf(w4, bf2f(v4.y), ay4);
    ax5 = fmaf(w5, bf2f(v5.x), ax5); ay5 = fmaf(w5, bf2f(v5.y), ay5);
    ax6 = fmaf(w6, bf2f(v6.x), ax6); ay6 = fmaf(w6, bf2f(v6.y), ay6);
    ax7 = fmaf(w7, bf2f(v7.x), ax7); ay7 = fmaf(w7, bf2f(v7.y), ay7);
  }
  float axs = ((ax0 + ax1) + (ax2 + ax3)) + ((ax4 + ax5) + (ax6 + ax7));
  float ays = ((ay0 + ay1) + (ay2 + ay3)) + ((ay4 + ay5) + (ay6 + ay7));
  float2 bb = *(const float2*)(b1 + lane * 2);
  ushort2 r;
  r.x = f2bf(fmaxf(axs + bb.x, 0.f));
  r.y = f2bf(fmaxf(ays + bb.y, 0.f));
  *(ushort2*)(hbf + (size_t)node * F2 + lane * 2) = r;
}

// ---------------- GEMM2 (MFMA, no LDS): h2p[N,64pad] = h[N,128] @ W2[128,40] ----------------
__global__ __launch_bounds__(256) void k_gemm2(const ushort_t* __restrict__ hbf, const ushort_t* __restrict__ w2p,
                                               ushort_t* __restrict__ h2p, int N) {
  const int tid = threadIdx.x;
  const int lane = tid & 63;
  const int w = tid >> 6;
  const int r0 = blockIdx.x * 64;
  const int arow = r0 + w * 16 + (lane & 15);
  const int ar = (arow < N) ? arow : 0;
  const int kg = (lane >> 4) * 8;

  bf16x8 a[4];
#pragma unroll
  for (int kt = 0; kt < 4; ++kt)
    a[kt] = *(const bf16x8*)(hbf + (size_t)ar * F2 + kt * 32 + kg);

  f32x4 acc[3];
#pragma unroll
  for (int t = 0; t < 3; ++t) acc[t] = (f32x4){0.f, 0.f, 0.f, 0.f};

#pragma unroll
  for (int kt = 0; kt < 4; ++kt) {
#pragma unroll
    for (int t = 0; t < 3; ++t) {
      bf16x8 b = *(const bf16x8*)(w2p + (size_t)(((kt * 3 + t) * 64) + lane) * 8);
      acc[t] = __builtin_amdgcn_mfma_f32_16x16x32_bf16(a[kt], b, acc[t], 0, 0, 0);
    }
  }

#pragma unroll
  for (int t = 0; t < 3; ++t) {
    int gc = t * 16 + (lane & 15);
    if (gc < F3) {
#pragma unroll
      for (int j = 0; j < 4; ++j) {
        int gr = r0 + w * 16 + (lane >> 4) * 4 + j;
        if (gr < N) h2p[(size_t)gr * H2S + gc] = f2bf(acc[t][j]);
      }
    }
  }
  for (int idx = tid; idx < 64 * 24; idx += 256) {
    int row = idx / 24, pc = F3 + idx % 24;
    int gr = r0 + row;
    if (gr < N) h2p[(size_t)gr * H2S + pc] = 0;
  }
}

// ---------------- SpMM2 (padded rows) + b2 + log_softmax fused, batched 8-deep ----------------
__global__ __launch_bounds__(256) void k_spmm2lsm(const int* __restrict__ ip, const int2* __restrict__ epk,
                                                  const ushort_t* __restrict__ h2p,
                                                  const float* __restrict__ b2, float* __restrict__ out) {
  int node = blockIdx.x * 4 + (threadIdx.x >> 6);
  int lane = threadIdx.x & 63;
  int e0 = __builtin_amdgcn_readfirstlane(ip[node]);
  int e1 = __builtin_amdgcn_readfirstlane(ip[node + 1]);
  float a0 = 0.f, a1 = 0.f, a2 = 0.f, a3 = 0.f;
  float a4 = 0.f, a5 = 0.f, a6 = 0.f, a7 = 0.f;
  for (int e = e0; e < e1; e += 8) {
    int i1 = e1 - 1;
    int2 p0 = epk[(e + 0 < e1) ? e + 0 : i1];
    int2 p1 = epk[(e + 1 < e1) ? e + 1 : i1];
    int2 p2 = epk[(e + 2 < e1) ? e + 2 : i1];
    int2 p3 = epk[(e + 3 < e1) ? e + 3 : i1];
    int2 p4 = epk[(e + 4 < e1) ? e + 4 : i1];
    int2 p5 = epk[(e + 5 < e1) ? e + 5 : i1];
    int2 p6 = epk[(e + 6 < e1) ? e + 6 : i1];
    int2 p7 = epk[(e + 7 < e1) ? e + 7 : i1];
    ushort_t u0 = h2p[(size_t)p0.x * H2S + lane];
    ushort_t u1 = h2p[(size_t)p1.x * H2S + lane];
    ushort_t u2 = h2p[(size_t)p2.x * H2S + lane];
    ushort_t u3 = h2p[(size_t)p3.x * H2S + lane];
    ushort_t u4 = h2p[(size_t)p4.x * H2S + lane];
    ushort_t u5 = h2p[(size_t)p5.x * H2S + lane];
    ushort_t u6 = h2p[(size_t)p6.x * H2S + lane];
    ushort_t u7 = h2p[(size_t)p7.x * H2S + lane];
    float w0 = (e + 0 < e1) ? i2f(p0.y) : 0.f;
    float w1 = (e + 1 < e1) ? i2f(p1.y) : 0.f;
    float w2 = (e + 2 < e1) ? i2f(p2.y) : 0.f;
    float w3 = (e + 3 < e1) ? i2f(p3.y) : 0.f;
    float w4 = (e + 4 < e1) ? i2f(p4.y) : 0.f;
    float w5 = (e + 5 < e1) ? i2f(p5.y) : 0.f;
    float w6 = (e + 6 < e1) ? i2f(p6.y) : 0.f;
    float w7 = (e + 7 < e1) ? i2f(p7.y) : 0.f;
    a0 = fmaf(w0, bf2f(u0), a0);
    a1 = fmaf(w1, bf2f(u1), a1);
    a2 = fmaf(w2, bf2f(u2), a2);
    a3 = fmaf(w3, bf2f(u3), a3);
    a4 = fmaf(w4, bf2f(u4), a4);
    a5 = fmaf(w5, bf2f(u5), a5);
    a6 = fmaf(w6, bf2f(u6), a6);
    a7 = fmaf(w7, bf2f(u7), a7);
  }
  float acc = ((a0 + a1) + (a2 + a3)) + ((a4 + a5) + (a6 + a7));
  float logit = (lane < F3) ? (acc + b2[lane]) : -INFINITY;
  float m = logit;
#pragma unroll
  for (int off = 32; off > 0; off >>= 1) m = fmaxf(m, __shfl_xor(m, off));
  float ex = (lane < F3) ? __expf(logit - m) : 0.f;
  float s = ex;
#pragma unroll
  for (int off = 32; off > 0; off >>= 1) s += __shfl_xor(s, off);
  if (lane < F3) out[(size_t)node * F3 + lane] = logit - m - __logf(s);
}

extern "C" void kernel_launch(void* const* d_in, const int* in_sizes, int n_in,
                              void* d_out, int out_size, void* d_ws, size_t ws_size,
                              hipStream_t stream) {
  const float* x     = (const float*)d_in[0];
  const int* erow    = (const int*)d_in[1];
  const int* ecol_in = (const int*)d_in[2];
  const float* ew_in = (const float*)d_in[3];
  const float* W1    = (const float*)d_in[4];
  const float* b1    = (const float*)d_in[5];
  const float* W2    = (const float*)d_in[6];
  const float* b2    = (const float*)d_in[7];
  float* out = (float*)d_out;

  const int N = in_sizes[0] / F1;  // 100000
  const int E = in_sizes[1];       // 1600000

  const int G = (E + TPB - 1) / TPB;          // 196
  const int NBIN = (N + RPB - 1) >> RSH;      // 391
  const int M = NBIN * G;                     // 76636
  const int nb2 = (M + 1023) / 1024;          // 75

  // ws layout (~65.1 MB):
  //   region0 [N*128 u16 = 25.6MB]: epk2 (CSR build) -> h0bf (gemm1..spmm1) -> h2p (gemm2..spmm2)
  //   hbf[N*128 u16] | ip[N+32] | cnt[M+8] | cntoff[M+64] | aux[128] | epk[E] int2 | w1pf | w2p
  ushort_t* h0bf = (ushort_t*)d_ws;
  int2* epk2 = (int2*)d_ws;
  ushort_t* h2p = h0bf;
  ushort_t* hbf = h0bf + (size_t)N * F2;
  int* ip = (int*)(hbf + (size_t)N * F2);
  int* cnt = ip + (N + 32);
  int* cntoff = cnt + M + 8;
  int* aux = cntoff + M + 64;
  int2* epk = (int2*)(aux + 128);
  ushort_t* w1pf = (ushort_t*)(epk + E);      // 8*8*64*8 = 32768 ushorts
  ushort_t* w2p = w1pf + 32768;               // 6144 ushorts

  hipLaunchKernelGGL(k_cnt, dim3(G), dim3(256), 0, stream, erow, cnt, E, G, NBIN);
  hipLaunchKernelGGL(k_scan1, dim3(nb2), dim3(256), 0, stream, cnt, cntoff, aux, M);
  hipLaunchKernelGGL(k_scan_aux, dim3(1), dim3(128), 0, stream, aux, nb2);
  hipLaunchKernelGGL(k_scan_add, dim3(nb2), dim3(256), 0, stream, cntoff, aux, M, E);
  hipLaunchKernelGGL(k_scatter1, dim3(G), dim3(256), 0, stream, erow, ecol_in, ew_in, cntoff, epk2, E, G, NBIN);
  hipLaunchKernelGGL(k_binsort, dim3(NBIN), dim3(256), 0, stream, cntoff, epk2, ip, epk, G, NBIN, N, E);
  hipLaunchKernelGGL(k_w1prep, dim3(128), dim3(256), 0, stream, W1, w1pf);
  hipLaunchKernelGGL(k_w2prep, dim3((4 * 3 * 64 * 8 + 255) / 256), dim3(256), 0, stream, W2, w2p);
  hipLaunchKernelGGL(k_gemm1, dim3((N + 63) / 64), dim3(256), 0, stream, x, w1pf, h0bf, N);
  hipLaunchKernelGGL(k_spmm1, dim3(N / 4), dim3(256), 0, stream, ip, epk, h0bf, b1, hbf);
  hipLaunchKernelGGL(k_gemm2, dim3((N + 63) / 64), dim3(256), 0, stream, hbf, w2p, h2p, N);
  hipLaunchKernelGGL(k_spmm2lsm, dim3(N / 4), dim3(256), 0, stream, ip, epk, h2p, b2, out);
}

// Round 12
// 210.480 us; speedup vs baseline: 3.5238x; 1.0505x over previous
//
#include <hip/hip_runtime.h>
#include <math.h>

#define F1 256
#define F2 128
#define F3 40
#define H2S 64    // padded h2 fp8 row stride in bytes (half cacheline)
#define RPB 256   // rows per bin (counting-sort granularity)
#define RSH 8
#define TPB 8192  // edges per block in cnt/scatter1 passes

typedef unsigned short ushort_t;
typedef unsigned char uchar_t;
typedef __attribute__((ext_vector_type(8))) short bf16x8;
typedef __attribute__((ext_vector_type(4))) float f32x4;
typedef __attribute__((ext_vector_type(2))) float f32x2;

__device__ inline ushort_t f2bf(float f) {
  unsigned u = __builtin_bit_cast(unsigned, f);
  u += 0x7FFF + ((u >> 16) & 1);
  return (ushort_t)(u >> 16);
}
__device__ inline float bf2f(ushort_t b) {
  unsigned u = ((unsigned)b) << 16;
  return __builtin_bit_cast(float, u);
}
__device__ inline float i2f(int b) { return __builtin_bit_cast(float, b); }
// fp8 e4m3 (OCP) hardware converts
__device__ inline uchar_t f2fp8(float f) {
  return (uchar_t)(__builtin_amdgcn_cvt_pk_fp8_f32(f, 0.f, 0, false) & 0xff);
}
__device__ inline f32x2 fp8pair2f(unsigned u) {
  return __builtin_amdgcn_cvt_pk_f32_fp8(u, false);
}
__device__ inline float fp82f(unsigned u) {
  return __builtin_amdgcn_cvt_f32_fp8(u, 0);
}

// ---------------- CSR build: 2-level counting sort (XCD-write-amplification-free) ----------------

__global__ __launch_bounds__(256) void k_cnt(const int* __restrict__ row, int* __restrict__ cnt,
                                             int E, int G, int NBIN) {
  __shared__ int h[400];
  int tid = threadIdx.x, blk = blockIdx.x;
  for (int i = tid; i < NBIN; i += 256) h[i] = 0;
  __syncthreads();
  int base = blk * TPB, lim = min(base + TPB, E);
  for (int i = base + tid; i < lim; i += 256) atomicAdd(&h[row[i] >> RSH], 1);
  __syncthreads();
  for (int i = tid; i < NBIN; i += 256) cnt[i * G + blk] = h[i];
}

__global__ __launch_bounds__(256) void k_scan1(const int* __restrict__ in, int* __restrict__ out,
                                               int* __restrict__ aux, int n) {
  __shared__ int lds[256];
  int tid = threadIdx.x;
  int base = blockIdx.x * 1024 + tid * 4;
  int v0 = 0, v1 = 0, v2 = 0, v3 = 0;
  if (base + 0 < n) v0 = in[base + 0];
  if (base + 1 < n) v1 = in[base + 1];
  if (base + 2 < n) v2 = in[base + 2];
  if (base + 3 < n) v3 = in[base + 3];
  int s = v0 + v1 + v2 + v3;
  lds[tid] = s;
  __syncthreads();
  for (int off = 1; off < 256; off <<= 1) {
    int t = (tid >= off) ? lds[tid - off] : 0;
    __syncthreads();
    lds[tid] += t;
    __syncthreads();
  }
  int excl = (tid > 0) ? lds[tid - 1] : 0;
  if (tid == 255) aux[blockIdx.x] = lds[255];
  if (base + 0 < n) out[base + 0] = excl;
  if (base + 1 < n) out[base + 1] = excl + v0;
  if (base + 2 < n) out[base + 2] = excl + v0 + v1;
  if (base + 3 < n) out[base + 3] = excl + v0 + v1 + v2;
}

__global__ __launch_bounds__(128) void k_scan_aux(int* __restrict__ aux, int nb) {
  __shared__ int lds[128];
  int tid = threadIdx.x;
  int v = (tid < nb) ? aux[tid] : 0;
  lds[tid] = v;
  __syncthreads();
  for (int off = 1; off < 128; off <<= 1) {
    int t = (tid >= off) ? lds[tid - off] : 0;
    __syncthreads();
    lds[tid] += t;
    __syncthreads();
  }
  int excl = (tid > 0) ? lds[tid - 1] : 0;
  if (tid < nb) aux[tid] = excl;
}

__global__ __launch_bounds__(256) void k_scan_add(int* __restrict__ out, const int* __restrict__ aux,
                                                  int n, int E) {
  int add = aux[blockIdx.x];
  int base = blockIdx.x * 1024 + threadIdx.x * 4;
#pragma unroll
  for (int i = 0; i < 4; i++)
    if (base + i < n) out[base + i] += add;
  if (blockIdx.x == 0 && threadIdx.x == 0) out[n] = E;  // sentinel: cntoff[M] = E
}

__global__ __launch_bounds__(256) void k_scatter1(const int* __restrict__ row, const int* __restrict__ col,
                                                  const float* __restrict__ w, const int* __restrict__ cntoff,
                                                  int2* __restrict__ epk2, int E, int G, int NBIN) {
  __shared__ int cur[400];
  int tid = threadIdx.x, blk = blockIdx.x;
  for (int i = tid; i < NBIN; i += 256) cur[i] = cntoff[i * G + blk];
  __syncthreads();
  int base = blk * TPB, lim = min(base + TPB, E);
  for (int i = base + tid; i < lim; i += 256) {
    int r = row[i];
    int pos = atomicAdd(&cur[r >> RSH], 1);
    epk2[pos] = make_int2(((r & (RPB - 1)) << 17) | col[i], __builtin_bit_cast(int, w[i]));
  }
}

__global__ __launch_bounds__(256) void k_binsort(const int* __restrict__ cntoff, const int2* __restrict__ epk2,
                                                 int* __restrict__ ip, int2* __restrict__ epk,
                                                 int G, int NBIN, int N, int E) {
  __shared__ int sc[256], cur[256];
  int tid = threadIdx.x, b = blockIdx.x;
  int s = cntoff[b * G], eend = cntoff[(b + 1) * G];
  cur[tid] = 0;
  __syncthreads();
  for (int i = s + tid; i < eend; i += 256) atomicAdd(&cur[epk2[i].x >> 17], 1);
  __syncthreads();
  int d = cur[tid];
  sc[tid] = d;
  __syncthreads();
  for (int o = 1; o < 256; o <<= 1) {
    int t = (tid >= o) ? sc[tid - o] : 0;
    __syncthreads();
    sc[tid] += t;
    __syncthreads();
  }
  int excl = (tid > 0) ? sc[tid - 1] : 0;
  __syncthreads();
  cur[tid] = excl;
  int gr = (b << RSH) + tid;
  if (gr <= N) ip[gr] = s + excl;
  if (b == 0 && tid == 0) ip[N] = E;
  __syncthreads();
  for (int i = s + tid; i < eend; i += 256) {
    int2 rec = epk2[i];
    int local = rec.x >> 17, c = rec.x & 0x1FFFF;
    int p = s + atomicAdd(&cur[local], 1);
    epk[p] = make_int2(c, rec.y);
  }
}

// ---------------- W1 prep: fp32 [256][128] -> per-lane B-fragments [kt 8][t 8][lane 64][8] ----------------
__global__ __launch_bounds__(256) void k_w1prep(const float* __restrict__ W1, ushort_t* __restrict__ w1pf) {
  int idx = blockIdx.x * 256 + threadIdx.x;
  if (idx < 8 * 8 * 64 * 8) {
    int j = idx & 7;
    int l = (idx >> 3) & 63;
    int t = (idx >> 9) & 7;
    int kt = idx >> 12;
    int k = kt * 32 + (l >> 4) * 8 + j;
    int c = t * 16 + (l & 15);
    w1pf[idx] = f2bf(W1[(size_t)k * F2 + c]);
  }
}

// ---------------- W2 prep: fp32 [128][40] -> per-lane B-fragments [kt 4][t 3][lane 64][8] ----------------
__global__ __launch_bounds__(256) void k_w2prep(const float* __restrict__ W2, ushort_t* __restrict__ w2p) {
  int idx = blockIdx.x * 256 + threadIdx.x;
  if (idx < 4 * 3 * 64 * 8) {
    int j = idx & 7;
    int rem = idx >> 3;
    int l = rem & 63;
    int g = rem >> 6;       // 0..11
    int t = g % 3, kt = g / 3;
    int colc = t * 16 + (l & 15);
    int k = kt * 32 + (l >> 4) * 8 + j;
    w2p[idx] = (colc < F3) ? f2bf(W2[(size_t)k * F3 + colc]) : (ushort_t)0;
  }
}

// ---------------- GEMM1 (MFMA, no LDS): h0f8[N,128] = fp8(x[N,256] @ W1) ----------------
__global__ __launch_bounds__(256) void k_gemm1(const float* __restrict__ x, const ushort_t* __restrict__ w1pf,
                                               uchar_t* __restrict__ h0f8, int N) {
  const int tid = threadIdx.x;
  const int lane = tid & 63;
  const int w = tid >> 6;
  const int r0 = blockIdx.x * 64;
  const int arow = r0 + w * 16 + (lane & 15);
  const int ar = (arow < N) ? arow : 0;
  const int kg = (lane >> 4) * 8;
  const float* xr = x + (size_t)ar * F1 + kg;

  f32x4 acc[8];
#pragma unroll
  for (int t = 0; t < 8; ++t) acc[t] = (f32x4){0.f, 0.f, 0.f, 0.f};

#pragma unroll
  for (int kt = 0; kt < 8; ++kt) {
    float4 v0 = *(const float4*)(xr + kt * 32);
    float4 v1 = *(const float4*)(xr + kt * 32 + 4);
    bf16x8 a;
    a[0] = (short)f2bf(v0.x); a[1] = (short)f2bf(v0.y);
    a[2] = (short)f2bf(v0.z); a[3] = (short)f2bf(v0.w);
    a[4] = (short)f2bf(v1.x); a[5] = (short)f2bf(v1.y);
    a[6] = (short)f2bf(v1.z); a[7] = (short)f2bf(v1.w);
#pragma unroll
    for (int t = 0; t < 8; ++t) {
      bf16x8 b = *(const bf16x8*)(w1pf + (size_t)(((kt * 8 + t) * 64) + lane) * 8);
      acc[t] = __builtin_amdgcn_mfma_f32_16x16x32_bf16(a, b, acc[t], 0, 0, 0);
    }
  }

  // C/D layout (HW-verified): col = lane&15, row = (lane>>4)*4 + j
#pragma unroll
  for (int t = 0; t < 8; ++t) {
    int gc = t * 16 + (lane & 15);
#pragma unroll
    for (int j = 0; j < 4; ++j) {
      int gr = r0 + w * 16 + (lane >> 4) * 4 + j;
      if (gr < N) h0f8[(size_t)gr * F2 + gc] = f2fp8(acc[t][j]);
    }
  }
}

// ---------------- SpMM1 (F=128, fp8 gather: 1 line/edge) + b1 + relu -> h bf16 ----------------
__global__ __launch_bounds__(256) void k_spmm1(const int* __restrict__ ip, const int2* __restrict__ epk,
                                               const uchar_t* __restrict__ h0f8,
                                               const float* __restrict__ b1, ushort_t* __restrict__ hbf) {
  int node = blockIdx.x * 4 + (threadIdx.x >> 6);
  int lane = threadIdx.x & 63;
  int e0 = __builtin_amdgcn_readfirstlane(ip[node]);
  int e1 = __builtin_amdgcn_readfirstlane(ip[node + 1]);
  const ushort_t* hb = (const ushort_t*)h0f8;  // 2 fp8 per ushort, row stride 64 ushorts
  float ax0 = 0.f, ay0 = 0.f, ax1 = 0.f, ay1 = 0.f;
  float ax2 = 0.f, ay2 = 0.f, ax3 = 0.f, ay3 = 0.f;
  float ax4 = 0.f, ay4 = 0.f, ax5 = 0.f, ay5 = 0.f;
  float ax6 = 0.f, ay6 = 0.f, ax7 = 0.f, ay7 = 0.f;
  for (int e = e0; e < e1; e += 8) {
    int i1 = e1 - 1;
    int2 p0 = epk[(e + 0 < e1) ? e + 0 : i1];
    int2 p1 = epk[(e + 1 < e1) ? e + 1 : i1];
    int2 p2 = epk[(e + 2 < e1) ? e + 2 : i1];
    int2 p3 = epk[(e + 3 < e1) ? e + 3 : i1];
    int2 p4 = epk[(e + 4 < e1) ? e + 4 : i1];
    int2 p5 = epk[(e + 5 < e1) ? e + 5 : i1];
    int2 p6 = epk[(e + 6 < e1) ? e + 6 : i1];
    int2 p7 = epk[(e + 7 < e1) ? e + 7 : i1];
    unsigned u0 = hb[(size_t)p0.x * 64 + lane];
    unsigned u1 = hb[(size_t)p1.x * 64 + lane];
    unsigned u2 = hb[(size_t)p2.x * 64 + lane];
    unsigned u3 = hb[(size_t)p3.x * 64 + lane];
    unsigned u4 = hb[(size_t)p4.x * 64 + lane];
    unsigned u5 = hb[(size_t)p5.x * 64 + lane];
    unsigned u6 = hb[(size_t)p6.x * 64 + lane];
    unsigned u7 = hb[(size_t)p7.x * 64 + lane];
    float w0 = (e + 0 < e1) ? i2f(p0.y) : 0.f;
    float w1 = (e + 1 < e1) ? i2f(p1.y) : 0.f;
    float w2 = (e + 2 < e1) ? i2f(p2.y) : 0.f;
    float w3 = (e + 3 < e1) ? i2f(p3.y) : 0.f;
    float w4 = (e + 4 < e1) ? i2f(p4.y) : 0.f;
    float w5 = (e + 5 < e1) ? i2f(p5.y) : 0.f;
    float w6 = (e + 6 < e1) ? i2f(p6.y) : 0.f;
    float w7 = (e + 7 < e1) ? i2f(p7.y) : 0.f;
    f32x2 v0 = fp8pair2f(u0); ax0 = fmaf(w0, v0.x, ax0); ay0 = fmaf(w0, v0.y, ay0);
    f32x2 v1 = fp8pair2f(u1); ax1 = fmaf(w1, v1.x, ax1); ay1 = fmaf(w1, v1.y, ay1);
    f32x2 v2 = fp8pair2f(u2); ax2 = fmaf(w2, v2.x, ax2); ay2 = fmaf(w2, v2.y, ay2);
    f32x2 v3 = fp8pair2f(u3); ax3 = fmaf(w3, v3.x, ax3); ay3 = fmaf(w3, v3.y, ay3);
    f32x2 v4 = fp8pair2f(u4); ax4 = fmaf(w4, v4.x, ax4); ay4 = fmaf(w4, v4.y, ay4);
    f32x2 v5 = fp8pair2f(u5); ax5 = fmaf(w5, v5.x, ax5); ay5 = fmaf(w5, v5.y, ay5);
    f32x2 v6 = fp8pair2f(u6); ax6 = fmaf(w6, v6.x, ax6); ay6 = fmaf(w6, v6.y, ay6);
    f32x2 v7 = fp8pair2f(u7); ax7 = fmaf(w7, v7.x, ax7); ay7 = fmaf(w7, v7.y, ay7);
  }
  float axs = ((ax0 + ax1) + (ax2 + ax3)) + ((ax4 + ax5) + (ax6 + ax7));
  float ays = ((ay0 + ay1) + (ay2 + ay3)) + ((ay4 + ay5) + (ay6 + ay7));
  float2 bb = *(const float2*)(b1 + lane * 2);
  ushort2 r;
  r.x = f2bf(fmaxf(axs + bb.x, 0.f));
  r.y = f2bf(fmaxf(ays + bb.y, 0.f));
  *(ushort2*)(hbf + (size_t)node * F2 + lane * 2) = r;
}

// ---------------- GEMM2 (MFMA, no LDS): h2f8[N,64B] = fp8(h[N,128] @ W2[128,40]) ----------------
__global__ __launch_bounds__(256) void k_gemm2(const ushort_t* __restrict__ hbf, const ushort_t* __restrict__ w2p,
                                               uchar_t* __restrict__ h2f8, int N) {
  const int tid = threadIdx.x;
  const int lane = tid & 63;
  const int w = tid >> 6;
  const int r0 = blockIdx.x * 64;
  const int arow = r0 + w * 16 + (lane & 15);
  const int ar = (arow < N) ? arow : 0;
  const int kg = (lane >> 4) * 8;

  bf16x8 a[4];
#pragma unroll
  for (int kt = 0; kt < 4; ++kt)
    a[kt] = *(const bf16x8*)(hbf + (size_t)ar * F2 + kt * 32 + kg);

  f32x4 acc[3];
#pragma unroll
  for (int t = 0; t < 3; ++t) acc[t] = (f32x4){0.f, 0.f, 0.f, 0.f};

#pragma unroll
  for (int kt = 0; kt < 4; ++kt) {
#pragma unroll
    for (int t = 0; t < 3; ++t) {
      bf16x8 b = *(const bf16x8*)(w2p + (size_t)(((kt * 3 + t) * 64) + lane) * 8);
      acc[t] = __builtin_amdgcn_mfma_f32_16x16x32_bf16(a[kt], b, acc[t], 0, 0, 0);
    }
  }

#pragma unroll
  for (int t = 0; t < 3; ++t) {
    int gc = t * 16 + (lane & 15);
    if (gc < F3) {
#pragma unroll
      for (int j = 0; j < 4; ++j) {
        int gr = r0 + w * 16 + (lane >> 4) * 4 + j;
        if (gr < N) h2f8[(size_t)gr * H2S + gc] = f2fp8(acc[t][j]);
      }
    }
  }
  for (int idx = tid; idx < 64 * 24; idx += 256) {
    int row = idx / 24, pc = F3 + idx % 24;
    int gr = r0 + row;
    if (gr < N) h2f8[(size_t)gr * H2S + pc] = 0;
  }
}

// ---------------- SpMM2 (fp8 64B rows) + b2 + log_softmax fused, batched 8-deep ----------------
__global__ __launch_bounds__(256) void k_spmm2lsm(const int* __restrict__ ip, const int2* __restrict__ epk,
                                                  const uchar_t* __restrict__ h2f8,
                                                  const float* __restrict__ b2, float* __restrict__ out) {
  int node = blockIdx.x * 4 + (threadIdx.x >> 6);
  int lane = threadIdx.x & 63;
  int e0 = __builtin_amdgcn_readfirstlane(ip[node]);
  int e1 = __builtin_amdgcn_readfirstlane(ip[node + 1]);
  float a0 = 0.f, a1 = 0.f, a2 = 0.f, a3 = 0.f;
  float a4 = 0.f, a5 = 0.f, a6 = 0.f, a7 = 0.f;
  for (int e = e0; e < e1; e += 8) {
    int i1 = e1 - 1;
    int2 p0 = epk[(e + 0 < e1) ? e + 0 : i1];
    int2 p1 = epk[(e + 1 < e1) ? e + 1 : i1];
    int2 p2 = epk[(e + 2 < e1) ? e + 2 : i1];
    int2 p3 = epk[(e + 3 < e1) ? e + 3 : i1];
    int2 p4 = epk[(e + 4 < e1) ? e + 4 : i1];
    int2 p5 = epk[(e + 5 < e1) ? e + 5 : i1];
    int2 p6 = epk[(e + 6 < e1) ? e + 6 : i1];
    int2 p7 = epk[(e + 7 < e1) ? e + 7 : i1];
    unsigned u0 = h2f8[(size_t)p0.x * H2S + lane];
    unsigned u1 = h2f8[(size_t)p1.x * H2S + lane];
    unsigned u2 = h2f8[(size_t)p2.x * H2S + lane];
    unsigned u3 = h2f8[(size_t)p3.x * H2S + lane];
    unsigned u4 = h2f8[(size_t)p4.x * H2S + lane];
    unsigned u5 = h2f8[(size_t)p5.x * H2S + lane];
    unsigned u6 = h2f8[(size_t)p6.x * H2S + lane];
    unsigned u7 = h2f8[(size_t)p7.x * H2S + lane];
    float w0 = (e + 0 < e1) ? i2f(p0.y) : 0.f;
    float w1 = (e + 1 < e1) ? i2f(p1.y) : 0.f;
    float w2 = (e + 2 < e1) ? i2f(p2.y) : 0.f;
    float w3 = (e + 3 < e1) ? i2f(p3.y) : 0.f;
    float w4 = (e + 4 < e1) ? i2f(p4.y) : 0.f;
    float w5 = (e + 5 < e1) ? i2f(p5.y) : 0.f;
    float w6 = (e + 6 < e1) ? i2f(p6.y) : 0.f;
    float w7 = (e + 7 < e1) ? i2f(p7.y) : 0.f;
    a0 = fmaf(w0, fp82f(u0), a0);
    a1 = fmaf(w1, fp82f(u1), a1);
    a2 = fmaf(w2, fp82f(u2), a2);
    a3 = fmaf(w3, fp82f(u3), a3);
    a4 = fmaf(w4, fp82f(u4), a4);
    a5 = fmaf(w5, fp82f(u5), a5);
    a6 = fmaf(w6, fp82f(u6), a6);
    a7 = fmaf(w7, fp82f(u7), a7);
  }
  float acc = ((a0 + a1) + (a2 + a3)) + ((a4 + a5) + (a6 + a7));
  float logit = (lane < F3) ? (acc + b2[lane]) : -INFINITY;
  float m = logit;
#pragma unroll
  for (int off = 32; off > 0; off >>= 1) m = fmaxf(m, __shfl_xor(m, off));
  float ex = (lane < F3) ? __expf(logit - m) : 0.f;
  float s = ex;
#pragma unroll
  for (int off = 32; off > 0; off >>= 1) s += __shfl_xor(s, off);
  if (lane < F3) out[(size_t)node * F3 + lane] = logit - m - __logf(s);
}

extern "C" void kernel_launch(void* const* d_in, const int* in_sizes, int n_in,
                              void* d_out, int out_size, void* d_ws, size_t ws_size,
                              hipStream_t stream) {
  const float* x     = (const float*)d_in[0];
  const int* erow    = (const int*)d_in[1];
  const int* ecol_in = (const int*)d_in[2];
  const float* ew_in = (const float*)d_in[3];
  const float* W1    = (const float*)d_in[4];
  const float* b1    = (const float*)d_in[5];
  const float* W2    = (const float*)d_in[6];
  const float* b2    = (const float*)d_in[7];
  float* out = (float*)d_out;

  const int N = in_sizes[0] / F1;  // 100000
  const int E = in_sizes[1];       // 1600000

  const int G = (E + TPB - 1) / TPB;          // 196
  const int NBIN = (N + RPB - 1) >> RSH;      // 391
  const int M = NBIN * G;                     // 76636
  const int nb2 = (M + 1023) / 1024;          // 75

  // ws layout (~65.1 MB, unchanged footprint):
  //   region0 [25.6MB]: epk2 (CSR build) -> h0f8[N*128 B] (gemm1..spmm1) -> h2f8[N*64 B] (gemm2..spmm2)
  //   hbf[N*128 u16] | ip[N+32] | cnt[M+8] | cntoff[M+64] | aux[128] | epk[E] int2 | w1pf | w2p
  uchar_t* region0 = (uchar_t*)d_ws;
  int2* epk2 = (int2*)d_ws;
  uchar_t* h0f8 = region0;
  uchar_t* h2f8 = region0;
  ushort_t* hbf = (ushort_t*)(region0 + (size_t)N * F2 * 2);
  int* ip = (int*)(hbf + (size_t)N * F2);
  int* cnt = ip + (N + 32);
  int* cntoff = cnt + M + 8;
  int* aux = cntoff + M + 64;
  int2* epk = (int2*)(aux + 128);
  ushort_t* w1pf = (ushort_t*)(epk + E);      // 8*8*64*8 = 32768 ushorts
  ushort_t* w2p = w1pf + 32768;               // 6144 ushorts

  hipLaunchKernelGGL(k_cnt, dim3(G), dim3(256), 0, stream, erow, cnt, E, G, NBIN);
  hipLaunchKernelGGL(k_scan1, dim3(nb2), dim3(256), 0, stream, cnt, cntoff, aux, M);
  hipLaunchKernelGGL(k_scan_aux, dim3(1), dim3(128), 0, stream, aux, nb2);
  hipLaunchKernelGGL(k_scan_add, dim3(nb2), dim3(256), 0, stream, cntoff, aux, M, E);
  hipLaunchKernelGGL(k_scatter1, dim3(G), dim3(256), 0, stream, erow, ecol_in, ew_in, cntoff, epk2, E, G, NBIN);
  hipLaunchKernelGGL(k_binsort, dim3(NBIN), dim3(256), 0, stream, cntoff, epk2, ip, epk, G, NBIN, N, E);
  hipLaunchKernelGGL(k_w1prep, dim3(128), dim3(256), 0, stream, W1, w1pf);
  hipLaunchKernelGGL(k_w2prep, dim3((4 * 3 * 64 * 8 + 255) / 256), dim3(256), 0, stream, W2, w2p);
  hipLaunchKernelGGL(k_gemm1, dim3((N + 63) / 64), dim3(256), 0, stream, x, w1pf, h0f8, N);
  hipLaunchKernelGGL(k_spmm1, dim3(N / 4), dim3(256), 0, stream, ip, epk, h0f8, b1, hbf);
  hipLaunchKernelGGL(k_gemm2, dim3((N + 63) / 64), dim3(256), 0, stream, hbf, w2p, h2f8, N);
  hipLaunchKernelGGL(k_spmm2lsm, dim3(N / 4), dim3(256), 0, stream, ip, epk, h2f8, b2, out);
}

// Round 14
// 208.964 us; speedup vs baseline: 3.5494x; 1.0073x over previous
//
#include <hip/hip_runtime.h>
#include <math.h>

#define F1 256
#define F2 128
#define F3 40
#define H2S 64    // padded h2 fp8 row stride in bytes (half cacheline)
#define RPB 256   // rows per bin (counting-sort granularity)
#define RSH 8
#define TPB 8192  // edges per block in cnt/scatter1 passes

typedef unsigned short ushort_t;
typedef unsigned char uchar_t;
typedef __attribute__((ext_vector_type(8))) short bf16x8;
typedef __attribute__((ext_vector_type(4))) float f32x4;
typedef __attribute__((ext_vector_type(2))) float f32x2;

__device__ inline ushort_t f2bf(float f) {
  unsigned u = __builtin_bit_cast(unsigned, f);
  u += 0x7FFF + ((u >> 16) & 1);
  return (ushort_t)(u >> 16);
}
__device__ inline float bf2f(ushort_t b) {
  unsigned u = ((unsigned)b) << 16;
  return __builtin_bit_cast(float, u);
}
__device__ inline float i2f(int b) { return __builtin_bit_cast(float, b); }
// fp8 e4m3 (OCP) hardware converts
__device__ inline uchar_t f2fp8(float f) {
  return (uchar_t)(__builtin_amdgcn_cvt_pk_fp8_f32(f, 0.f, 0, false) & 0xff);
}
__device__ inline f32x2 fp8pair2f(unsigned u) {
  return __builtin_amdgcn_cvt_pk_f32_fp8(u, false);
}
__device__ inline float fp82f(unsigned u) {
  return __builtin_amdgcn_cvt_f32_fp8(u, 0);
}
// NT edge-record load: 8B record {col:int, wbits:int} as one long long
__device__ inline long long nt_ld_rec(const long long* p) {
  return __builtin_nontemporal_load(p);
}
__device__ inline int rec_col(long long r) { return (int)(unsigned)(r & 0xffffffffll); }
__device__ inline float rec_w(long long r) { return i2f((int)(unsigned)(((unsigned long long)r) >> 32)); }

// ---------------- CSR build: 2-level counting sort (XCD-write-amplification-free) ----------------

__global__ __launch_bounds__(256) void k_cnt(const int* __restrict__ row, int* __restrict__ cnt,
                                             int E, int G, int NBIN) {
  __shared__ int h[400];
  int tid = threadIdx.x, blk = blockIdx.x;
  for (int i = tid; i < NBIN; i += 256) h[i] = 0;
  __syncthreads();
  int base = blk * TPB, lim = min(base + TPB, E);
  for (int i = base + tid; i < lim; i += 256) atomicAdd(&h[row[i] >> RSH], 1);
  __syncthreads();
  for (int i = tid; i < NBIN; i += 256) cnt[i * G + blk] = h[i];
}

__global__ __launch_bounds__(256) void k_scan1(const int* __restrict__ in, int* __restrict__ out,
                                               int* __restrict__ aux, int n) {
  __shared__ int lds[256];
  int tid = threadIdx.x;
  int base = blockIdx.x * 1024 + tid * 4;
  int v0 = 0, v1 = 0, v2 = 0, v3 = 0;
  if (base + 0 < n) v0 = in[base + 0];
  if (base + 1 < n) v1 = in[base + 1];
  if (base + 2 < n) v2 = in[base + 2];
  if (base + 3 < n) v3 = in[base + 3];
  int s = v0 + v1 + v2 + v3;
  lds[tid] = s;
  __syncthreads();
  for (int off = 1; off < 256; off <<= 1) {
    int t = (tid >= off) ? lds[tid - off] : 0;
    __syncthreads();
    lds[tid] += t;
    __syncthreads();
  }
  int excl = (tid > 0) ? lds[tid - 1] : 0;
  if (tid == 255) aux[blockIdx.x] = lds[255];
  if (base + 0 < n) out[base + 0] = excl;
  if (base + 1 < n) out[base + 1] = excl + v0;
  if (base + 2 < n) out[base + 2] = excl + v0 + v1;
  if (base + 3 < n) out[base + 3] = excl + v0 + v1 + v2;
}

__global__ __launch_bounds__(128) void k_scan_aux(int* __restrict__ aux, int nb) {
  __shared__ int lds[128];
  int tid = threadIdx.x;
  int v = (tid < nb) ? aux[tid] : 0;
  lds[tid] = v;
  __syncthreads();
  for (int off = 1; off < 128; off <<= 1) {
    int t = (tid >= off) ? lds[tid - off] : 0;
    __syncthreads();
    lds[tid] += t;
    __syncthreads();
  }
  int excl = (tid > 0) ? lds[tid - 1] : 0;
  if (tid < nb) aux[tid] = excl;
}

__global__ __launch_bounds__(256) void k_scan_add(int* __restrict__ out, const int* __restrict__ aux,
                                                  int n, int E) {
  int add = aux[blockIdx.x];
  int base = blockIdx.x * 1024 + threadIdx.x * 4;
#pragma unroll
  for (int i = 0; i < 4; i++)
    if (base + i < n) out[base + i] += add;
  if (blockIdx.x == 0 && threadIdx.x == 0) out[n] = E;  // sentinel: cntoff[M] = E
}

__global__ __launch_bounds__(256) void k_scatter1(const int* __restrict__ row, const int* __restrict__ col,
                                                  const float* __restrict__ w, const int* __restrict__ cntoff,
                                                  int2* __restrict__ epk2, int E, int G, int NBIN) {
  __shared__ int cur[400];
  int tid = threadIdx.x, blk = blockIdx.x;
  for (int i = tid; i < NBIN; i += 256) cur[i] = cntoff[i * G + blk];
  __syncthreads();
  int base = blk * TPB, lim = min(base + TPB, E);
  for (int i = base + tid; i < lim; i += 256) {
    int r = row[i];
    int pos = atomicAdd(&cur[r >> RSH], 1);
    epk2[pos] = make_int2(((r & (RPB - 1)) << 17) | col[i], __builtin_bit_cast(int, w[i]));
  }
}

__global__ __launch_bounds__(256) void k_binsort(const int* __restrict__ cntoff, const int2* __restrict__ epk2,
                                                 int* __restrict__ ip, int2* __restrict__ epk,
                                                 int G, int NBIN, int N, int E) {
  __shared__ int sc[256], cur[256];
  int tid = threadIdx.x, b = blockIdx.x;
  int s = cntoff[b * G], eend = cntoff[(b + 1) * G];
  cur[tid] = 0;
  __syncthreads();
  for (int i = s + tid; i < eend; i += 256) atomicAdd(&cur[epk2[i].x >> 17], 1);
  __syncthreads();
  int d = cur[tid];
  sc[tid] = d;
  __syncthreads();
  for (int o = 1; o < 256; o <<= 1) {
    int t = (tid >= o) ? sc[tid - o] : 0;
    __syncthreads();
    sc[tid] += t;
    __syncthreads();
  }
  int excl = (tid > 0) ? sc[tid - 1] : 0;
  __syncthreads();
  cur[tid] = excl;
  int gr = (b << RSH) + tid;
  if (gr <= N) ip[gr] = s + excl;
  if (b == 0 && tid == 0) ip[N] = E;
  __syncthreads();
  for (int i = s + tid; i < eend; i += 256) {
    int2 rec = epk2[i];
    int local = rec.x >> 17, c = rec.x & 0x1FFFF;
    int p = s + atomicAdd(&cur[local], 1);
    epk[p] = make_int2(c, rec.y);
  }
}

// ---------------- W1 prep: fp32 [256][128] -> per-lane B-fragments [kt 8][t 8][lane 64][8] ----------------
__global__ __launch_bounds__(256) void k_w1prep(const float* __restrict__ W1, ushort_t* __restrict__ w1pf) {
  int idx = blockIdx.x * 256 + threadIdx.x;
  if (idx < 8 * 8 * 64 * 8) {
    int j = idx & 7;
    int l = (idx >> 3) & 63;
    int t = (idx >> 9) & 7;
    int kt = idx >> 12;
    int k = kt * 32 + (l >> 4) * 8 + j;
    int c = t * 16 + (l & 15);
    w1pf[idx] = f2bf(W1[(size_t)k * F2 + c]);
  }
}

// ---------------- W2 prep: fp32 [128][40] -> per-lane B-fragments [kt 4][t 3][lane 64][8] ----------------
__global__ __launch_bounds__(256) void k_w2prep(const float* __restrict__ W2, ushort_t* __restrict__ w2p) {
  int idx = blockIdx.x * 256 + threadIdx.x;
  if (idx < 4 * 3 * 64 * 8) {
    int j = idx & 7;
    int rem = idx >> 3;
    int l = rem & 63;
    int g = rem >> 6;       // 0..11
    int t = g % 3, kt = g / 3;
    int colc = t * 16 + (l & 15);
    int k = kt * 32 + (l >> 4) * 8 + j;
    w2p[idx] = (colc < F3) ? f2bf(W2[(size_t)k * F3 + colc]) : (ushort_t)0;
  }
}

// ---------------- GEMM1 (MFMA, no LDS): h0f8[N,128] = fp8(x[N,256] @ W1) ----------------
__global__ __launch_bounds__(256) void k_gemm1(const float* __restrict__ x, const ushort_t* __restrict__ w1pf,
                                               uchar_t* __restrict__ h0f8, int N) {
  const int tid = threadIdx.x;
  const int lane = tid & 63;
  const int w = tid >> 6;
  const int r0 = blockIdx.x * 64;
  const int arow = r0 + w * 16 + (lane & 15);
  const int ar = (arow < N) ? arow : 0;
  const int kg = (lane >> 4) * 8;
  const float* xr = x + (size_t)ar * F1 + kg;

  f32x4 acc[8];
#pragma unroll
  for (int t = 0; t < 8; ++t) acc[t] = (f32x4){0.f, 0.f, 0.f, 0.f};

#pragma unroll
  for (int kt = 0; kt < 8; ++kt) {
    float4 v0 = *(const float4*)(xr + kt * 32);
    float4 v1 = *(const float4*)(xr + kt * 32 + 4);
    bf16x8 a;
    a[0] = (short)f2bf(v0.x); a[1] = (short)f2bf(v0.y);
    a[2] = (short)f2bf(v0.z); a[3] = (short)f2bf(v0.w);
    a[4] = (short)f2bf(v1.x); a[5] = (short)f2bf(v1.y);
    a[6] = (short)f2bf(v1.z); a[7] = (short)f2bf(v1.w);
#pragma unroll
    for (int t = 0; t < 8; ++t) {
      bf16x8 b = *(const bf16x8*)(w1pf + (size_t)(((kt * 8 + t) * 64) + lane) * 8);
      acc[t] = __builtin_amdgcn_mfma_f32_16x16x32_bf16(a, b, acc[t], 0, 0, 0);
    }
  }

  // C/D layout (HW-verified): col = lane&15, row = (lane>>4)*4 + j
#pragma unroll
  for (int t = 0; t < 8; ++t) {
    int gc = t * 16 + (lane & 15);
#pragma unroll
    for (int j = 0; j < 4; ++j) {
      int gr = r0 + w * 16 + (lane >> 4) * 4 + j;
      if (gr < N) h0f8[(size_t)gr * F2 + gc] = f2fp8(acc[t][j]);
    }
  }
}

// ---------------- SpMM1 (F=128, fp8 gather: 1 line/edge) + b1 + relu -> h bf16 ----------------
// streaming accesses (epk, hbf) are non-temporal to preserve L2 for the h0f8 gather set
__global__ __launch_bounds__(256) void k_spmm1(const int* __restrict__ ip, const long long* __restrict__ epk,
                                               const uchar_t* __restrict__ h0f8,
                                               const float* __restrict__ b1, ushort_t* __restrict__ hbf) {
  int node = blockIdx.x * 4 + (threadIdx.x >> 6);
  int lane = threadIdx.x & 63;
  int e0 = __builtin_amdgcn_readfirstlane(ip[node]);
  int e1 = __builtin_amdgcn_readfirstlane(ip[node + 1]);
  const ushort_t* hb = (const ushort_t*)h0f8;  // 2 fp8 per ushort, row stride 64 ushorts
  float ax0 = 0.f, ay0 = 0.f, ax1 = 0.f, ay1 = 0.f;
  float ax2 = 0.f, ay2 = 0.f, ax3 = 0.f, ay3 = 0.f;
  float ax4 = 0.f, ay4 = 0.f, ax5 = 0.f, ay5 = 0.f;
  float ax6 = 0.f, ay6 = 0.f, ax7 = 0.f, ay7 = 0.f;
  for (int e = e0; e < e1; e += 8) {
    int i1 = e1 - 1;
    long long p0 = nt_ld_rec(&epk[(e + 0 < e1) ? e + 0 : i1]);
    long long p1 = nt_ld_rec(&epk[(e + 1 < e1) ? e + 1 : i1]);
    long long p2 = nt_ld_rec(&epk[(e + 2 < e1) ? e + 2 : i1]);
    long long p3 = nt_ld_rec(&epk[(e + 3 < e1) ? e + 3 : i1]);
    long long p4 = nt_ld_rec(&epk[(e + 4 < e1) ? e + 4 : i1]);
    long long p5 = nt_ld_rec(&epk[(e + 5 < e1) ? e + 5 : i1]);
    long long p6 = nt_ld_rec(&epk[(e + 6 < e1) ? e + 6 : i1]);
    long long p7 = nt_ld_rec(&epk[(e + 7 < e1) ? e + 7 : i1]);
    unsigned u0 = hb[(size_t)rec_col(p0) * 64 + lane];
    unsigned u1 = hb[(size_t)rec_col(p1) * 64 + lane];
    unsigned u2 = hb[(size_t)rec_col(p2) * 64 + lane];
    unsigned u3 = hb[(size_t)rec_col(p3) * 64 + lane];
    unsigned u4 = hb[(size_t)rec_col(p4) * 64 + lane];
    unsigned u5 = hb[(size_t)rec_col(p5) * 64 + lane];
    unsigned u6 = hb[(size_t)rec_col(p6) * 64 + lane];
    unsigned u7 = hb[(size_t)rec_col(p7) * 64 + lane];
    float w0 = (e + 0 < e1) ? rec_w(p0) : 0.f;
    float w1 = (e + 1 < e1) ? rec_w(p1) : 0.f;
    float w2 = (e + 2 < e1) ? rec_w(p2) : 0.f;
    float w3 = (e + 3 < e1) ? rec_w(p3) : 0.f;
    float w4 = (e + 4 < e1) ? rec_w(p4) : 0.f;
    float w5 = (e + 5 < e1) ? rec_w(p5) : 0.f;
    float w6 = (e + 6 < e1) ? rec_w(p6) : 0.f;
    float w7 = (e + 7 < e1) ? rec_w(p7) : 0.f;
    f32x2 v0 = fp8pair2f(u0); ax0 = fmaf(w0, v0.x, ax0); ay0 = fmaf(w0, v0.y, ay0);
    f32x2 v1 = fp8pair2f(u1); ax1 = fmaf(w1, v1.x, ax1); ay1 = fmaf(w1, v1.y, ay1);
    f32x2 v2 = fp8pair2f(u2); ax2 = fmaf(w2, v2.x, ax2); ay2 = fmaf(w2, v2.y, ay2);
    f32x2 v3 = fp8pair2f(u3); ax3 = fmaf(w3, v3.x, ax3); ay3 = fmaf(w3, v3.y, ay3);
    f32x2 v4 = fp8pair2f(u4); ax4 = fmaf(w4, v4.x, ax4); ay4 = fmaf(w4, v4.y, ay4);
    f32x2 v5 = fp8pair2f(u5); ax5 = fmaf(w5, v5.x, ax5); ay5 = fmaf(w5, v5.y, ay5);
    f32x2 v6 = fp8pair2f(u6); ax6 = fmaf(w6, v6.x, ax6); ay6 = fmaf(w6, v6.y, ay6);
    f32x2 v7 = fp8pair2f(u7); ax7 = fmaf(w7, v7.x, ax7); ay7 = fmaf(w7, v7.y, ay7);
  }
  float axs = ((ax0 + ax1) + (ax2 + ax3)) + ((ax4 + ax5) + (ax6 + ax7));
  float ays = ((ay0 + ay1) + (ay2 + ay3)) + ((ay4 + ay5) + (ay6 + ay7));
  float2 bb = *(const float2*)(b1 + lane * 2);
  unsigned rr = (unsigned)f2bf(fmaxf(axs + bb.x, 0.f)) |
                ((unsigned)f2bf(fmaxf(ays + bb.y, 0.f)) << 16);
  __builtin_nontemporal_store(rr, (unsigned*)(hbf + (size_t)node * F2 + lane * 2));
}

// ---------------- GEMM2 (MFMA, no LDS): h2f8[N,64B] = fp8(h[N,128] @ W2[128,40]) ----------------
__global__ __launch_bounds__(256) void k_gemm2(const ushort_t* __restrict__ hbf, const ushort_t* __restrict__ w2p,
                                               uchar_t* __restrict__ h2f8, int N) {
  const int tid = threadIdx.x;
  const int lane = tid & 63;
  const int w = tid >> 6;
  const int r0 = blockIdx.x * 64;
  const int arow = r0 + w * 16 + (lane & 15);
  const int ar = (arow < N) ? arow : 0;
  const int kg = (lane >> 4) * 8;

  bf16x8 a[4];
#pragma unroll
  for (int kt = 0; kt < 4; ++kt)
    a[kt] = *(const bf16x8*)(hbf + (size_t)ar * F2 + kt * 32 + kg);

  f32x4 acc[3];
#pragma unroll
  for (int t = 0; t < 3; ++t) acc[t] = (f32x4){0.f, 0.f, 0.f, 0.f};

#pragma unroll
  for (int kt = 0; kt < 4; ++kt) {
#pragma unroll
    for (int t = 0; t < 3; ++t) {
      bf16x8 b = *(const bf16x8*)(w2p + (size_t)(((kt * 3 + t) * 64) + lane) * 8);
      acc[t] = __builtin_amdgcn_mfma_f32_16x16x32_bf16(a[kt], b, acc[t], 0, 0, 0);
    }
  }

#pragma unroll
  for (int t = 0; t < 3; ++t) {
    int gc = t * 16 + (lane & 15);
    if (gc < F3) {
#pragma unroll
      for (int j = 0; j < 4; ++j) {
        int gr = r0 + w * 16 + (lane >> 4) * 4 + j;
        if (gr < N) h2f8[(size_t)gr * H2S + gc] = f2fp8(acc[t][j]);
      }
    }
  }
  for (int idx = tid; idx < 64 * 24; idx += 256) {
    int row = idx / 24, pc = F3 + idx % 24;
    int gr = r0 + row;
    if (gr < N) h2f8[(size_t)gr * H2S + pc] = 0;
  }
}

// ---------------- SpMM2 (fp8 64B rows) + b2 + log_softmax fused ----------------
// streaming accesses (epk, out) non-temporal; h2f8 (6.4MB) gather stays cached -> L2-resident
__global__ __launch_bounds__(256) void k_spmm2lsm(const int* __restrict__ ip, const long long* __restrict__ epk,
                                                  const uchar_t* __restrict__ h2f8,
                                                  const float* __restrict__ b2, float* __restrict__ out) {
  int node = blockIdx.x * 4 + (threadIdx.x >> 6);
  int lane = threadIdx.x & 63;
  int e0 = __builtin_amdgcn_readfirstlane(ip[node]);
  int e1 = __builtin_amdgcn_readfirstlane(ip[node + 1]);
  float a0 = 0.f, a1 = 0.f, a2 = 0.f, a3 = 0.f;
  float a4 = 0.f, a5 = 0.f, a6 = 0.f, a7 = 0.f;
  for (int e = e0; e < e1; e += 8) {
    int i1 = e1 - 1;
    long long p0 = nt_ld_rec(&epk[(e + 0 < e1) ? e + 0 : i1]);
    long long p1 = nt_ld_rec(&epk[(e + 1 < e1) ? e + 1 : i1]);
    long long p2 = nt_ld_rec(&epk[(e + 2 < e1) ? e + 2 : i1]);
    long long p3 = nt_ld_rec(&epk[(e + 3 < e1) ? e + 3 : i1]);
    long long p4 = nt_ld_rec(&epk[(e + 4 < e1) ? e + 4 : i1]);
    long long p5 = nt_ld_rec(&epk[(e + 5 < e1) ? e + 5 : i1]);
    long long p6 = nt_ld_rec(&epk[(e + 6 < e1) ? e + 6 : i1]);
    long long p7 = nt_ld_rec(&epk[(e + 7 < e1) ? e + 7 : i1]);
    unsigned u0 = h2f8[(size_t)rec_col(p0) * H2S + lane];
    unsigned u1 = h2f8[(size_t)rec_col(p1) * H2S + lane];
    unsigned u2 = h2f8[(size_t)rec_col(p2) * H2S + lane];
    unsigned u3 = h2f8[(size_t)rec_col(p3) * H2S + lane];
    unsigned u4 = h2f8[(size_t)rec_col(p4) * H2S + lane];
    unsigned u5 = h2f8[(size_t)rec_col(p5) * H2S + lane];
    unsigned u6 = h2f8[(size_t)rec_col(p6) * H2S + lane];
    unsigned u7 = h2f8[(size_t)rec_col(p7) * H2S + lane];
    float w0 = (e + 0 < e1) ? rec_w(p0) : 0.f;
    float w1 = (e + 1 < e1) ? rec_w(p1) : 0.f;
    float w2 = (e + 2 < e1) ? rec_w(p2) : 0.f;
    float w3 = (e + 3 < e1) ? rec_w(p3) : 0.f;
    float w4 = (e + 4 < e1) ? rec_w(p4) : 0.f;
    float w5 = (e + 5 < e1) ? rec_w(p5) : 0.f;
    float w6 = (e + 6 < e1) ? rec_w(p6) : 0.f;
    float w7 = (e + 7 < e1) ? rec_w(p7) : 0.f;
    a0 = fmaf(w0, fp82f(u0), a0);
    a1 = fmaf(w1, fp82f(u1), a1);
    a2 = fmaf(w2, fp82f(u2), a2);
    a3 = fmaf(w3, fp82f(u3), a3);
    a4 = fmaf(w4, fp82f(u4), a4);
    a5 = fmaf(w5, fp82f(u5), a5);
    a6 = fmaf(w6, fp82f(u6), a6);
    a7 = fmaf(w7, fp82f(u7), a7);
  }
  float acc = ((a0 + a1) + (a2 + a3)) + ((a4 + a5) + (a6 + a7));
  float logit = (lane < F3) ? (acc + b2[lane]) : -INFINITY;
  float m = logit;
#pragma unroll
  for (int off = 32; off > 0; off >>= 1) m = fmaxf(m, __shfl_xor(m, off));
  float ex = (lane < F3) ? __expf(logit - m) : 0.f;
  float s = ex;
#pragma unroll
  for (int off = 32; off > 0; off >>= 1) s += __shfl_xor(s, off);
  if (lane < F3)
    __builtin_nontemporal_store(logit - m - __logf(s), out + (size_t)node * F3 + lane);
}

extern "C" void kernel_launch(void* const* d_in, const int* in_sizes, int n_in,
                              void* d_out, int out_size, void* d_ws, size_t ws_size,
                              hipStream_t stream) {
  const float* x     = (const float*)d_in[0];
  const int* erow    = (const int*)d_in[1];
  const int* ecol_in = (const int*)d_in[2];
  const float* ew_in = (const float*)d_in[3];
  const float* W1    = (const float*)d_in[4];
  const float* b1    = (const float*)d_in[5];
  const float* W2    = (const float*)d_in[6];
  const float* b2    = (const float*)d_in[7];
  float* out = (float*)d_out;

  const int N = in_sizes[0] / F1;  // 100000
  const int E = in_sizes[1];       // 1600000

  const int G = (E + TPB - 1) / TPB;          // 196
  const int NBIN = (N + RPB - 1) >> RSH;      // 391
  const int M = NBIN * G;                     // 76636
  const int nb2 = (M + 1023) / 1024;          // 75

  // ws layout (~65.1 MB, unchanged footprint):
  //   region0 [25.6MB]: epk2 (CSR build) -> h0f8[N*128 B] (gemm1..spmm1) -> h2f8[N*64 B] (gemm2..spmm2)
  //   hbf[N*128 u16] | ip[N+32] | cnt[M+8] | cntoff[M+64] | aux[128] | epk[E] int2 | w1pf | w2p
  uchar_t* region0 = (uchar_t*)d_ws;
  int2* epk2 = (int2*)d_ws;
  uchar_t* h0f8 = region0;
  uchar_t* h2f8 = region0;
  ushort_t* hbf = (ushort_t*)(region0 + (size_t)N * F2 * 2);
  int* ip = (int*)(hbf + (size_t)N * F2);
  int* cnt = ip + (N + 32);
  int* cntoff = cnt + M + 8;
  int* aux = cntoff + M + 64;
  int2* epk = (int2*)(aux + 128);
  ushort_t* w1pf = (ushort_t*)(epk + E);      // 8*8*64*8 = 32768 ushorts
  ushort_t* w2p = w1pf + 32768;               // 6144 ushorts

  hipLaunchKernelGGL(k_cnt, dim3(G), dim3(256), 0, stream, erow, cnt, E, G, NBIN);
  hipLaunchKernelGGL(k_scan1, dim3(nb2), dim3(256), 0, stream, cnt, cntoff, aux, M);
  hipLaunchKernelGGL(k_scan_aux, dim3(1), dim3(128), 0, stream, aux, nb2);
  hipLaunchKernelGGL(k_scan_add, dim3(nb2), dim3(256), 0, stream, cntoff, aux, M, E);
  hipLaunchKernelGGL(k_scatter1, dim3(G), dim3(256), 0, stream, erow, ecol_in, ew_in, cntoff, epk2, E, G, NBIN);
  hipLaunchKernelGGL(k_binsort, dim3(NBIN), dim3(256), 0, stream, cntoff, epk2, ip, epk, G, NBIN, N, E);
  hipLaunchKernelGGL(k_w1prep, dim3(128), dim3(256), 0, stream, W1, w1pf);
  hipLaunchKernelGGL(k_w2prep, dim3((4 * 3 * 64 * 8 + 255) / 256), dim3(256), 0, stream, W2, w2p);
  hipLaunchKernelGGL(k_gemm1, dim3((N + 63) / 64), dim3(256), 0, stream, x, w1pf, h0f8, N);
  hipLaunchKernelGGL(k_spmm1, dim3(N / 4), dim3(256), 0, stream, ip, (const long long*)epk, h0f8, b1, hbf);
  hipLaunchKernelGGL(k_gemm2, dim3((N + 63) / 64), dim3(256), 0, stream, hbf, w2p, h2f8, N);
  hipLaunchKernelGGL(k_spmm2lsm, dim3(N / 4), dim3(256), 0, stream, ip, (const long long*)epk, h2f8, b2, out);
}

// Round 15
// 206.354 us; speedup vs baseline: 3.5943x; 1.0126x over previous
//
#include <hip/hip_runtime.h>
#include <math.h>

#define F1 256
#define F2 128
#define F3 40
#define H2S 64    // h2 fp8 row stride in bytes (16 dwords; 10 valid + zero pad)
#define RPB 256
#define RSH 8
#define TPB 8192

typedef unsigned short ushort_t;
typedef unsigned char uchar_t;
typedef unsigned int uint_t;
typedef __attribute__((ext_vector_type(8))) short bf16x8;
typedef __attribute__((ext_vector_type(4))) float f32x4;
typedef __attribute__((ext_vector_type(2))) float f32x2;

__device__ inline ushort_t f2bf(float f) {
  unsigned u = __builtin_bit_cast(unsigned, f);
  u += 0x7FFF + ((u >> 16) & 1);
  return (ushort_t)(u >> 16);
}
__device__ inline float bf2f(ushort_t b) {
  unsigned u = ((unsigned)b) << 16;
  return __builtin_bit_cast(float, u);
}
__device__ inline float i2f(int b) { return __builtin_bit_cast(float, b); }
__device__ inline uchar_t f2fp8(float f) {
  return (uchar_t)(__builtin_amdgcn_cvt_pk_fp8_f32(f, 0.f, 0, false) & 0xff);
}
// decode dword of 4 fp8 -> 4 floats
__device__ inline f32x2 fp8lo(unsigned u) { return __builtin_amdgcn_cvt_pk_f32_fp8(u, false); }
__device__ inline f32x2 fp8hi(unsigned u) { return __builtin_amdgcn_cvt_pk_f32_fp8(u, true); }
__device__ inline long long nt_ld_rec(const long long* p) {
  return __builtin_nontemporal_load(p);
}
__device__ inline int rec_col(long long r) { return (int)(unsigned)(r & 0xffffffffll); }
__device__ inline float rec_w(long long r) { return i2f((int)(unsigned)(((unsigned long long)r) >> 32)); }

// ---------------- CSR build: 2-level counting sort ----------------

__global__ __launch_bounds__(256) void k_cnt(const int* __restrict__ row, int* __restrict__ cnt,
                                             int E, int G, int NBIN) {
  __shared__ int h[400];
  int tid = threadIdx.x, blk = blockIdx.x;
  for (int i = tid; i < NBIN; i += 256) h[i] = 0;
  __syncthreads();
  int base = blk * TPB, lim = min(base + TPB, E);
  for (int i = base + tid; i < lim; i += 256) atomicAdd(&h[row[i] >> RSH], 1);
  __syncthreads();
  for (int i = tid; i < NBIN; i += 256) cnt[i * G + blk] = h[i];
}

__global__ __launch_bounds__(256) void k_scan1(const int* __restrict__ in, int* __restrict__ out,
                                               int* __restrict__ aux, int n) {
  __shared__ int lds[256];
  int tid = threadIdx.x;
  int base = blockIdx.x * 1024 + tid * 4;
  int v0 = 0, v1 = 0, v2 = 0, v3 = 0;
  if (base + 0 < n) v0 = in[base + 0];
  if (base + 1 < n) v1 = in[base + 1];
  if (base + 2 < n) v2 = in[base + 2];
  if (base + 3 < n) v3 = in[base + 3];
  int s = v0 + v1 + v2 + v3;
  lds[tid] = s;
  __syncthreads();
  for (int off = 1; off < 256; off <<= 1) {
    int t = (tid >= off) ? lds[tid - off] : 0;
    __syncthreads();
    lds[tid] += t;
    __syncthreads();
  }
  int excl = (tid > 0) ? lds[tid - 1] : 0;
  if (tid == 255) aux[blockIdx.x] = lds[255];
  if (base + 0 < n) out[base + 0] = excl;
  if (base + 1 < n) out[base + 1] = excl + v0;
  if (base + 2 < n) out[base + 2] = excl + v0 + v1;
  if (base + 3 < n) out[base + 3] = excl + v0 + v1 + v2;
}

__global__ __launch_bounds__(128) void k_scan_aux(int* __restrict__ aux, int nb) {
  __shared__ int lds[128];
  int tid = threadIdx.x;
  int v = (tid < nb) ? aux[tid] : 0;
  lds[tid] = v;
  __syncthreads();
  for (int off = 1; off < 128; off <<= 1) {
    int t = (tid >= off) ? lds[tid - off] : 0;
    __syncthreads();
    lds[tid] += t;
    __syncthreads();
  }
  int excl = (tid > 0) ? lds[tid - 1] : 0;
  if (tid < nb) aux[tid] = excl;
}

__global__ __launch_bounds__(256) void k_scan_add(int* __restrict__ out, const int* __restrict__ aux,
                                                  int n, int E) {
  int add = aux[blockIdx.x];
  int base = blockIdx.x * 1024 + threadIdx.x * 4;
#pragma unroll
  for (int i = 0; i < 4; i++)
    if (base + i < n) out[base + i] += add;
  if (blockIdx.x == 0 && threadIdx.x == 0) out[n] = E;
}

__global__ __launch_bounds__(256) void k_scatter1(const int* __restrict__ row, const int* __restrict__ col,
                                                  const float* __restrict__ w, const int* __restrict__ cntoff,
                                                  int2* __restrict__ epk2, int E, int G, int NBIN) {
  __shared__ int cur[400];
  int tid = threadIdx.x, blk = blockIdx.x;
  for (int i = tid; i < NBIN; i += 256) cur[i] = cntoff[i * G + blk];
  __syncthreads();
  int base = blk * TPB, lim = min(base + TPB, E);
  for (int i = base + tid; i < lim; i += 256) {
    int r = row[i];
    int pos = atomicAdd(&cur[r >> RSH], 1);
    epk2[pos] = make_int2(((r & (RPB - 1)) << 17) | col[i], __builtin_bit_cast(int, w[i]));
  }
}

__global__ __launch_bounds__(256) void k_binsort(const int* __restrict__ cntoff, const int2* __restrict__ epk2,
                                                 int* __restrict__ ip, int2* __restrict__ epk,
                                                 int G, int NBIN, int N, int E) {
  __shared__ int sc[256], cur[256];
  int tid = threadIdx.x, b = blockIdx.x;
  int s = cntoff[b * G], eend = cntoff[(b + 1) * G];
  cur[tid] = 0;
  __syncthreads();
  for (int i = s + tid; i < eend; i += 256) atomicAdd(&cur[epk2[i].x >> 17], 1);
  __syncthreads();
  int d = cur[tid];
  sc[tid] = d;
  __syncthreads();
  for (int o = 1; o < 256; o <<= 1) {
    int t = (tid >= o) ? sc[tid - o] : 0;
    __syncthreads();
    sc[tid] += t;
    __syncthreads();
  }
  int excl = (tid > 0) ? sc[tid - 1] : 0;
  __syncthreads();
  cur[tid] = excl;
  int gr = (b << RSH) + tid;
  if (gr <= N) ip[gr] = s + excl;
  if (b == 0 && tid == 0) ip[N] = E;
  __syncthreads();
  for (int i = s + tid; i < eend; i += 256) {
    int2 rec = epk2[i];
    int local = rec.x >> 17, c = rec.x & 0x1FFFF;
    int p = s + atomicAdd(&cur[local], 1);
    epk[p] = make_int2(c, rec.y);
  }
}

// ---------------- W1 prep ----------------
__global__ __launch_bounds__(256) void k_w1prep(const float* __restrict__ W1, ushort_t* __restrict__ w1pf) {
  int idx = blockIdx.x * 256 + threadIdx.x;
  if (idx < 8 * 8 * 64 * 8) {
    int j = idx & 7;
    int l = (idx >> 3) & 63;
    int t = (idx >> 9) & 7;
    int kt = idx >> 12;
    int k = kt * 32 + (l >> 4) * 8 + j;
    int c = t * 16 + (l & 15);
    w1pf[idx] = f2bf(W1[(size_t)k * F2 + c]);
  }
}

// ---------------- W2 prep ----------------
__global__ __launch_bounds__(256) void k_w2prep(const float* __restrict__ W2, ushort_t* __restrict__ w2p) {
  int idx = blockIdx.x * 256 + threadIdx.x;
  if (idx < 4 * 3 * 64 * 8) {
    int j = idx & 7;
    int rem = idx >> 3;
    int l = rem & 63;
    int g = rem >> 6;
    int t = g % 3, kt = g / 3;
    int colc = t * 16 + (l & 15);
    int k = kt * 32 + (l >> 4) * 8 + j;
    w2p[idx] = (colc < F3) ? f2bf(W2[(size_t)k * F3 + colc]) : (ushort_t)0;
  }
}

// ---------------- GEMM1 (MFMA, no LDS): h0f8[N,128] = fp8(x @ W1) ----------------
__global__ __launch_bounds__(256) void k_gemm1(const float* __restrict__ x, const ushort_t* __restrict__ w1pf,
                                               uchar_t* __restrict__ h0f8, int N) {
  const int tid = threadIdx.x;
  const int lane = tid & 63;
  const int w = tid >> 6;
  const int r0 = blockIdx.x * 64;
  const int arow = r0 + w * 16 + (lane & 15);
  const int ar = (arow < N) ? arow : 0;
  const int kg = (lane >> 4) * 8;
  const float* xr = x + (size_t)ar * F1 + kg;

  f32x4 acc[8];
#pragma unroll
  for (int t = 0; t < 8; ++t) acc[t] = (f32x4){0.f, 0.f, 0.f, 0.f};

#pragma unroll
  for (int kt = 0; kt < 8; ++kt) {
    float4 v0 = *(const float4*)(xr + kt * 32);
    float4 v1 = *(const float4*)(xr + kt * 32 + 4);
    bf16x8 a;
    a[0] = (short)f2bf(v0.x); a[1] = (short)f2bf(v0.y);
    a[2] = (short)f2bf(v0.z); a[3] = (short)f2bf(v0.w);
    a[4] = (short)f2bf(v1.x); a[5] = (short)f2bf(v1.y);
    a[6] = (short)f2bf(v1.z); a[7] = (short)f2bf(v1.w);
#pragma unroll
    for (int t = 0; t < 8; ++t) {
      bf16x8 b = *(const bf16x8*)(w1pf + (size_t)(((kt * 8 + t) * 64) + lane) * 8);
      acc[t] = __builtin_amdgcn_mfma_f32_16x16x32_bf16(a, b, acc[t], 0, 0, 0);
    }
  }

#pragma unroll
  for (int t = 0; t < 8; ++t) {
    int gc = t * 16 + (lane & 15);
#pragma unroll
    for (int j = 0; j < 4; ++j) {
      int gr = r0 + w * 16 + (lane >> 4) * 4 + j;
      if (gr < N) h0f8[(size_t)gr * F2 + gc] = f2fp8(acc[t][j]);
    }
  }
}

// ---------------- SpMM1: 2 edges per gather instruction (32 dword-lanes each) ----------------
__global__ __launch_bounds__(256) void k_spmm1(const int* __restrict__ ip, const long long* __restrict__ epk,
                                               const uchar_t* __restrict__ h0f8,
                                               const float* __restrict__ b1, ushort_t* __restrict__ hbf) {
  int node = blockIdx.x * 4 + (threadIdx.x >> 6);
  int lane = threadIdx.x & 63;
  int e0 = __builtin_amdgcn_readfirstlane(ip[node]);
  int e1 = __builtin_amdgcn_readfirstlane(ip[node + 1]);
  const uint_t* hb = (const uint_t*)h0f8;   // row = 32 dwords
  const int half = lane >> 5;               // which edge of the pair
  const int d = lane & 31;                  // dword within row -> cols 4d..4d+3
  float a0x = 0.f, a0y = 0.f, a0z = 0.f, a0w = 0.f;
  float a1x = 0.f, a1y = 0.f, a1z = 0.f, a1w = 0.f;
  float a2x = 0.f, a2y = 0.f, a2z = 0.f, a2w = 0.f;
  float a3x = 0.f, a3y = 0.f, a3z = 0.f, a3w = 0.f;
  for (int e = e0; e < e1; e += 8) {
    int i1 = e1 - 1;
    long long p0 = nt_ld_rec(&epk[(e + 0 < e1) ? e + 0 : i1]);
    long long p1 = nt_ld_rec(&epk[(e + 1 < e1) ? e + 1 : i1]);
    long long p2 = nt_ld_rec(&epk[(e + 2 < e1) ? e + 2 : i1]);
    long long p3 = nt_ld_rec(&epk[(e + 3 < e1) ? e + 3 : i1]);
    long long p4 = nt_ld_rec(&epk[(e + 4 < e1) ? e + 4 : i1]);
    long long p5 = nt_ld_rec(&epk[(e + 5 < e1) ? e + 5 : i1]);
    long long p6 = nt_ld_rec(&epk[(e + 6 < e1) ? e + 6 : i1]);
    long long p7 = nt_ld_rec(&epk[(e + 7 < e1) ? e + 7 : i1]);
    // per-pair column select (lane half chooses which edge)
    int c0 = half ? rec_col(p1) : rec_col(p0);
    int c1 = half ? rec_col(p3) : rec_col(p2);
    int c2 = half ? rec_col(p5) : rec_col(p4);
    int c3 = half ? rec_col(p7) : rec_col(p6);
    uint_t u0 = hb[(size_t)c0 * 32 + d];
    uint_t u1 = hb[(size_t)c1 * 32 + d];
    uint_t u2 = hb[(size_t)c2 * 32 + d];
    uint_t u3 = hb[(size_t)c3 * 32 + d];
    float w0 = (e + 0 + half < e1) ? (half ? rec_w(p1) : rec_w(p0)) : 0.f;
    float w1 = (e + 2 + half < e1) ? (half ? rec_w(p3) : rec_w(p2)) : 0.f;
    float w2 = (e + 4 + half < e1) ? (half ? rec_w(p5) : rec_w(p4)) : 0.f;
    float w3 = (e + 6 + half < e1) ? (half ? rec_w(p7) : rec_w(p6)) : 0.f;
    f32x2 l0 = fp8lo(u0), h0 = fp8hi(u0);
    f32x2 l1 = fp8lo(u1), h1 = fp8hi(u1);
    f32x2 l2 = fp8lo(u2), h2 = fp8hi(u2);
    f32x2 l3 = fp8lo(u3), h3 = fp8hi(u3);
    a0x = fmaf(w0, l0.x, a0x); a0y = fmaf(w0, l0.y, a0y); a0z = fmaf(w0, h0.x, a0z); a0w = fmaf(w0, h0.y, a0w);
    a1x = fmaf(w1, l1.x, a1x); a1y = fmaf(w1, l1.y, a1y); a1z = fmaf(w1, h1.x, a1z); a1w = fmaf(w1, h1.y, a1w);
    a2x = fmaf(w2, l2.x, a2x); a2y = fmaf(w2, l2.y, a2y); a2z = fmaf(w2, h2.x, a2z); a2w = fmaf(w2, h2.y, a2w);
    a3x = fmaf(w3, l3.x, a3x); a3y = fmaf(w3, l3.y, a3y); a3z = fmaf(w3, h3.x, a3z); a3w = fmaf(w3, h3.y, a3w);
  }
  float sx = (a0x + a1x) + (a2x + a3x);
  float sy = (a0y + a1y) + (a2y + a3y);
  float sz = (a0z + a1z) + (a2z + a3z);
  float sw = (a0w + a1w) + (a2w + a3w);
  // combine the two edge-halves (lane L and L^32 hold same cols)
  sx += __shfl_xor(sx, 32);
  sy += __shfl_xor(sy, 32);
  sz += __shfl_xor(sz, 32);
  sw += __shfl_xor(sw, 32);
  float4 bb = *(const float4*)(b1 + d * 4);
  unsigned long long rr =
      (unsigned long long)f2bf(fmaxf(sx + bb.x, 0.f)) |
      ((unsigned long long)f2bf(fmaxf(sy + bb.y, 0.f)) << 16) |
      ((unsigned long long)f2bf(fmaxf(sz + bb.z, 0.f)) << 32) |
      ((unsigned long long)f2bf(fmaxf(sw + bb.w, 0.f)) << 48);
  if (lane < 32)
    __builtin_nontemporal_store(rr, (unsigned long long*)(hbf + (size_t)node * F2 + d * 4));
}

// ---------------- GEMM2 (MFMA, no LDS): h2f8[N,64B] = fp8(h @ W2) ----------------
__global__ __launch_bounds__(256) void k_gemm2(const ushort_t* __restrict__ hbf, const ushort_t* __restrict__ w2p,
                                               uchar_t* __restrict__ h2f8, int N) {
  const int tid = threadIdx.x;
  const int lane = tid & 63;
  const int w = tid >> 6;
  const int r0 = blockIdx.x * 64;
  const int arow = r0 + w * 16 + (lane & 15);
  const int ar = (arow < N) ? arow : 0;
  const int kg = (lane >> 4) * 8;

  bf16x8 a[4];
#pragma unroll
  for (int kt = 0; kt < 4; ++kt)
    a[kt] = *(const bf16x8*)(hbf + (size_t)ar * F2 + kt * 32 + kg);

  f32x4 acc[3];
#pragma unroll
  for (int t = 0; t < 3; ++t) acc[t] = (f32x4){0.f, 0.f, 0.f, 0.f};

#pragma unroll
  for (int kt = 0; kt < 4; ++kt) {
#pragma unroll
    for (int t = 0; t < 3; ++t) {
      bf16x8 b = *(const bf16x8*)(w2p + (size_t)(((kt * 3 + t) * 64) + lane) * 8);
      acc[t] = __builtin_amdgcn_mfma_f32_16x16x32_bf16(a[kt], b, acc[t], 0, 0, 0);
    }
  }

#pragma unroll
  for (int t = 0; t < 3; ++t) {
    int gc = t * 16 + (lane & 15);
    if (gc < F3) {
#pragma unroll
      for (int j = 0; j < 4; ++j) {
        int gr = r0 + w * 16 + (lane >> 4) * 4 + j;
        if (gr < N) h2f8[(size_t)gr * H2S + gc] = f2fp8(acc[t][j]);
      }
    }
  }
  for (int idx = tid; idx < 64 * 24; idx += 256) {
    int row = idx / 24, pc = F3 + idx % 24;
    int gr = r0 + row;
    if (gr < N) h2f8[(size_t)gr * H2S + pc] = 0;
  }
}

// ---------------- SpMM2 + lsm: 4 edges per gather instruction (16 dword-lanes each) ----------------
__global__ __launch_bounds__(256) void k_spmm2lsm(const int* __restrict__ ip, const long long* __restrict__ epk,
                                                  const uchar_t* __restrict__ h2f8,
                                                  const float* __restrict__ b2, float* __restrict__ out) {
  int node = blockIdx.x * 4 + (threadIdx.x >> 6);
  int lane = threadIdx.x & 63;
  int e0 = __builtin_amdgcn_readfirstlane(ip[node]);
  int e1 = __builtin_amdgcn_readfirstlane(ip[node + 1]);
  const uint_t* hb = (const uint_t*)h2f8;   // row = 16 dwords (10 valid + zero pad)
  const int slot = lane >> 4;               // edge slot 0..3 within quad
  const int d = lane & 15;                  // dword -> cols 4d..4d+3 (valid d<10)
  float aAx = 0.f, aAy = 0.f, aAz = 0.f, aAw = 0.f;
  float aBx = 0.f, aBy = 0.f, aBz = 0.f, aBw = 0.f;
  for (int e = e0; e < e1; e += 8) {
    int i1 = e1 - 1;
    long long p0 = nt_ld_rec(&epk[(e + 0 < e1) ? e + 0 : i1]);
    long long p1 = nt_ld_rec(&epk[(e + 1 < e1) ? e + 1 : i1]);
    long long p2 = nt_ld_rec(&epk[(e + 2 < e1) ? e + 2 : i1]);
    long long p3 = nt_ld_rec(&epk[(e + 3 < e1) ? e + 3 : i1]);
    long long p4 = nt_ld_rec(&epk[(e + 4 < e1) ? e + 4 : i1]);
    long long p5 = nt_ld_rec(&epk[(e + 5 < e1) ? e + 5 : i1]);
    long long p6 = nt_ld_rec(&epk[(e + 6 < e1) ? e + 6 : i1]);
    long long p7 = nt_ld_rec(&epk[(e + 7 < e1) ? e + 7 : i1]);
    // quad A = edges e..e+3, quad B = e+4..e+7; slot selects edge
    long long qa = (slot < 2) ? (slot == 0 ? p0 : p1) : (slot == 2 ? p2 : p3);
    long long qb = (slot < 2) ? (slot == 0 ? p4 : p5) : (slot == 2 ? p6 : p7);
    uint_t uA = hb[(size_t)rec_col(qa) * 16 + d];
    uint_t uB = hb[(size_t)rec_col(qb) * 16 + d];
    float wA = (e + slot < e1) ? rec_w(qa) : 0.f;
    float wB = (e + 4 + slot < e1) ? rec_w(qb) : 0.f;
    f32x2 lA = fp8lo(uA), hA = fp8hi(uA);
    f32x2 lB = fp8lo(uB), hB = fp8hi(uB);
    aAx = fmaf(wA, lA.x, aAx); aAy = fmaf(wA, lA.y, aAy); aAz = fmaf(wA, hA.x, aAz); aAw = fmaf(wA, hA.y, aAw);
    aBx = fmaf(wB, lB.x, aBx); aBy = fmaf(wB, lB.y, aBy); aBz = fmaf(wB, hB.x, aBz); aBw = fmaf(wB, hB.y, aBw);
  }
  float sx = aAx + aBx, sy = aAy + aBy, sz = aAz + aBz, sw = aAw + aBw;
  // sum over the 4 edge-slots (16-lane groups)
  sx += __shfl_xor(sx, 16); sx += __shfl_xor(sx, 32);
  sy += __shfl_xor(sy, 16); sy += __shfl_xor(sy, 32);
  sz += __shfl_xor(sz, 16); sz += __shfl_xor(sz, 32);
  sw += __shfl_xor(sw, 16); sw += __shfl_xor(sw, 32);
  // logits for cols 4d..4d+3
  float l0 = -INFINITY, l1 = -INFINITY, l2 = -INFINITY, l3 = -INFINITY;
  if (d < 10) {
    float4 bb = *(const float4*)(b2 + d * 4);
    l0 = sx + bb.x; l1 = sy + bb.y; l2 = sz + bb.z; l3 = sw + bb.w;
  }
  float m = fmaxf(fmaxf(l0, l1), fmaxf(l2, l3));
#pragma unroll
  for (int off = 1; off < 16; off <<= 1) m = fmaxf(m, __shfl_xor(m, off));
  float e0x = (d < 10) ? __expf(l0 - m) : 0.f;
  float e1x = (d < 10) ? __expf(l1 - m) : 0.f;
  float e2x = (d < 10) ? __expf(l2 - m) : 0.f;
  float e3x = (d < 10) ? __expf(l3 - m) : 0.f;
  float s = (e0x + e1x) + (e2x + e3x);
#pragma unroll
  for (int off = 1; off < 16; off <<= 1) s += __shfl_xor(s, off);
  float ls = __logf(s);
  if (d < 10) {
    f32x4 r;
    r[0] = l0 - m - ls; r[1] = l1 - m - ls; r[2] = l2 - m - ls; r[3] = l3 - m - ls;
    __builtin_nontemporal_store(r, (f32x4*)(out + (size_t)node * F3 + d * 4));
  }
}

extern "C" void kernel_launch(void* const* d_in, const int* in_sizes, int n_in,
                              void* d_out, int out_size, void* d_ws, size_t ws_size,
                              hipStream_t stream) {
  const float* x     = (const float*)d_in[0];
  const int* erow    = (const int*)d_in[1];
  const int* ecol_in = (const int*)d_in[2];
  const float* ew_in = (const float*)d_in[3];
  const float* W1    = (const float*)d_in[4];
  const float* b1    = (const float*)d_in[5];
  const float* W2    = (const float*)d_in[6];
  const float* b2    = (const float*)d_in[7];
  float* out = (float*)d_out;

  const int N = in_sizes[0] / F1;  // 100000
  const int E = in_sizes[1];       // 1600000

  const int G = (E + TPB - 1) / TPB;          // 196
  const int NBIN = (N + RPB - 1) >> RSH;      // 391
  const int M = NBIN * G;                     // 76636
  const int nb2 = (M + 1023) / 1024;          // 75

  uchar_t* region0 = (uchar_t*)d_ws;
  int2* epk2 = (int2*)d_ws;
  uchar_t* h0f8 = region0;
  uchar_t* h2f8 = region0;
  ushort_t* hbf = (ushort_t*)(region0 + (size_t)N * F2 * 2);
  int* ip = (int*)(hbf + (size_t)N * F2);
  int* cnt = ip + (N + 32);
  int* cntoff = cnt + M + 8;
  int* aux = cntoff + M + 64;
  int2* epk = (int2*)(aux + 128);
  ushort_t* w1pf = (ushort_t*)(epk + E);
  ushort_t* w2p = w1pf + 32768;

  hipLaunchKernelGGL(k_cnt, dim3(G), dim3(256), 0, stream, erow, cnt, E, G, NBIN);
  hipLaunchKernelGGL(k_scan1, dim3(nb2), dim3(256), 0, stream, cnt, cntoff, aux, M);
  hipLaunchKernelGGL(k_scan_aux, dim3(1), dim3(128), 0, stream, aux, nb2);
  hipLaunchKernelGGL(k_scan_add, dim3(nb2), dim3(256), 0, stream, cntoff, aux, M, E);
  hipLaunchKernelGGL(k_scatter1, dim3(G), dim3(256), 0, stream, erow, ecol_in, ew_in, cntoff, epk2, E, G, NBIN);
  hipLaunchKernelGGL(k_binsort, dim3(NBIN), dim3(256), 0, stream, cntoff, epk2, ip, epk, G, NBIN, N, E);
  hipLaunchKernelGGL(k_w1prep, dim3(128), dim3(256), 0, stream, W1, w1pf);
  hipLaunchKernelGGL(k_w2prep, dim3((4 * 3 * 64 * 8 + 255) / 256), dim3(256), 0, stream, W2, w2p);
  hipLaunchKernelGGL(k_gemm1, dim3((N + 63) / 64), dim3(256), 0, stream, x, w1pf, h0f8, N);
  hipLaunchKernelGGL(k_spmm1, dim3(N / 4), dim3(256), 0, stream, ip, (const long long*)epk, h0f8, b1, hbf);
  hipLaunchKernelGGL(k_gemm2, dim3((N + 63) / 64), dim3(256), 0, stream, hbf, w2p, h2f8, N);
  hipLaunchKernelGGL(k_spmm2lsm, dim3(N / 4), dim3(256), 0, stream, ip, (const long long*)epk, h2f8, b2, out);
}

// Round 16
// 204.193 us; speedup vs baseline: 3.6323x; 1.0106x over previous
//
#include <hip/hip_runtime.h>
#include <math.h>

#define F1 256
#define F2 128
#define F3 40
#define H2S 64    // h2 fp8 row stride in bytes (16 dwords; 10 valid + zero pad)
#define RPB 256
#define RSH 8
#define TPB 8192

typedef unsigned short ushort_t;
typedef unsigned char uchar_t;
typedef unsigned int uint_t;
typedef __attribute__((ext_vector_type(8))) short bf16x8;
typedef __attribute__((ext_vector_type(4))) float f32x4;
typedef __attribute__((ext_vector_type(2))) float f32x2;

__device__ inline ushort_t f2bf(float f) {
  unsigned u = __builtin_bit_cast(unsigned, f);
  u += 0x7FFF + ((u >> 16) & 1);
  return (ushort_t)(u >> 16);
}
__device__ inline float bf2f(ushort_t b) {
  unsigned u = ((unsigned)b) << 16;
  return __builtin_bit_cast(float, u);
}
__device__ inline float i2f(int b) { return __builtin_bit_cast(float, b); }
__device__ inline uchar_t f2fp8(float f) {
  return (uchar_t)(__builtin_amdgcn_cvt_pk_fp8_f32(f, 0.f, 0, false) & 0xff);
}
__device__ inline f32x2 fp8lo(unsigned u) { return __builtin_amdgcn_cvt_pk_f32_fp8(u, false); }
__device__ inline f32x2 fp8hi(unsigned u) { return __builtin_amdgcn_cvt_pk_f32_fp8(u, true); }
__device__ inline long long nt_ld_rec(const long long* p) {
  return __builtin_nontemporal_load(p);
}
__device__ inline int rec_col(long long r) { return (int)(unsigned)(r & 0xffffffffll); }
__device__ inline float rec_w(long long r) { return i2f((int)(unsigned)(((unsigned long long)r) >> 32)); }

// ---------------- CSR build: 2-level counting sort ----------------

__global__ __launch_bounds__(256) void k_cnt(const int* __restrict__ row, int* __restrict__ cnt,
                                             int E, int G, int NBIN) {
  __shared__ int h[400];
  int tid = threadIdx.x, blk = blockIdx.x;
  for (int i = tid; i < NBIN; i += 256) h[i] = 0;
  __syncthreads();
  int base = blk * TPB, lim = min(base + TPB, E);
  for (int i = base + tid; i < lim; i += 256) atomicAdd(&h[row[i] >> RSH], 1);
  __syncthreads();
  for (int i = tid; i < NBIN; i += 256) cnt[i * G + blk] = h[i];
}

__global__ __launch_bounds__(256) void k_scan1(const int* __restrict__ in, int* __restrict__ out,
                                               int* __restrict__ aux, int n) {
  __shared__ int lds[256];
  int tid = threadIdx.x;
  int base = blockIdx.x * 1024 + tid * 4;
  int v0 = 0, v1 = 0, v2 = 0, v3 = 0;
  if (base + 0 < n) v0 = in[base + 0];
  if (base + 1 < n) v1 = in[base + 1];
  if (base + 2 < n) v2 = in[base + 2];
  if (base + 3 < n) v3 = in[base + 3];
  int s = v0 + v1 + v2 + v3;
  lds[tid] = s;
  __syncthreads();
  for (int off = 1; off < 256; off <<= 1) {
    int t = (tid >= off) ? lds[tid - off] : 0;
    __syncthreads();
    lds[tid] += t;
    __syncthreads();
  }
  int excl = (tid > 0) ? lds[tid - 1] : 0;
  if (tid == 255) aux[blockIdx.x] = lds[255];
  if (base + 0 < n) out[base + 0] = excl;
  if (base + 1 < n) out[base + 1] = excl + v0;
  if (base + 2 < n) out[base + 2] = excl + v0 + v1;
  if (base + 3 < n) out[base + 3] = excl + v0 + v1 + v2;
}

__global__ __launch_bounds__(128) void k_scan_aux(int* __restrict__ aux, int nb) {
  __shared__ int lds[128];
  int tid = threadIdx.x;
  int v = (tid < nb) ? aux[tid] : 0;
  lds[tid] = v;
  __syncthreads();
  for (int off = 1; off < 128; off <<= 1) {
    int t = (tid >= off) ? lds[tid - off] : 0;
    __syncthreads();
    lds[tid] += t;
    __syncthreads();
  }
  int excl = (tid > 0) ? lds[tid - 1] : 0;
  if (tid < nb) aux[tid] = excl;
}

__global__ __launch_bounds__(256) void k_scan_add(int* __restrict__ out, const int* __restrict__ aux,
                                                  int n, int E) {
  int add = aux[blockIdx.x];
  int base = blockIdx.x * 1024 + threadIdx.x * 4;
#pragma unroll
  for (int i = 0; i < 4; i++)
    if (base + i < n) out[base + i] += add;
  if (blockIdx.x == 0 && threadIdx.x == 0) out[n] = E;
}

__global__ __launch_bounds__(256) void k_scatter1(const int* __restrict__ row, const int* __restrict__ col,
                                                  const float* __restrict__ w, const int* __restrict__ cntoff,
                                                  int2* __restrict__ epk2, int E, int G, int NBIN) {
  __shared__ int cur[400];
  int tid = threadIdx.x, blk = blockIdx.x;
  for (int i = tid; i < NBIN; i += 256) cur[i] = cntoff[i * G + blk];
  __syncthreads();
  int base = blk * TPB, lim = min(base + TPB, E);
  for (int i = base + tid; i < lim; i += 256) {
    int r = row[i];
    int pos = atomicAdd(&cur[r >> RSH], 1);
    epk2[pos] = make_int2(((r & (RPB - 1)) << 17) | col[i], __builtin_bit_cast(int, w[i]));
  }
}

__global__ __launch_bounds__(256) void k_binsort(const int* __restrict__ cntoff, const int2* __restrict__ epk2,
                                                 int* __restrict__ ip, int2* __restrict__ epk,
                                                 int G, int NBIN, int N, int E) {
  __shared__ int sc[256], cur[256];
  int tid = threadIdx.x, b = blockIdx.x;
  int s = cntoff[b * G], eend = cntoff[(b + 1) * G];
  cur[tid] = 0;
  __syncthreads();
  for (int i = s + tid; i < eend; i += 256) atomicAdd(&cur[epk2[i].x >> 17], 1);
  __syncthreads();
  int d = cur[tid];
  sc[tid] = d;
  __syncthreads();
  for (int o = 1; o < 256; o <<= 1) {
    int t = (tid >= o) ? sc[tid - o] : 0;
    __syncthreads();
    sc[tid] += t;
    __syncthreads();
  }
  int excl = (tid > 0) ? sc[tid - 1] : 0;
  __syncthreads();
  cur[tid] = excl;
  int gr = (b << RSH) + tid;
  if (gr <= N) ip[gr] = s + excl;
  if (b == 0 && tid == 0) ip[N] = E;
  __syncthreads();
  for (int i = s + tid; i < eend; i += 256) {
    int2 rec = epk2[i];
    int local = rec.x >> 17, c = rec.x & 0x1FFFF;
    int p = s + atomicAdd(&cur[local], 1);
    epk[p] = make_int2(c, rec.y);
  }
}

// ---------------- W1 prep ----------------
__global__ __launch_bounds__(256) void k_w1prep(const float* __restrict__ W1, ushort_t* __restrict__ w1pf) {
  int idx = blockIdx.x * 256 + threadIdx.x;
  if (idx < 8 * 8 * 64 * 8) {
    int j = idx & 7;
    int l = (idx >> 3) & 63;
    int t = (idx >> 9) & 7;
    int kt = idx >> 12;
    int k = kt * 32 + (l >> 4) * 8 + j;
    int c = t * 16 + (l & 15);
    w1pf[idx] = f2bf(W1[(size_t)k * F2 + c]);
  }
}

// ---------------- W2 prep ----------------
__global__ __launch_bounds__(256) void k_w2prep(const float* __restrict__ W2, ushort_t* __restrict__ w2p) {
  int idx = blockIdx.x * 256 + threadIdx.x;
  if (idx < 4 * 3 * 64 * 8) {
    int j = idx & 7;
    int rem = idx >> 3;
    int l = rem & 63;
    int g = rem >> 6;
    int t = g % 3, kt = g / 3;
    int colc = t * 16 + (l & 15);
    int k = kt * 32 + (l >> 4) * 8 + j;
    w2p[idx] = (colc < F3) ? f2bf(W2[(size_t)k * F3 + colc]) : (ushort_t)0;
  }
}

// ---------------- GEMM1 (MFMA, no LDS, phased loads): h0f8[N,128] = fp8(x @ W1) ----------------
__global__ __launch_bounds__(256) void k_gemm1(const float* __restrict__ x, const ushort_t* __restrict__ w1pf,
                                               uchar_t* __restrict__ h0f8, int N) {
  const int tid = threadIdx.x;
  const int lane = tid & 63;
  const int w = tid >> 6;
  const int r0 = blockIdx.x * 64;
  const int arow = r0 + w * 16 + (lane & 15);
  const int ar = (arow < N) ? arow : 0;
  const int kg = (lane >> 4) * 8;
  const float* xr = x + (size_t)ar * F1 + kg;

  // phase 1: issue ALL 16 independent x loads (16-deep MLP; was 2-deep interleaved)
  f32x4 xv[16];
#pragma unroll
  for (int kt = 0; kt < 8; ++kt) {
    xv[2 * kt]     = *(const f32x4*)(xr + kt * 32);
    xv[2 * kt + 1] = *(const f32x4*)(xr + kt * 32 + 4);
  }

  // phase 2: convert to bf16 A-fragments
  bf16x8 a[8];
#pragma unroll
  for (int kt = 0; kt < 8; ++kt) {
    f32x4 v0 = xv[2 * kt], v1 = xv[2 * kt + 1];
    a[kt][0] = (short)f2bf(v0.x); a[kt][1] = (short)f2bf(v0.y);
    a[kt][2] = (short)f2bf(v0.z); a[kt][3] = (short)f2bf(v0.w);
    a[kt][4] = (short)f2bf(v1.x); a[kt][5] = (short)f2bf(v1.y);
    a[kt][6] = (short)f2bf(v1.z); a[kt][7] = (short)f2bf(v1.w);
  }

  f32x4 acc[8];
#pragma unroll
  for (int t = 0; t < 8; ++t) acc[t] = (f32x4){0.f, 0.f, 0.f, 0.f};

  // phase 3: MFMAs with L2-resident B-fragment loads
#pragma unroll
  for (int kt = 0; kt < 8; ++kt) {
#pragma unroll
    for (int t = 0; t < 8; ++t) {
      bf16x8 b = *(const bf16x8*)(w1pf + (size_t)(((kt * 8 + t) * 64) + lane) * 8);
      acc[t] = __builtin_amdgcn_mfma_f32_16x16x32_bf16(a[kt], b, acc[t], 0, 0, 0);
    }
  }

  // C/D layout (HW-verified): col = lane&15, row = (lane>>4)*4 + j
#pragma unroll
  for (int t = 0; t < 8; ++t) {
    int gc = t * 16 + (lane & 15);
#pragma unroll
    for (int j = 0; j < 4; ++j) {
      int gr = r0 + w * 16 + (lane >> 4) * 4 + j;
      if (gr < N) h0f8[(size_t)gr * F2 + gc] = f2fp8(acc[t][j]);
    }
  }
}

// ---------------- SpMM1: 2 edges per gather instruction (32 dword-lanes each) ----------------
__global__ __launch_bounds__(256) void k_spmm1(const int* __restrict__ ip, const long long* __restrict__ epk,
                                               const uchar_t* __restrict__ h0f8,
                                               const float* __restrict__ b1, ushort_t* __restrict__ hbf) {
  int node = blockIdx.x * 4 + (threadIdx.x >> 6);
  int lane = threadIdx.x & 63;
  int e0 = __builtin_amdgcn_readfirstlane(ip[node]);
  int e1 = __builtin_amdgcn_readfirstlane(ip[node + 1]);
  const uint_t* hb = (const uint_t*)h0f8;   // row = 32 dwords
  const int half = lane >> 5;
  const int d = lane & 31;
  float a0x = 0.f, a0y = 0.f, a0z = 0.f, a0w = 0.f;
  float a1x = 0.f, a1y = 0.f, a1z = 0.f, a1w = 0.f;
  float a2x = 0.f, a2y = 0.f, a2z = 0.f, a2w = 0.f;
  float a3x = 0.f, a3y = 0.f, a3z = 0.f, a3w = 0.f;
  for (int e = e0; e < e1; e += 8) {
    int i1 = e1 - 1;
    long long p0 = nt_ld_rec(&epk[(e + 0 < e1) ? e + 0 : i1]);
    long long p1 = nt_ld_rec(&epk[(e + 1 < e1) ? e + 1 : i1]);
    long long p2 = nt_ld_rec(&epk[(e + 2 < e1) ? e + 2 : i1]);
    long long p3 = nt_ld_rec(&epk[(e + 3 < e1) ? e + 3 : i1]);
    long long p4 = nt_ld_rec(&epk[(e + 4 < e1) ? e + 4 : i1]);
    long long p5 = nt_ld_rec(&epk[(e + 5 < e1) ? e + 5 : i1]);
    long long p6 = nt_ld_rec(&epk[(e + 6 < e1) ? e + 6 : i1]);
    long long p7 = nt_ld_rec(&epk[(e + 7 < e1) ? e + 7 : i1]);
    int c0 = half ? rec_col(p1) : rec_col(p0);
    int c1 = half ? rec_col(p3) : rec_col(p2);
    int c2 = half ? rec_col(p5) : rec_col(p4);
    int c3 = half ? rec_col(p7) : rec_col(p6);
    uint_t u0 = hb[(size_t)c0 * 32 + d];
    uint_t u1 = hb[(size_t)c1 * 32 + d];
    uint_t u2 = hb[(size_t)c2 * 32 + d];
    uint_t u3 = hb[(size_t)c3 * 32 + d];
    float w0 = (e + 0 + half < e1) ? (half ? rec_w(p1) : rec_w(p0)) : 0.f;
    float w1 = (e + 2 + half < e1) ? (half ? rec_w(p3) : rec_w(p2)) : 0.f;
    float w2 = (e + 4 + half < e1) ? (half ? rec_w(p5) : rec_w(p4)) : 0.f;
    float w3 = (e + 6 + half < e1) ? (half ? rec_w(p7) : rec_w(p6)) : 0.f;
    f32x2 l0 = fp8lo(u0), h0 = fp8hi(u0);
    f32x2 l1 = fp8lo(u1), h1 = fp8hi(u1);
    f32x2 l2 = fp8lo(u2), h2 = fp8hi(u2);
    f32x2 l3 = fp8lo(u3), h3 = fp8hi(u3);
    a0x = fmaf(w0, l0.x, a0x); a0y = fmaf(w0, l0.y, a0y); a0z = fmaf(w0, h0.x, a0z); a0w = fmaf(w0, h0.y, a0w);
    a1x = fmaf(w1, l1.x, a1x); a1y = fmaf(w1, l1.y, a1y); a1z = fmaf(w1, h1.x, a1z); a1w = fmaf(w1, h1.y, a1w);
    a2x = fmaf(w2, l2.x, a2x); a2y = fmaf(w2, l2.y, a2y); a2z = fmaf(w2, h2.x, a2z); a2w = fmaf(w2, h2.y, a2w);
    a3x = fmaf(w3, l3.x, a3x); a3y = fmaf(w3, l3.y, a3y); a3z = fmaf(w3, h3.x, a3z); a3w = fmaf(w3, h3.y, a3w);
  }
  float sx = (a0x + a1x) + (a2x + a3x);
  float sy = (a0y + a1y) + (a2y + a3y);
  float sz = (a0z + a1z) + (a2z + a3z);
  float sw = (a0w + a1w) + (a2w + a3w);
  sx += __shfl_xor(sx, 32);
  sy += __shfl_xor(sy, 32);
  sz += __shfl_xor(sz, 32);
  sw += __shfl_xor(sw, 32);
  float4 bb = *(const float4*)(b1 + d * 4);
  unsigned long long rr =
      (unsigned long long)f2bf(fmaxf(sx + bb.x, 0.f)) |
      ((unsigned long long)f2bf(fmaxf(sy + bb.y, 0.f)) << 16) |
      ((unsigned long long)f2bf(fmaxf(sz + bb.z, 0.f)) << 32) |
      ((unsigned long long)f2bf(fmaxf(sw + bb.w, 0.f)) << 48);
  if (lane < 32)
    __builtin_nontemporal_store(rr, (unsigned long long*)(hbf + (size_t)node * F2 + d * 4));
}

// ---------------- GEMM2 (MFMA, no LDS): h2f8[N,64B] = fp8(h @ W2) ----------------
__global__ __launch_bounds__(256) void k_gemm2(const ushort_t* __restrict__ hbf, const ushort_t* __restrict__ w2p,
                                               uchar_t* __restrict__ h2f8, int N) {
  const int tid = threadIdx.x;
  const int lane = tid & 63;
  const int w = tid >> 6;
  const int r0 = blockIdx.x * 64;
  const int arow = r0 + w * 16 + (lane & 15);
  const int ar = (arow < N) ? arow : 0;
  const int kg = (lane >> 4) * 8;

  bf16x8 a[4];
#pragma unroll
  for (int kt = 0; kt < 4; ++kt)
    a[kt] = *(const bf16x8*)(hbf + (size_t)ar * F2 + kt * 32 + kg);

  f32x4 acc[3];
#pragma unroll
  for (int t = 0; t < 3; ++t) acc[t] = (f32x4){0.f, 0.f, 0.f, 0.f};

#pragma unroll
  for (int kt = 0; kt < 4; ++kt) {
#pragma unroll
    for (int t = 0; t < 3; ++t) {
      bf16x8 b = *(const bf16x8*)(w2p + (size_t)(((kt * 3 + t) * 64) + lane) * 8);
      acc[t] = __builtin_amdgcn_mfma_f32_16x16x32_bf16(a[kt], b, acc[t], 0, 0, 0);
    }
  }

#pragma unroll
  for (int t = 0; t < 3; ++t) {
    int gc = t * 16 + (lane & 15);
    if (gc < F3) {
#pragma unroll
      for (int j = 0; j < 4; ++j) {
        int gr = r0 + w * 16 + (lane >> 4) * 4 + j;
        if (gr < N) h2f8[(size_t)gr * H2S + gc] = f2fp8(acc[t][j]);
      }
    }
  }
  for (int idx = tid; idx < 64 * 24; idx += 256) {
    int row = idx / 24, pc = F3 + idx % 24;
    int gr = r0 + row;
    if (gr < N) h2f8[(size_t)gr * H2S + pc] = 0;
  }
}

// ---------------- SpMM2 + lsm: 4 edges per gather instruction (16 dword-lanes each) ----------------
__global__ __launch_bounds__(256) void k_spmm2lsm(const int* __restrict__ ip, const long long* __restrict__ epk,
                                                  const uchar_t* __restrict__ h2f8,
                                                  const float* __restrict__ b2, float* __restrict__ out) {
  int node = blockIdx.x * 4 + (threadIdx.x >> 6);
  int lane = threadIdx.x & 63;
  int e0 = __builtin_amdgcn_readfirstlane(ip[node]);
  int e1 = __builtin_amdgcn_readfirstlane(ip[node + 1]);
  const uint_t* hb = (const uint_t*)h2f8;
  const int slot = lane >> 4;
  const int d = lane & 15;
  float aAx = 0.f, aAy = 0.f, aAz = 0.f, aAw = 0.f;
  float aBx = 0.f, aBy = 0.f, aBz = 0.f, aBw = 0.f;
  for (int e = e0; e < e1; e += 8) {
    int i1 = e1 - 1;
    long long p0 = nt_ld_rec(&epk[(e + 0 < e1) ? e + 0 : i1]);
    long long p1 = nt_ld_rec(&epk[(e + 1 < e1) ? e + 1 : i1]);
    long long p2 = nt_ld_rec(&epk[(e + 2 < e1) ? e + 2 : i1]);
    long long p3 = nt_ld_rec(&epk[(e + 3 < e1) ? e + 3 : i1]);
    long long p4 = nt_ld_rec(&epk[(e + 4 < e1) ? e + 4 : i1]);
    long long p5 = nt_ld_rec(&epk[(e + 5 < e1) ? e + 5 : i1]);
    long long p6 = nt_ld_rec(&epk[(e + 6 < e1) ? e + 6 : i1]);
    long long p7 = nt_ld_rec(&epk[(e + 7 < e1) ? e + 7 : i1]);
    long long qa = (slot < 2) ? (slot == 0 ? p0 : p1) : (slot == 2 ? p2 : p3);
    long long qb = (slot < 2) ? (slot == 0 ? p4 : p5) : (slot == 2 ? p6 : p7);
    uint_t uA = hb[(size_t)rec_col(qa) * 16 + d];
    uint_t uB = hb[(size_t)rec_col(qb) * 16 + d];
    float wA = (e + slot < e1) ? rec_w(qa) : 0.f;
    float wB = (e + 4 + slot < e1) ? rec_w(qb) : 0.f;
    f32x2 lA = fp8lo(uA), hA = fp8hi(uA);
    f32x2 lB = fp8lo(uB), hB = fp8hi(uB);
    aAx = fmaf(wA, lA.x, aAx); aAy = fmaf(wA, lA.y, aAy); aAz = fmaf(wA, hA.x, aAz); aAw = fmaf(wA, hA.y, aAw);
    aBx = fmaf(wB, lB.x, aBx); aBy = fmaf(wB, lB.y, aBy); aBz = fmaf(wB, hB.x, aBz); aBw = fmaf(wB, hB.y, aBw);
  }
  float sx = aAx + aBx, sy = aAy + aBy, sz = aAz + aBz, sw = aAw + aBw;
  sx += __shfl_xor(sx, 16); sx += __shfl_xor(sx, 32);
  sy += __shfl_xor(sy, 16); sy += __shfl_xor(sy, 32);
  sz += __shfl_xor(sz, 16); sz += __shfl_xor(sz, 32);
  sw += __shfl_xor(sw, 16); sw += __shfl_xor(sw, 32);
  float l0 = -INFINITY, l1 = -INFINITY, l2 = -INFINITY, l3 = -INFINITY;
  if (d < 10) {
    float4 bb = *(const float4*)(b2 + d * 4);
    l0 = sx + bb.x; l1 = sy + bb.y; l2 = sz + bb.z; l3 = sw + bb.w;
  }
  float m = fmaxf(fmaxf(l0, l1), fmaxf(l2, l3));
#pragma unroll
  for (int off = 1; off < 16; off <<= 1) m = fmaxf(m, __shfl_xor(m, off));
  float e0x = (d < 10) ? __expf(l0 - m) : 0.f;
  float e1x = (d < 10) ? __expf(l1 - m) : 0.f;
  float e2x = (d < 10) ? __expf(l2 - m) : 0.f;
  float e3x = (d < 10) ? __expf(l3 - m) : 0.f;
  float s = (e0x + e1x) + (e2x + e3x);
#pragma unroll
  for (int off = 1; off < 16; off <<= 1) s += __shfl_xor(s, off);
  float ls = __logf(s);
  if (d < 10) {
    f32x4 r;
    r[0] = l0 - m - ls; r[1] = l1 - m - ls; r[2] = l2 - m - ls; r[3] = l3 - m - ls;
    __builtin_nontemporal_store(r, (f32x4*)(out + (size_t)node * F3 + d * 4));
  }
}

extern "C" void kernel_launch(void* const* d_in, const int* in_sizes, int n_in,
                              void* d_out, int out_size, void* d_ws, size_t ws_size,
                              hipStream_t stream) {
  const float* x     = (const float*)d_in[0];
  const int* erow    = (const int*)d_in[1];
  const int* ecol_in = (const int*)d_in[2];
  const float* ew_in = (const float*)d_in[3];
  const float* W1    = (const float*)d_in[4];
  const float* b1    = (const float*)d_in[5];
  const float* W2    = (const float*)d_in[6];
  const float* b2    = (const float*)d_in[7];
  float* out = (float*)d_out;

  const int N = in_sizes[0] / F1;  // 100000
  const int E = in_sizes[1];       // 1600000

  const int G = (E + TPB - 1) / TPB;          // 196
  const int NBIN = (N + RPB - 1) >> RSH;      // 391
  const int M = NBIN * G;                     // 76636
  const int nb2 = (M + 1023) / 1024;          // 75

  uchar_t* region0 = (uchar_t*)d_ws;
  int2* epk2 = (int2*)d_ws;
  uchar_t* h0f8 = region0;
  uchar_t* h2f8 = region0;
  ushort_t* hbf = (ushort_t*)(region0 + (size_t)N * F2 * 2);
  int* ip = (int*)(hbf + (size_t)N * F2);
  int* cnt = ip + (N + 32);
  int* cntoff = cnt + M + 8;
  int* aux = cntoff + M + 64;
  int2* epk = (int2*)(aux + 128);
  ushort_t* w1pf = (ushort_t*)(epk + E);
  ushort_t* w2p = w1pf + 32768;

  hipLaunchKernelGGL(k_cnt, dim3(G), dim3(256), 0, stream, erow, cnt, E, G, NBIN);
  hipLaunchKernelGGL(k_scan1, dim3(nb2), dim3(256), 0, stream, cnt, cntoff, aux, M);
  hipLaunchKernelGGL(k_scan_aux, dim3(1), dim3(128), 0, stream, aux, nb2);
  hipLaunchKernelGGL(k_scan_add, dim3(nb2), dim3(256), 0, stream, cntoff, aux, M, E);
  hipLaunchKernelGGL(k_scatter1, dim3(G), dim3(256), 0, stream, erow, ecol_in, ew_in, cntoff, epk2, E, G, NBIN);
  hipLaunchKernelGGL(k_binsort, dim3(NBIN), dim3(256), 0, stream, cntoff, epk2, ip, epk, G, NBIN, N, E);
  hipLaunchKernelGGL(k_w1prep, dim3(128), dim3(256), 0, stream, W1, w1pf);
  hipLaunchKernelGGL(k_w2prep, dim3((4 * 3 * 64 * 8 + 255) / 256), dim3(256), 0, stream, W2, w2p);
  hipLaunchKernelGGL(k_gemm1, dim3((N + 63) / 64), dim3(256), 0, stream, x, w1pf, h0f8, N);
  hipLaunchKernelGGL(k_spmm1, dim3(N / 4), dim3(256), 0, stream, ip, (const long long*)epk, h0f8, b1, hbf);
  hipLaunchKernelGGL(k_gemm2, dim3((N + 63) / 64), dim3(256), 0, stream, hbf, w2p, h2f8, N);
  hipLaunchKernelGGL(k_spmm2lsm, dim3(N / 4), dim3(256), 0, stream, ip, (const long long*)epk, h2f8, b2, out);
}